// Round 7
// baseline (3172.992 us; speedup 1.0000x reference)
//
#include <hip/hip_runtime.h>
#include <cmath>

typedef unsigned short bf16_t;                                  // raw bf16 bits
typedef _Float16 f16_t;                                         // IEEE fp16
typedef __attribute__((ext_vector_type(8))) short short8;       // MFMA A/B frag
typedef __attribute__((ext_vector_type(4))) float f32x4;        // MFMA C/D frag
typedef _Float16 h2 __attribute__((ext_vector_type(2)));
typedef _Float16 h8 __attribute__((ext_vector_type(8)));

#define NI_N 32768
#define NV_N 131072
#define E_VV 1048576
#define E_VI 524288
#define E_IV 524288
#define NT_N (NV_N+NV_N+NI_N)          // 294912 concatenated nodes (vv|iv|vi)
#define ET_N (E_VV+E_IV+E_VI)          // 2097152 concatenated edges
#define SC_WIN 8                        // scatter windows

#if __has_builtin(__builtin_amdgcn_fdot2)
#define FDOT2(a,b,c) __builtin_amdgcn_fdot2((a),(b),(c),false)
#else
#define FDOT2(a,b,c) ((float)(a)[0]*(float)(b)[0]+(float)(a)[1]*(float)(b)[1]+(c))
#endif

__device__ __forceinline__ float bf2f(bf16_t u){ return __builtin_bit_cast(float,((unsigned)u)<<16); }
__device__ __forceinline__ bf16_t f2bf(float f){
  unsigned u=__builtin_bit_cast(unsigned,f);
  return (bf16_t)((u+0x7fffu+((u>>16)&1u))>>16);
}
__device__ __forceinline__ float gelu_f(float x){ return 0.5f*x*(1.0f+erff(x*0.7071067811865476f)); }

// split f32 into hi/lo bf16
__device__ __forceinline__ void splitf(float v, short& hi, short& lo){
  bf16_t h=f2bf(v);
  hi=(short)h;
  lo=(short)f2bf(v-bf2f(h));
}
__device__ __forceinline__ float ldval(const float* p){ return *p; }
__device__ __forceinline__ float ldval(const f16_t* p){ return (float)*p; }
__device__ __forceinline__ void stval(float* p,float v){ *p=v; }
__device__ __forceinline__ void stval(f16_t* p,float v){ *p=(f16_t)v; }

// ---------------- fused CSR build over 3 concatenated edge types ----------------
__global__ __launch_bounds__(256) void k_hist3(const int* __restrict__ dvv,const int* __restrict__ div_,
    const int* __restrict__ dvi,int* __restrict__ cnt){
  int i=blockIdx.x*256+threadIdx.x;
  if(i<E_VV) atomicAdd(&cnt[dvv[i]],1);
  else if(i<E_VV+E_IV) atomicAdd(&cnt[NV_N+div_[i-E_VV]],1);
  else atomicAdd(&cnt[2*NV_N+dvi[i-E_VV-E_IV]],1);
}
__global__ __launch_bounds__(512) void k_scan1(const int* __restrict__ cnt,int N,int* __restrict__ rp,int* __restrict__ bsum){
  __shared__ int sh[512];
  int i=blockIdx.x*512+threadIdx.x;
  int v=(i<N)?cnt[i]:0;
  sh[threadIdx.x]=v; __syncthreads();
  for(int off=1;off<512;off<<=1){
    int t=(threadIdx.x>=(unsigned)off)?sh[threadIdx.x-off]:0; __syncthreads();
    sh[threadIdx.x]+=t; __syncthreads();
  }
  if(i<N) rp[i]=sh[threadIdx.x]-v;
  if(threadIdx.x==511) bsum[blockIdx.x]=sh[511];
}
__global__ __launch_bounds__(1024) void k_scan2(const int* __restrict__ bsum,int* __restrict__ boff,int nb){
  __shared__ int sh[1024];
  int t=threadIdx.x;
  int v=(t<nb)?bsum[t]:0;
  sh[t]=v; __syncthreads();
  for(int off=1;off<1024;off<<=1){
    int x=(t>=(unsigned)off)?sh[t-off]:0; __syncthreads();
    sh[t]+=x; __syncthreads();
  }
  if(t<nb) boff[t]=sh[t]-v;
  if(t==1023) boff[nb]=sh[1023];
}
__global__ __launch_bounds__(512) void k_scan3(int* __restrict__ rp,const int* __restrict__ boff,int* __restrict__ cur,int N,int nb){
  int i=blockIdx.x*512+threadIdx.x;
  if(i<N){ int v=rp[i]+boff[i>>9]; rp[i]=v; cur[i]=v; }
  if(i==0) rp[N]=boff[nb];
}
// windowed scatter: only edges whose (global) destination is in [dlo,dhi) are placed.
// rp monotone => writes land in a contiguous ~1MB slice => L2 merges stores.
__global__ __launch_bounds__(256) void k_scatter3w(const int* __restrict__ svv,const int* __restrict__ dvv,
    const int* __restrict__ siv,const int* __restrict__ div_,
    const int* __restrict__ svi,const int* __restrict__ dvi,
    int* __restrict__ cur,int* __restrict__ esrc,int dlo,int dhi){
  int i=blockIdx.x*256+threadIdx.x;
  int d,s;
  if(i<E_VV){ d=dvv[i]; if(d<dlo||d>=dhi) return; s=svv[i]; }
  else if(i<E_VV+E_IV){ int j=i-E_VV; d=NV_N+div_[j]; if(d<dlo||d>=dhi) return; s=siv[j]; }
  else { int j=i-E_VV-E_IV; d=2*NV_N+dvi[j]; if(d<dlo||d>=dhi) return; s=svi[j]; }
  int p=atomicAdd(&cur[d],1); esrc[p]=s;
}

// ---------------- weight folding + pre-split to bf16 hi/lo planes ----------------
struct FoldArgs{
  const float *Wk_i,*Wq_i,*Wv_i,*bk_i,*bq_i,*bv_i;
  const float *Wk_v,*Wq_v,*Wv_v,*bk_v,*bq_v,*bv_v;
  const float *arel_vv,*mrel_vv,*prel_vv,*arel_vi,*mrel_vi,*prel_vi,*arel_iv,*mrel_iv,*prel_iv;
  const float *Wa_i,*Wa_v;
  short *fwh_var,*fwl_var,*fwh_ins,*fwl_ins,*wah_i,*wal_i,*wah_v,*wal_v;
  float *fwb_var,*fwb_ins;
  int l;
};
__global__ __launch_bounds__(256) void k_fold(FoldArgs fa){
  int gid=blockIdx.x*256+threadIdx.x;
  if(gid>=640*64) return;
  int r=gid>>6, c=gid&63;
  int l=fa.l;
  if(r>=512){
    int ro=r&63;
    const float* W=(r<576)?fa.Wa_i:fa.Wa_v;
    short *sh=(r<576)?fa.wah_i:fa.wah_v, *sl=(r<576)?fa.wal_i:fa.wal_v;
    short h,lo; splitf(W[l*4096+ro*64+c],h,lo);
    sh[ro*64+c]=h; sl[ro*64+c]=lo;
    return;
  }
  const float *W,*B,*rel=nullptr,*prl=nullptr;
  short *sh,*sl; float *fwb; int orow;
  if(r<320){
    sh=fa.fwh_var; sl=fa.fwl_var; fwb=fa.fwb_var; orow=r;
    if(r<64){ W=fa.Wq_v; B=fa.bq_v; }
    else if(r<128){ W=fa.Wk_v; B=fa.bk_v; rel=fa.arel_vv; prl=fa.prel_vv; }
    else if(r<192){ W=fa.Wv_v; B=fa.bv_v; rel=fa.mrel_vv; }
    else if(r<256){ W=fa.Wk_v; B=fa.bk_v; rel=fa.arel_vi; prl=fa.prel_vi; }
    else         { W=fa.Wv_v; B=fa.bv_v; rel=fa.mrel_vi; }
  }else{
    int rr=r-320; sh=fa.fwh_ins; sl=fa.fwl_ins; fwb=fa.fwb_ins; orow=rr;
    if(rr<64){ W=fa.Wq_i; B=fa.bq_i; }
    else if(rr<128){ W=fa.Wk_i; B=fa.bk_i; rel=fa.arel_iv; prl=fa.prel_iv; }
    else           { W=fa.Wv_i; B=fa.bv_i; rel=fa.mrel_iv; }
  }
  int ro=orow&63;
  float val,bval;
  if(!rel){
    val=W[l*4096+ro*64+c]; bval=B[l*64+ro];
  }else{
    int h=ro>>3, e=ro&7;
    float s=prl?prl[l*8+h]*0.3535533905932738f:1.0f;
    float acc=0.f,bacc=0.f;
    #pragma unroll
    for(int d=0;d<8;d++){
      float rv=rel[l*512+h*64+d*8+e];
      acc += W[l*4096+(h*8+d)*64+c]*rv;
      bacc+= B[l*64+h*8+d]*rv;
    }
    val=acc*s; bval=bacc*s;
  }
  short h2v,lo2; splitf(val,h2v,lo2);
  sh[orow*64+c]=h2v; sl[orow*64+c]=lo2;
  if(c==0) fwb[orow]=bval;
}

__global__ __launch_bounds__(256) void k_split2(const float* __restrict__ W,int n,short* __restrict__ hi,short* __restrict__ lo){
  int i=blockIdx.x*256+threadIdx.x;
  if(i<n){ short h,l2; splitf(W[i],h,l2); hi[i]=h; lo[i]=l2; }
}

// ---------------- split-bf16 K=64 MFMA GEMM, panel-looped (A read once) ----------------
template<typename AT, typename OT>
__global__ __launch_bounds__(256) void k_gemm64p(const AT* __restrict__ A,int N,
    const short* __restrict__ Bh,const short* __restrict__ Bl,
    const float* __restrict__ bias,float bias_scale,
    OT* __restrict__ out,int octot,int ocol0,int npanels)
{
  const int wave=threadIdx.x>>6, lane=threadIdx.x&63;
  const int m=lane&15, quad=lane>>4;
  const int row0=blockIdx.x*64+wave*16;
  if(row0>=N) return;
  const AT* ap=A+(size_t)(row0+m)*64+quad*8;
  short8 ahi[2], alo[2];
  #pragma unroll
  for(int kf=0;kf<2;kf++){
    short8 th,tl;
    #pragma unroll
    for(int j=0;j<8;j++){ short h,l2; splitf(ldval(&ap[kf*32+j]),h,l2); th[j]=h; tl[j]=l2; }
    ahi[kf]=th; alo[kf]=tl;
  }
  for(int pan=0;pan<npanels;pan++){
    int colbase=pan*64;
    short8 bhi[4][2], blo[4][2];
    #pragma unroll
    for(int ot=0;ot<4;ot++){
      size_t o=(size_t)(colbase+ot*16+m)*64+quad*8;
      #pragma unroll
      for(int kf=0;kf<2;kf++){
        bhi[ot][kf]=*(const short8*)(Bh+o+kf*32);
        blo[ot][kf]=*(const short8*)(Bl+o+kf*32);
      }
    }
    f32x4 acc[4];
    #pragma unroll
    for(int ot=0;ot<4;ot++){
      float bv=bias[colbase+ot*16+m]*bias_scale;
      acc[ot][0]=bv; acc[ot][1]=bv; acc[ot][2]=bv; acc[ot][3]=bv;
    }
    #pragma unroll
    for(int ot=0;ot<4;ot++){
      #pragma unroll
      for(int kf=0;kf<2;kf++){
        acc[ot]=__builtin_amdgcn_mfma_f32_16x16x32_bf16(alo[kf],bhi[ot][kf],acc[ot],0,0,0);
        acc[ot]=__builtin_amdgcn_mfma_f32_16x16x32_bf16(ahi[kf],blo[ot][kf],acc[ot],0,0,0);
        acc[ot]=__builtin_amdgcn_mfma_f32_16x16x32_bf16(ahi[kf],bhi[ot][kf],acc[ot],0,0,0);
      }
    }
    #pragma unroll
    for(int ot=0;ot<4;ot++){
      int col=ocol0+colbase+ot*16+m;
      #pragma unroll
      for(int r=0;r<4;r++){
        int row=row0+quad*4+r;
        stval(&out[(size_t)row*octot+col],acc[ot][r]);
      }
    }
  }
}

// ---------------- fused per-layer update (instr blocks then var blocks) ----------------
__global__ __launch_bounds__(256) void k_update2(const float* __restrict__ agg_i,const float* __restrict__ agg_v,
    const short* __restrict__ wah_i,const short* __restrict__ wal_i,
    const short* __restrict__ wah_v,const short* __restrict__ wal_v,
    const float* __restrict__ ba_i,const float* __restrict__ ba_v,
    const float* __restrict__ skip_i,const float* __restrict__ skip_v,
    float* __restrict__ x_i,float* __restrict__ x_v,
    f16_t* __restrict__ outs,int nbi)
{
  const int wave=threadIdx.x>>6, lane=threadIdx.x&63;
  const int m=lane&15, quad=lane>>4;
  const bool isI=(int)blockIdx.x<nbi;
  const int row0=(isI?blockIdx.x:(blockIdx.x-nbi))*64+wave*16;
  const float* agg=isI?agg_i:agg_v;
  const short* Wah=isI?wah_i:wah_v;
  const short* Wal=isI?wal_i:wal_v;
  const float* ba=isI?ba_i:ba_v;
  const float* skip=isI?skip_i:skip_v;
  float* x=isI?x_i:x_v;
  f16_t* oo=isI?outs:nullptr;
  short8 bhi[4][2], blo[4][2];
  #pragma unroll
  for(int ot=0;ot<4;ot++){
    size_t o=(size_t)(ot*16+m)*64+quad*8;
    #pragma unroll
    for(int kf=0;kf<2;kf++){
      bhi[ot][kf]=*(const short8*)(Wah+o+kf*32);
      blo[ot][kf]=*(const short8*)(Wal+o+kf*32);
    }
  }
  const float* ap=agg+(size_t)(row0+m)*64+quad*8;
  short8 ahi[2], alo[2];
  #pragma unroll
  for(int kf=0;kf<2;kf++){
    short8 th,tl;
    #pragma unroll
    for(int j=0;j<8;j++){ short h,l2; splitf(gelu_f(ap[kf*32+j]),h,l2); th[j]=h; tl[j]=l2; }
    ahi[kf]=th; alo[kf]=tl;
  }
  f32x4 acc[4];
  #pragma unroll
  for(int ot=0;ot<4;ot++){
    float bv=ba[ot*16+m];
    acc[ot][0]=bv; acc[ot][1]=bv; acc[ot][2]=bv; acc[ot][3]=bv;
  }
  #pragma unroll
  for(int ot=0;ot<4;ot++){
    #pragma unroll
    for(int kf=0;kf<2;kf++){
      acc[ot]=__builtin_amdgcn_mfma_f32_16x16x32_bf16(alo[kf],bhi[ot][kf],acc[ot],0,0,0);
      acc[ot]=__builtin_amdgcn_mfma_f32_16x16x32_bf16(ahi[kf],blo[ot][kf],acc[ot],0,0,0);
      acc[ot]=__builtin_amdgcn_mfma_f32_16x16x32_bf16(ahi[kf],bhi[ot][kf],acc[ot],0,0,0);
    }
  }
  float s=1.0f/(1.0f+__expf(-skip[0]));
  #pragma unroll
  for(int ot=0;ot<4;ot++){
    int col=ot*16+m;
    #pragma unroll
    for(int r=0;r<4;r++){
      int row=row0+quad*4+r;
      size_t idx=(size_t)row*64+col;
      float xn=s*acc[ot][r]+(1.0f-s)*x[idx];
      x[idx]=xn;
      if(oo) oo[idx]=(f16_t)xn;
    }
  }
}

// ---------------- edge attention: 4 dst nodes per wave, interleaved streams ----------------
// lane = (edge_slot eL=lane>>3, head h=lane&7); 8 edges/chunk; online softmax.
// feature layout: stride 192 f16, k@64, v@128. rp values ABSOLUTE into esrc_all.
__device__ __forceinline__ void edge_phase4(const int* __restrict__ rp,const int* __restrict__ es,
    const f16_t* __restrict__ sf,int base,int eL,int h,
    const h2 q[4][4],float acc[4][8],float ls[4])
{
  int b[4],e[4],i[4]; float m[4];
  #pragma unroll
  for(int j=0;j<4;j++){
    b[j]=__builtin_amdgcn_readfirstlane(rp[base+j]);
    e[j]=__builtin_amdgcn_readfirstlane(rp[base+j+1]);
    i[j]=b[j]; m[j]=-INFINITY; ls[j]=0.f;
    #pragma unroll
    for(int t=0;t<8;t++) acc[j][t]=0.f;
  }
  bool any=(i[0]<e[0])|(i[1]<e[1])|(i[2]<e[2])|(i[3]<e[3]);
  while(any){
    bool act[4]; int sidx[4];
    #pragma unroll
    for(int j=0;j<4;j++){
      act[j]=i[j]<e[j];
      if(act[j]){
        int ii=i[j]+eL;
        int iic=ii<e[j]?ii:e[j]-1;
        sidx[j]=es[iic];
      }
    }
    h8 kk[4],vv[4];
    #pragma unroll
    for(int j=0;j<4;j++){
      if(act[j]){
        const f16_t* rowp=sf+(size_t)sidx[j]*192;
        kk[j]=*(const h8*)(rowp+64+h*8);
        vv[j]=*(const h8*)(rowp+128+h*8);
      }
    }
    #pragma unroll
    for(int j=0;j<4;j++){
      if(act[j]){
        h2 k0={kk[j][0],kk[j][1]},k1={kk[j][2],kk[j][3]},k2={kk[j][4],kk[j][5]},k3={kk[j][6],kk[j][7]};
        float pp=FDOT2(q[j][0],k0,0.f);
        pp=FDOT2(q[j][1],k1,pp);
        pp=FDOT2(q[j][2],k2,pp);
        pp=FDOT2(q[j][3],k3,pp);
        if(i[j]+eL>=e[j]) pp=-INFINITY;
        float pm=pp;
        pm=fmaxf(pm,__shfl_xor(pm,8));
        pm=fmaxf(pm,__shfl_xor(pm,16));
        pm=fmaxf(pm,__shfl_xor(pm,32));
        float mn=fmaxf(m[j],pm);
        float sc=__expf(m[j]-mn);
        float w=__expf(pp-mn);
        ls[j]=ls[j]*sc+w;
        #pragma unroll
        for(int t=0;t<8;t++) acc[j][t]=acc[j][t]*sc+w*(float)vv[j][t];
        m[j]=mn;
        i[j]+=8;
      }
    }
    any=(i[0]<e[0])|(i[1]<e[1])|(i[2]<e[2])|(i[3]<e[3]);
  }
}
__device__ __forceinline__ void reduce4(float acc[4][8],float ls[4]){
  #pragma unroll
  for(int j=0;j<4;j++){
    #pragma unroll
    for(int msk=8;msk<64;msk<<=1){
      ls[j]+=__shfl_xor(ls[j],msk);
      #pragma unroll
      for(int t=0;t<8;t++) acc[j][t]+=__shfl_xor(acc[j][t],msk);
    }
  }
}

__global__ __launch_bounds__(256) void k_edge_var(const int* __restrict__ rp_vv,const int* __restrict__ rp_iv,
    const int* __restrict__ es,
    const f16_t* __restrict__ var_feat,const f16_t* __restrict__ ins_feat,
    float* __restrict__ agg)
{
  int wave=threadIdx.x>>6, lane=threadIdx.x&63;
  int base=blockIdx.x*16+wave*4;
  int eL=lane>>3, h=lane&7;
  h2 q[4][4];
  #pragma unroll
  for(int j=0;j<4;j++){
    h8 qq=*(const h8*)(var_feat+(size_t)(base+j)*192+h*8);
    q[j][0]=h2{qq[0],qq[1]}; q[j][1]=h2{qq[2],qq[3]}; q[j][2]=h2{qq[4],qq[5]}; q[j][3]=h2{qq[6],qq[7]};
  }
  float a1[4][8],ls1[4],a2[4][8],ls2[4];
  edge_phase4(rp_vv,es,var_feat,base,eL,h,q,a1,ls1);
  edge_phase4(rp_iv,es,ins_feat,base,eL,h,q,a2,ls2);
  reduce4(a1,ls1);
  reduce4(a2,ls2);
  if(eL==0){
    #pragma unroll
    for(int j=0;j<4;j++){
      float r[8];
      #pragma unroll
      for(int t=0;t<8;t++) r[t]=a1[j][t]/(ls1[j]+1e-16f)+a2[j][t]/(ls2[j]+1e-16f);
      f32x4 o1={r[0],r[1],r[2],r[3]}, o2={r[4],r[5],r[6],r[7]};
      *(f32x4*)(agg+(size_t)(base+j)*64+h*8)=o1;
      *(f32x4*)(agg+(size_t)(base+j)*64+h*8+4)=o2;
    }
  }
}
__global__ __launch_bounds__(256) void k_edge_ins(const int* __restrict__ rp,const int* __restrict__ es,
    const f16_t* __restrict__ ins_feat,const f16_t* __restrict__ var_feat,
    float* __restrict__ agg)
{
  int wave=threadIdx.x>>6, lane=threadIdx.x&63;
  int base=blockIdx.x*16+wave*4;
  int eL=lane>>3, h=lane&7;
  h2 q[4][4];
  #pragma unroll
  for(int j=0;j<4;j++){
    h8 qq=*(const h8*)(ins_feat+(size_t)(base+j)*192+h*8);
    q[j][0]=h2{qq[0],qq[1]}; q[j][1]=h2{qq[2],qq[3]}; q[j][2]=h2{qq[4],qq[5]}; q[j][3]=h2{qq[6],qq[7]};
  }
  float a1[4][8],ls1[4];
  edge_phase4(rp,es,var_feat,base,eL,h,q,a1,ls1);
  reduce4(a1,ls1);
  if(eL==0){
    #pragma unroll
    for(int j=0;j<4;j++){
      float r[8];
      #pragma unroll
      for(int t=0;t<8;t++) r[t]=a1[j][t]/(ls1[j]+1e-16f);
      f32x4 o1={r[0],r[1],r[2],r[3]}, o2={r[4],r[5],r[6],r[7]};
      *(f32x4*)(agg+(size_t)(base+j)*64+h*8)=o1;
      *(f32x4*)(agg+(size_t)(base+j)*64+h*8+4)=o2;
    }
  }
}

// ---------------- jumping-knowledge 5x5 attention, one wave per node
__global__ __launch_bounds__(256) void k_jk(const f16_t* __restrict__ qkv,float* __restrict__ osum,int n_nodes){
  int wave=threadIdx.x>>6, lane=threadIdx.x&63;
  int n=blockIdx.x*4+wave;
  if(n>=n_nodes) return;
  float q[5],k[5],v[5];
  #pragma unroll
  for(int s=0;s<5;s++){
    const f16_t* p=qkv+((size_t)s*n_nodes+n)*192;
    q[s]=(float)p[lane]; k[s]=(float)p[64+lane]; v[s]=(float)p[128+lane];
  }
  float sc[5][5];
  #pragma unroll
  for(int s=0;s<5;s++)
    #pragma unroll
    for(int t=0;t<5;t++){
      float x=q[s]*k[t];
      x+=__shfl_xor(x,1); x+=__shfl_xor(x,2); x+=__shfl_xor(x,4);
      sc[s][t]=x*0.3535533905932738f;
    }
  float os=0.f;
  #pragma unroll
  for(int s=0;s<5;s++){
    float m=sc[s][0];
    #pragma unroll
    for(int t=1;t<5;t++) m=fmaxf(m,sc[s][t]);
    float den=0.f, acc=0.f;
    #pragma unroll
    for(int t=0;t<5;t++){ float e=__expf(sc[s][t]-m); den+=e; acc+=e*v[t]; }
    os+=acc/den;
  }
  osum[(size_t)n*64+lane]=os;
}

// ---------------- MLP head ----------------
struct MlpArgs{ const float *w0,*b0,*w1,*b1,*w2,*b2,*w3,*b3,*w4,*b4,*w5,*b5; };
__global__ __launch_bounds__(256) void k_mlp(const float* __restrict__ in,MlpArgs ma,float* __restrict__ out,int N){
  __shared__ float sw0[2048],sb0[32],sw1[512],sb1[16],sw2[128],sb2[8],sw3[32],sb3[4],sw4[8],sb4[2],sw5[2],sb5[1];
  for(int i=threadIdx.x;i<2048;i+=256) sw0[i]=ma.w0[i];
  for(int i=threadIdx.x;i<512;i+=256)  sw1[i]=ma.w1[i];
  if(threadIdx.x<128) sw2[threadIdx.x]=ma.w2[threadIdx.x];
  if(threadIdx.x<32){ sb0[threadIdx.x]=ma.b0[threadIdx.x]; sw3[threadIdx.x]=ma.w3[threadIdx.x]; }
  if(threadIdx.x<16) sb1[threadIdx.x]=ma.b1[threadIdx.x];
  if(threadIdx.x<8){ sb2[threadIdx.x]=ma.b2[threadIdx.x]; sw4[threadIdx.x]=ma.w4[threadIdx.x]; }
  if(threadIdx.x<4) sb3[threadIdx.x]=ma.b3[threadIdx.x];
  if(threadIdx.x<2){ sb4[threadIdx.x]=ma.b4[threadIdx.x]; sw5[threadIdx.x]=ma.w5[threadIdx.x]; }
  if(threadIdx.x==0) sb5[0]=ma.b5[0];
  __syncthreads();
  int n=blockIdx.x*256+threadIdx.x;
  if(n>=N) return;
  float a[64];
  const f32x4* p4=(const f32x4*)(in+(size_t)n*64);
  #pragma unroll
  for(int j=0;j<16;j++){ f32x4 t=p4[j]; a[4*j]=t[0]; a[4*j+1]=t[1]; a[4*j+2]=t[2]; a[4*j+3]=t[3]; }
  float h1[32];
  #pragma unroll
  for(int o=0;o<32;o++){ float s=sb0[o];
    #pragma unroll
    for(int c=0;c<64;c++) s+=a[c]*sw0[o*64+c];
    h1[o]=gelu_f(s); }
  float h2v[16];
  #pragma unroll
  for(int o=0;o<16;o++){ float s=sb1[o];
    #pragma unroll
    for(int c=0;c<32;c++) s+=h1[c]*sw1[o*32+c];
    h2v[o]=gelu_f(s); }
  float h3[8];
  #pragma unroll
  for(int o=0;o<8;o++){ float s=sb2[o];
    #pragma unroll
    for(int c=0;c<16;c++) s+=h2v[c]*sw2[o*16+c];
    h3[o]=gelu_f(s); }
  float h4[4];
  #pragma unroll
  for(int o=0;o<4;o++){ float s=sb3[o];
    #pragma unroll
    for(int c=0;c<8;c++) s+=h3[c]*sw3[o*8+c];
    h4[o]=gelu_f(s); }
  float h5[2];
  #pragma unroll
  for(int o=0;o<2;o++){ float s=sb4[o];
    #pragma unroll
    for(int c=0;c<4;c++) s+=h4[c]*sw4[o*4+c];
    h5[o]=gelu_f(s); }
  float r=sb5[0]+h5[0]*sw5[0]+h5[1]*sw5[1];
  out[n]=r;
}

// ================= host launcher =================
extern "C" void kernel_launch(void* const* d_in,const int* in_sizes,int n_in,
                              void* d_out,int out_size,void* d_ws,size_t ws_size,
                              hipStream_t stream){
  (void)in_sizes;(void)n_in;(void)out_size;(void)ws_size;
  const float* x_instr=(const float*)d_in[0];
  const float* x_var  =(const float*)d_in[1];
  const float* ba_i=(const float*)d_in[9];
  const float* skip_i=(const float*)d_in[10];
  const float* ba_v=(const float*)d_in[18];
  const float* skip_v=(const float*)d_in[19];
  const float* Wqkv=(const float*)d_in[29];
  const float* bqkv=(const float*)d_in[30];
  const float* Wo=(const float*)d_in[31];
  const float* bo=(const float*)d_in[32];
  const int* src_vv=(const int*)d_in[45];
  const int* dst_vv=(const int*)d_in[46];
  const int* src_vi=(const int*)d_in[47];
  const int* dst_vi=(const int*)d_in[48];
  const int* src_iv=(const int*)d_in[49];
  const int* dst_iv=(const int*)d_in[50];

  char* w=(char*)d_ws;
  auto alloc=[&](size_t b)->char*{ char* p=w; w+=(b+255)&~(size_t)255; return p; };
  // ---- fused CSR arrays (~12 MB) ----
  int* rp_all=(int*)alloc((size_t)(NT_N+1)*4);
  int* cnt_all=(int*)alloc((size_t)NT_N*4);
  int* cur_all=(int*)alloc((size_t)NT_N*4);
  int* bsum =(int*)alloc(640*4);
  int* boff =(int*)alloc(640*4);
  int* esrc_all=(int*)alloc((size_t)ET_N*4);
  int* rp_vv=rp_all;
  int* rp_iv=rp_all+NV_N;
  int* rp_vi=rp_all+2*NV_N;
  // ---- folded + pre-split weights (~400 KB) ----
  short* fwh_var=(short*)alloc(320*64*2);
  short* fwl_var=(short*)alloc(320*64*2);
  float* fwb_var=(float*)alloc(320*4);
  short* fwh_ins=(short*)alloc(192*64*2);
  short* fwl_ins=(short*)alloc(192*64*2);
  float* fwb_ins=(float*)alloc(192*4);
  short* wah_i=(short*)alloc(64*64*2);
  short* wal_i=(short*)alloc(64*64*2);
  short* wah_v=(short*)alloc(64*64*2);
  short* wal_v=(short*)alloc(64*64*2);
  short* qkvh=(short*)alloc(192*64*2);
  short* qkvl=(short*)alloc(192*64*2);
  short* woh=(short*)alloc(64*64*2);
  short* wol=(short*)alloc(64*64*2);
  // ---- persistent across phases: outs (f16, 21 MB) ----
  f16_t* outs=(f16_t*)alloc((size_t)5*NI_N*64*2);
  // ---- arena (140 MB), phase-overlaid ----
  char* arena=alloc((size_t)146800640);
  float*  xv      =(float*)(arena);                                // 33,554,432 B
  float*  xi      =(float*)(arena+33554432);                       //  8,388,608 B
  f16_t*  var_feat=(f16_t*)(arena+41943040);                       // 50,331,648 B (stride 192: q|k|v)
  f16_t*  ins_feat=(f16_t*)(arena+92274688);                       // 12,582,912 B (stride 192: q|k|v)
  float*  agg_v   =(float*)(arena+104857600);                      // 33,554,432 B
  float*  agg_i   =(float*)(arena+138412032);                      //  8,388,608 B
  // JK phase overlays:
  f16_t*  qkv   =(f16_t*)(arena);                                  // 62,914,560 B
  float*  osum  =agg_v;
  float*  out_jk=agg_i;

  // fused CSR build
  hipMemsetAsync(cnt_all,0,(size_t)NT_N*4,stream);
  k_hist3<<<ET_N/256,256,0,stream>>>(dst_vv,dst_iv,dst_vi,cnt_all);
  int nb=NT_N/512;   // 576
  k_scan1<<<nb,512,0,stream>>>(cnt_all,NT_N,rp_all,bsum);
  k_scan2<<<1,1024,0,stream>>>(bsum,boff,nb);
  k_scan3<<<nb,512,0,stream>>>(rp_all,boff,cur_all,NT_N,nb);
  for(int wdx=0;wdx<SC_WIN;wdx++){
    int dlo=wdx*(NT_N/SC_WIN), dhi=(wdx+1)*(NT_N/SC_WIN);
    k_scatter3w<<<ET_N/256,256,0,stream>>>(src_vv,dst_vv,src_iv,dst_iv,src_vi,dst_vi,cur_all,esrc_all,dlo,dhi);
  }

  hipMemcpyAsync(xi,x_instr,(size_t)NI_N*64*4,hipMemcpyDeviceToDevice,stream);
  hipMemcpyAsync(xv,x_var,(size_t)NV_N*64*4,hipMemcpyDeviceToDevice,stream);

  // one-time splits for JK weights
  k_split2<<<(192*64+255)/256,256,0,stream>>>(Wqkv,192*64,qkvh,qkvl);
  k_split2<<<(64*64+255)/256,256,0,stream>>>(Wo,64*64,woh,wol);

  FoldArgs fa;
  fa.Wk_i=(const float*)d_in[2]; fa.Wq_i=(const float*)d_in[3]; fa.Wv_i=(const float*)d_in[4];
  fa.bk_i=(const float*)d_in[6]; fa.bq_i=(const float*)d_in[7]; fa.bv_i=(const float*)d_in[8];
  fa.Wk_v=(const float*)d_in[11]; fa.Wq_v=(const float*)d_in[12]; fa.Wv_v=(const float*)d_in[13];
  fa.bk_v=(const float*)d_in[15]; fa.bq_v=(const float*)d_in[16]; fa.bv_v=(const float*)d_in[17];
  fa.arel_vv=(const float*)d_in[20]; fa.mrel_vv=(const float*)d_in[21]; fa.prel_vv=(const float*)d_in[22];
  fa.arel_vi=(const float*)d_in[23]; fa.mrel_vi=(const float*)d_in[24]; fa.prel_vi=(const float*)d_in[25];
  fa.arel_iv=(const float*)d_in[26]; fa.mrel_iv=(const float*)d_in[27]; fa.prel_iv=(const float*)d_in[28];
  fa.Wa_i=(const float*)d_in[5]; fa.Wa_v=(const float*)d_in[14];
  fa.fwh_var=fwh_var; fa.fwl_var=fwl_var; fa.fwh_ins=fwh_ins; fa.fwl_ins=fwl_ins;
  fa.wah_i=wah_i; fa.wal_i=wal_i; fa.wah_v=wah_v; fa.wal_v=wal_v;
  fa.fwb_var=fwb_var; fa.fwb_ins=fwb_ins;

  for(int l=0;l<6;l++){
    fa.l=l;
    k_fold<<<160,256,0,stream>>>(fa);
    // var pass 1: q | k_vv | v_vv (3 panels)
    k_gemm64p<float,f16_t><<<NV_N/64,256,0,stream>>>(xv,NV_N,fwh_var,fwl_var,fwb_var,1.0f,var_feat,192,0,3);
    // instr: q | k_iv | v_iv (3 panels)
    k_gemm64p<float,f16_t><<<NI_N/64,256,0,stream>>>(xi,NI_N,fwh_ins,fwl_ins,fwb_ins,1.0f,ins_feat,192,0,3);
    // var destinations: vv + iv fused
    k_edge_var<<<NV_N/16,256,0,stream>>>(rp_vv,rp_iv,esrc_all,var_feat,ins_feat,agg_v);
    // var pass 2: overwrite cols 64..191 with k_vi | v_vi (2 panels)
    k_gemm64p<float,f16_t><<<NV_N/64,256,0,stream>>>(xv,NV_N,fwh_var+192*64,fwl_var+192*64,fwb_var+192,1.0f,var_feat,192,64,2);
    // instr destinations: vi
    k_edge_ins<<<NI_N/16,256,0,stream>>>(rp_vi,esrc_all,ins_feat,var_feat,agg_i);
    // fused update (instr blocks then var blocks)
    k_update2<<<NI_N/64+NV_N/64,256,0,stream>>>(agg_i,agg_v,wah_i,wal_i,wah_v,wal_v,
        ba_i+l*64,ba_v+l*64,skip_i+l,skip_v+l,xi,xv,
        (l>0)?(outs+(size_t)(l-1)*NI_N*64):nullptr,NI_N/64);
  }

  // jumping knowledge + head
  k_gemm64p<f16_t,f16_t><<<5*NI_N/64,256,0,stream>>>(outs,5*NI_N,qkvh,qkvl,bqkv,1.0f,qkv,192,0,3);
  k_jk<<<NI_N/4,256,0,stream>>>(qkv,osum,NI_N);
  k_gemm64p<float,float><<<NI_N/64,256,0,stream>>>(osum,NI_N,woh,wol,bo,5.0f,out_jk,64,0,1);
  MlpArgs ma;
  ma.w0=(const float*)d_in[33]; ma.b0=(const float*)d_in[34];
  ma.w1=(const float*)d_in[35]; ma.b1=(const float*)d_in[36];
  ma.w2=(const float*)d_in[37]; ma.b2=(const float*)d_in[38];
  ma.w3=(const float*)d_in[39]; ma.b3=(const float*)d_in[40];
  ma.w4=(const float*)d_in[41]; ma.b4=(const float*)d_in[42];
  ma.w5=(const float*)d_in[43]; ma.b5=(const float*)d_in[44];
  k_mlp<<<NI_N/256,256,0,stream>>>(out_jk,ma,(float*)d_out,NI_N);
}

// Round 8
// 2392.371 us; speedup vs baseline: 1.3263x; 1.3263x over previous
//
#include <hip/hip_runtime.h>
#include <cmath>

typedef unsigned short bf16_t;                                  // raw bf16 bits
typedef _Float16 f16_t;                                         // IEEE fp16
typedef __attribute__((ext_vector_type(8))) short short8;       // MFMA A/B frag
typedef __attribute__((ext_vector_type(4))) float f32x4;        // MFMA C/D frag
typedef _Float16 h2 __attribute__((ext_vector_type(2)));
typedef _Float16 h8 __attribute__((ext_vector_type(8)));

#define NI_N 32768
#define NV_N 131072
#define E_VV 1048576
#define E_VI 524288
#define E_IV 524288
#define NT_N (NV_N+NV_N+NI_N)          // 294912 concatenated nodes (vv|iv|vi)
#define ET_N (E_VV+E_IV+E_VI)          // 2097152 concatenated edges
#define SC_WIN 8                        // scatter windows

#if __has_builtin(__builtin_amdgcn_fdot2)
#define FDOT2(a,b,c) __builtin_amdgcn_fdot2((a),(b),(c),false)
#else
#define FDOT2(a,b,c) ((float)(a)[0]*(float)(b)[0]+(float)(a)[1]*(float)(b)[1]+(c))
#endif

__device__ __forceinline__ float bf2f(bf16_t u){ return __builtin_bit_cast(float,((unsigned)u)<<16); }
__device__ __forceinline__ bf16_t f2bf(float f){
  unsigned u=__builtin_bit_cast(unsigned,f);
  return (bf16_t)((u+0x7fffu+((u>>16)&1u))>>16);
}
__device__ __forceinline__ float gelu_f(float x){ return 0.5f*x*(1.0f+erff(x*0.7071067811865476f)); }

// split f32 into hi/lo bf16
__device__ __forceinline__ void splitf(float v, short& hi, short& lo){
  bf16_t h=f2bf(v);
  hi=(short)h;
  lo=(short)f2bf(v-bf2f(h));
}
__device__ __forceinline__ float ldval(const float* p){ return *p; }
__device__ __forceinline__ float ldval(const f16_t* p){ return (float)*p; }
__device__ __forceinline__ void stval(float* p,float v){ *p=v; }
__device__ __forceinline__ void stval(f16_t* p,float v){ *p=(f16_t)v; }

// ---------------- fused CSR build over 3 concatenated edge types ----------------
__global__ __launch_bounds__(256) void k_hist3(const int* __restrict__ dvv,const int* __restrict__ div_,
    const int* __restrict__ dvi,int* __restrict__ cnt){
  int i=blockIdx.x*256+threadIdx.x;
  if(i<E_VV) atomicAdd(&cnt[dvv[i]],1);
  else if(i<E_VV+E_IV) atomicAdd(&cnt[NV_N+div_[i-E_VV]],1);
  else atomicAdd(&cnt[2*NV_N+dvi[i-E_VV-E_IV]],1);
}
__global__ __launch_bounds__(512) void k_scan1(const int* __restrict__ cnt,int N,int* __restrict__ rp,int* __restrict__ bsum){
  __shared__ int sh[512];
  int i=blockIdx.x*512+threadIdx.x;
  int v=(i<N)?cnt[i]:0;
  sh[threadIdx.x]=v; __syncthreads();
  for(int off=1;off<512;off<<=1){
    int t=(threadIdx.x>=(unsigned)off)?sh[threadIdx.x-off]:0; __syncthreads();
    sh[threadIdx.x]+=t; __syncthreads();
  }
  if(i<N) rp[i]=sh[threadIdx.x]-v;
  if(threadIdx.x==511) bsum[blockIdx.x]=sh[511];
}
__global__ __launch_bounds__(1024) void k_scan2(const int* __restrict__ bsum,int* __restrict__ boff,int nb){
  __shared__ int sh[1024];
  int t=threadIdx.x;
  int v=(t<nb)?bsum[t]:0;
  sh[t]=v; __syncthreads();
  for(int off=1;off<1024;off<<=1){
    int x=(t>=(unsigned)off)?sh[t-off]:0; __syncthreads();
    sh[t]+=x; __syncthreads();
  }
  if(t<nb) boff[t]=sh[t]-v;
  if(t==1023) boff[nb]=sh[1023];
}
__global__ __launch_bounds__(512) void k_scan3(int* __restrict__ rp,const int* __restrict__ boff,int* __restrict__ cur,int N,int nb){
  int i=blockIdx.x*512+threadIdx.x;
  if(i<N){ int v=rp[i]+boff[i>>9]; rp[i]=v; cur[i]=v; }
  if(i==0) rp[N]=boff[nb];
}
// windowed scatter: rp monotone => each window's writes land in a contiguous slice => L2 merges stores.
__global__ __launch_bounds__(256) void k_scatter3w(const int* __restrict__ svv,const int* __restrict__ dvv,
    const int* __restrict__ siv,const int* __restrict__ div_,
    const int* __restrict__ svi,const int* __restrict__ dvi,
    int* __restrict__ cur,int* __restrict__ esrc,int dlo,int dhi){
  int i=blockIdx.x*256+threadIdx.x;
  int d,s;
  if(i<E_VV){ d=dvv[i]; if(d<dlo||d>=dhi) return; s=svv[i]; }
  else if(i<E_VV+E_IV){ int j=i-E_VV; d=NV_N+div_[j]; if(d<dlo||d>=dhi) return; s=siv[j]; }
  else { int j=i-E_VV-E_IV; d=2*NV_N+dvi[j]; if(d<dlo||d>=dhi) return; s=svi[j]; }
  int p=atomicAdd(&cur[d],1); esrc[p]=s;
}

// ---------------- weight folding + pre-split to bf16 hi/lo planes ----------------
struct FoldArgs{
  const float *Wk_i,*Wq_i,*Wv_i,*bk_i,*bq_i,*bv_i;
  const float *Wk_v,*Wq_v,*Wv_v,*bk_v,*bq_v,*bv_v;
  const float *arel_vv,*mrel_vv,*prel_vv,*arel_vi,*mrel_vi,*prel_vi,*arel_iv,*mrel_iv,*prel_iv;
  const float *Wa_i,*Wa_v;
  short *fwh_var,*fwl_var,*fwh_ins,*fwl_ins,*wah_i,*wal_i,*wah_v,*wal_v;
  float *fwb_var,*fwb_ins;
  int l;
};
__global__ __launch_bounds__(256) void k_fold(FoldArgs fa){
  int gid=blockIdx.x*256+threadIdx.x;
  if(gid>=640*64) return;
  int r=gid>>6, c=gid&63;
  int l=fa.l;
  if(r>=512){
    int ro=r&63;
    const float* W=(r<576)?fa.Wa_i:fa.Wa_v;
    short *sh=(r<576)?fa.wah_i:fa.wah_v, *sl=(r<576)?fa.wal_i:fa.wal_v;
    short h,lo; splitf(W[l*4096+ro*64+c],h,lo);
    sh[ro*64+c]=h; sl[ro*64+c]=lo;
    return;
  }
  const float *W,*B,*rel=nullptr,*prl=nullptr;
  short *sh,*sl; float *fwb; int orow;
  if(r<320){
    sh=fa.fwh_var; sl=fa.fwl_var; fwb=fa.fwb_var; orow=r;
    if(r<64){ W=fa.Wq_v; B=fa.bq_v; }
    else if(r<128){ W=fa.Wk_v; B=fa.bk_v; rel=fa.arel_vv; prl=fa.prel_vv; }
    else if(r<192){ W=fa.Wv_v; B=fa.bv_v; rel=fa.mrel_vv; }
    else if(r<256){ W=fa.Wk_v; B=fa.bk_v; rel=fa.arel_vi; prl=fa.prel_vi; }
    else         { W=fa.Wv_v; B=fa.bv_v; rel=fa.mrel_vi; }
  }else{
    int rr=r-320; sh=fa.fwh_ins; sl=fa.fwl_ins; fwb=fa.fwb_ins; orow=rr;
    if(rr<64){ W=fa.Wq_i; B=fa.bq_i; }
    else if(rr<128){ W=fa.Wk_i; B=fa.bk_i; rel=fa.arel_iv; prl=fa.prel_iv; }
    else           { W=fa.Wv_i; B=fa.bv_i; rel=fa.mrel_iv; }
  }
  int ro=orow&63;
  float val,bval;
  if(!rel){
    val=W[l*4096+ro*64+c]; bval=B[l*64+ro];
  }else{
    int h=ro>>3, e=ro&7;
    float s=prl?prl[l*8+h]*0.3535533905932738f:1.0f;
    float acc=0.f,bacc=0.f;
    #pragma unroll
    for(int d=0;d<8;d++){
      float rv=rel[l*512+h*64+d*8+e];
      acc += W[l*4096+(h*8+d)*64+c]*rv;
      bacc+= B[l*64+h*8+d]*rv;
    }
    val=acc*s; bval=bacc*s;
  }
  short h2v,lo2; splitf(val,h2v,lo2);
  sh[orow*64+c]=h2v; sl[orow*64+c]=lo2;
  if(c==0) fwb[orow]=bval;
}

__global__ __launch_bounds__(256) void k_split2(const float* __restrict__ W,int n,short* __restrict__ hi,short* __restrict__ lo){
  int i=blockIdx.x*256+threadIdx.x;
  if(i<n){ short h,l2; splitf(W[i],h,l2); hi[i]=h; lo[i]=l2; }
}

// ---------------- split-bf16 K=64 MFMA GEMM, panel-looped (A read once) ----------------
template<typename AT, typename OT>
__global__ __launch_bounds__(256) void k_gemm64p(const AT* __restrict__ A,int N,
    const short* __restrict__ Bh,const short* __restrict__ Bl,
    const float* __restrict__ bias,float bias_scale,
    OT* __restrict__ out,int octot,int ocol0,int npanels)
{
  const int wave=threadIdx.x>>6, lane=threadIdx.x&63;
  const int m=lane&15, quad=lane>>4;
  const int row0=blockIdx.x*64+wave*16;
  if(row0>=N) return;
  const AT* ap=A+(size_t)(row0+m)*64+quad*8;
  short8 ahi[2], alo[2];
  #pragma unroll
  for(int kf=0;kf<2;kf++){
    short8 th,tl;
    #pragma unroll
    for(int j=0;j<8;j++){ short h,l2; splitf(ldval(&ap[kf*32+j]),h,l2); th[j]=h; tl[j]=l2; }
    ahi[kf]=th; alo[kf]=tl;
  }
  for(int pan=0;pan<npanels;pan++){
    int colbase=pan*64;
    short8 bhi[4][2], blo[4][2];
    #pragma unroll
    for(int ot=0;ot<4;ot++){
      size_t o=(size_t)(colbase+ot*16+m)*64+quad*8;
      #pragma unroll
      for(int kf=0;kf<2;kf++){
        bhi[ot][kf]=*(const short8*)(Bh+o+kf*32);
        blo[ot][kf]=*(const short8*)(Bl+o+kf*32);
      }
    }
    f32x4 acc[4];
    #pragma unroll
    for(int ot=0;ot<4;ot++){
      float bv=bias[colbase+ot*16+m]*bias_scale;
      acc[ot][0]=bv; acc[ot][1]=bv; acc[ot][2]=bv; acc[ot][3]=bv;
    }
    #pragma unroll
    for(int ot=0;ot<4;ot++){
      #pragma unroll
      for(int kf=0;kf<2;kf++){
        acc[ot]=__builtin_amdgcn_mfma_f32_16x16x32_bf16(alo[kf],bhi[ot][kf],acc[ot],0,0,0);
        acc[ot]=__builtin_amdgcn_mfma_f32_16x16x32_bf16(ahi[kf],blo[ot][kf],acc[ot],0,0,0);
        acc[ot]=__builtin_amdgcn_mfma_f32_16x16x32_bf16(ahi[kf],bhi[ot][kf],acc[ot],0,0,0);
      }
    }
    #pragma unroll
    for(int ot=0;ot<4;ot++){
      int col=ocol0+colbase+ot*16+m;
      #pragma unroll
      for(int r=0;r<4;r++){
        int row=row0+quad*4+r;
        stval(&out[(size_t)row*octot+col],acc[ot][r]);
      }
    }
  }
}

// ---------------- fused per-layer update (instr blocks then var blocks) ----------------
__global__ __launch_bounds__(256) void k_update2(const float* __restrict__ agg_i,const float* __restrict__ agg_v,
    const short* __restrict__ wah_i,const short* __restrict__ wal_i,
    const short* __restrict__ wah_v,const short* __restrict__ wal_v,
    const float* __restrict__ ba_i,const float* __restrict__ ba_v,
    const float* __restrict__ skip_i,const float* __restrict__ skip_v,
    float* __restrict__ x_i,float* __restrict__ x_v,
    f16_t* __restrict__ outs,int nbi)
{
  const int wave=threadIdx.x>>6, lane=threadIdx.x&63;
  const int m=lane&15, quad=lane>>4;
  const bool isI=(int)blockIdx.x<nbi;
  const int row0=(isI?blockIdx.x:(blockIdx.x-nbi))*64+wave*16;
  const float* agg=isI?agg_i:agg_v;
  const short* Wah=isI?wah_i:wah_v;
  const short* Wal=isI?wal_i:wal_v;
  const float* ba=isI?ba_i:ba_v;
  const float* skip=isI?skip_i:skip_v;
  float* x=isI?x_i:x_v;
  f16_t* oo=isI?outs:nullptr;
  short8 bhi[4][2], blo[4][2];
  #pragma unroll
  for(int ot=0;ot<4;ot++){
    size_t o=(size_t)(ot*16+m)*64+quad*8;
    #pragma unroll
    for(int kf=0;kf<2;kf++){
      bhi[ot][kf]=*(const short8*)(Wah+o+kf*32);
      blo[ot][kf]=*(const short8*)(Wal+o+kf*32);
    }
  }
  const float* ap=agg+(size_t)(row0+m)*64+quad*8;
  short8 ahi[2], alo[2];
  #pragma unroll
  for(int kf=0;kf<2;kf++){
    short8 th,tl;
    #pragma unroll
    for(int j=0;j<8;j++){ short h,l2; splitf(gelu_f(ap[kf*32+j]),h,l2); th[j]=h; tl[j]=l2; }
    ahi[kf]=th; alo[kf]=tl;
  }
  f32x4 acc[4];
  #pragma unroll
  for(int ot=0;ot<4;ot++){
    float bv=ba[ot*16+m];
    acc[ot][0]=bv; acc[ot][1]=bv; acc[ot][2]=bv; acc[ot][3]=bv;
  }
  #pragma unroll
  for(int ot=0;ot<4;ot++){
    #pragma unroll
    for(int kf=0;kf<2;kf++){
      acc[ot]=__builtin_amdgcn_mfma_f32_16x16x32_bf16(alo[kf],bhi[ot][kf],acc[ot],0,0,0);
      acc[ot]=__builtin_amdgcn_mfma_f32_16x16x32_bf16(ahi[kf],blo[ot][kf],acc[ot],0,0,0);
      acc[ot]=__builtin_amdgcn_mfma_f32_16x16x32_bf16(ahi[kf],bhi[ot][kf],acc[ot],0,0,0);
    }
  }
  float s=1.0f/(1.0f+__expf(-skip[0]));
  #pragma unroll
  for(int ot=0;ot<4;ot++){
    int col=ot*16+m;
    #pragma unroll
    for(int r=0;r<4;r++){
      int row=row0+quad*4+r;
      size_t idx=(size_t)row*64+col;
      float xn=s*acc[ot][r]+(1.0f-s)*x[idx];
      x[idx]=xn;
      if(oo) oo[idx]=(f16_t)xn;
    }
  }
}

// ---------------- edge attention: one node/wave, lane=(edge_slot,head), sw-pipelined ----------------
// 8 edges/chunk; es prefetched 2 chunks ahead, k/v loads issued 1 chunk ahead.
// feature layout: stride 192 f16, k@64, v@128. rp values ABSOLUTE into esrc_all.
__device__ __forceinline__ void edge_agg8(const int* __restrict__ rp,const int* __restrict__ es,
    const f16_t* __restrict__ sf,int n,int eL,int h,const h2 q[4],
    float acc[8],float& ls)
{
  int b=__builtin_amdgcn_readfirstlane(rp[n]);
  int e=__builtin_amdgcn_readfirstlane(rp[n+1]);
  float m=-INFINITY; ls=0.f;
  #pragma unroll
  for(int t=0;t<8;t++) acc[t]=0.f;
  if(b>=e) return;
  int i=b;
  int ii=i+eL;
  int s0=es[ii<e?ii:e-1];
  const f16_t* r0=sf+(size_t)s0*192;
  h8 kk0=*(const h8*)(r0+64+h*8);
  h8 vv0=*(const h8*)(r0+128+h*8);
  int sB=s0; bool hasB=(i+8)<e;
  if(hasB){ int jj=i+8+eL; sB=es[jj<e?jj:e-1]; }
  for(;i<e;i+=8){
    // prefetch chunk i+16 source index
    int sC=sB; bool hasC=(i+16)<e;
    if(hasC){ int jj=i+16+eL; sC=es[jj<e?jj:e-1]; }
    // issue k/v loads for chunk i+8
    h8 kk1=kk0, vv1=vv0;
    if(hasB){
      const f16_t* r1=sf+(size_t)sB*192;
      kk1=*(const h8*)(r1+64+h*8);
      vv1=*(const h8*)(r1+128+h*8);
    }
    // compute chunk i
    h2 k0={kk0[0],kk0[1]},k1={kk0[2],kk0[3]},k2={kk0[4],kk0[5]},k3={kk0[6],kk0[7]};
    float pp=FDOT2(q[0],k0,0.f);
    pp=FDOT2(q[1],k1,pp);
    pp=FDOT2(q[2],k2,pp);
    pp=FDOT2(q[3],k3,pp);
    if(i+eL>=e) pp=-INFINITY;
    float pm=pp;
    pm=fmaxf(pm,__shfl_xor(pm,8));
    pm=fmaxf(pm,__shfl_xor(pm,16));
    pm=fmaxf(pm,__shfl_xor(pm,32));
    float mn=fmaxf(m,pm);
    float sc=__expf(m-mn);
    float w=__expf(pp-mn);
    ls=ls*sc+w;
    #pragma unroll
    for(int t=0;t<8;t++) acc[t]=acc[t]*sc+w*(float)vv0[t];
    m=mn;
    kk0=kk1; vv0=vv1; sB=sC; hasB=hasC;
  }
}
__device__ __forceinline__ void reduce_e(float acc[8],float& ls){
  #pragma unroll
  for(int msk=8;msk<64;msk<<=1){
    ls+=__shfl_xor(ls,msk);
    #pragma unroll
    for(int t=0;t<8;t++) acc[t]+=__shfl_xor(acc[t],msk);
  }
}

// var destinations: vv + iv fused
__global__ __launch_bounds__(256) void k_edge_var(const int* __restrict__ rp_vv,const int* __restrict__ rp_iv,
    const int* __restrict__ es,
    const f16_t* __restrict__ var_feat,const f16_t* __restrict__ ins_feat,
    float* __restrict__ agg,int ndst)
{
  int wave=threadIdx.x>>6, lane=threadIdx.x&63;
  int n=blockIdx.x*4+wave;
  if(n>=ndst) return;
  int eL=lane>>3, h=lane&7;
  h8 qq=*(const h8*)(var_feat+(size_t)n*192+h*8);
  h2 q[4]={{qq[0],qq[1]},{qq[2],qq[3]},{qq[4],qq[5]},{qq[6],qq[7]}};
  float a1[8],ls1,a2[8],ls2;
  edge_agg8(rp_vv,es,var_feat,n,eL,h,q,a1,ls1);
  edge_agg8(rp_iv,es,ins_feat,n,eL,h,q,a2,ls2);
  reduce_e(a1,ls1);
  reduce_e(a2,ls2);
  if(eL==0){
    float r[8];
    #pragma unroll
    for(int t=0;t<8;t++) r[t]=a1[t]/(ls1+1e-16f)+a2[t]/(ls2+1e-16f);
    f32x4 o1={r[0],r[1],r[2],r[3]}, o2={r[4],r[5],r[6],r[7]};
    *(f32x4*)(agg+(size_t)n*64+h*8)=o1;
    *(f32x4*)(agg+(size_t)n*64+h*8+4)=o2;
  }
}
// instr destinations: vi
__global__ __launch_bounds__(256) void k_edge_ins(const int* __restrict__ rp,const int* __restrict__ es,
    const f16_t* __restrict__ ins_feat,const f16_t* __restrict__ var_feat,
    float* __restrict__ agg,int ndst)
{
  int wave=threadIdx.x>>6, lane=threadIdx.x&63;
  int n=blockIdx.x*4+wave;
  if(n>=ndst) return;
  int eL=lane>>3, h=lane&7;
  h8 qq=*(const h8*)(ins_feat+(size_t)n*192+h*8);
  h2 q[4]={{qq[0],qq[1]},{qq[2],qq[3]},{qq[4],qq[5]},{qq[6],qq[7]}};
  float a1[8],ls1;
  edge_agg8(rp,es,var_feat,n,eL,h,q,a1,ls1);
  reduce_e(a1,ls1);
  if(eL==0){
    float r[8];
    #pragma unroll
    for(int t=0;t<8;t++) r[t]=a1[t]/(ls1+1e-16f);
    f32x4 o1={r[0],r[1],r[2],r[3]}, o2={r[4],r[5],r[6],r[7]};
    *(f32x4*)(agg+(size_t)n*64+h*8)=o1;
    *(f32x4*)(agg+(size_t)n*64+h*8+4)=o2;
  }
}

// ---------------- jumping-knowledge 5x5 attention, one wave per node
__global__ __launch_bounds__(256) void k_jk(const f16_t* __restrict__ qkv,float* __restrict__ osum,int n_nodes){
  int wave=threadIdx.x>>6, lane=threadIdx.x&63;
  int n=blockIdx.x*4+wave;
  if(n>=n_nodes) return;
  float q[5],k[5],v[5];
  #pragma unroll
  for(int s=0;s<5;s++){
    const f16_t* p=qkv+((size_t)s*n_nodes+n)*192;
    q[s]=(float)p[lane]; k[s]=(float)p[64+lane]; v[s]=(float)p[128+lane];
  }
  float sc[5][5];
  #pragma unroll
  for(int s=0;s<5;s++)
    #pragma unroll
    for(int t=0;t<5;t++){
      float x=q[s]*k[t];
      x+=__shfl_xor(x,1); x+=__shfl_xor(x,2); x+=__shfl_xor(x,4);
      sc[s][t]=x*0.3535533905932738f;
    }
  float os=0.f;
  #pragma unroll
  for(int s=0;s<5;s++){
    float m=sc[s][0];
    #pragma unroll
    for(int t=1;t<5;t++) m=fmaxf(m,sc[s][t]);
    float den=0.f, acc=0.f;
    #pragma unroll
    for(int t=0;t<5;t++){ float e=__expf(sc[s][t]-m); den+=e; acc+=e*v[t]; }
    os+=acc/den;
  }
  osum[(size_t)n*64+lane]=os;
}

// ---------------- MLP head ----------------
struct MlpArgs{ const float *w0,*b0,*w1,*b1,*w2,*b2,*w3,*b3,*w4,*b4,*w5,*b5; };
__global__ __launch_bounds__(256) void k_mlp(const float* __restrict__ in,MlpArgs ma,float* __restrict__ out,int N){
  __shared__ float sw0[2048],sb0[32],sw1[512],sb1[16],sw2[128],sb2[8],sw3[32],sb3[4],sw4[8],sb4[2],sw5[2],sb5[1];
  for(int i=threadIdx.x;i<2048;i+=256) sw0[i]=ma.w0[i];
  for(int i=threadIdx.x;i<512;i+=256)  sw1[i]=ma.w1[i];
  if(threadIdx.x<128) sw2[threadIdx.x]=ma.w2[threadIdx.x];
  if(threadIdx.x<32){ sb0[threadIdx.x]=ma.b0[threadIdx.x]; sw3[threadIdx.x]=ma.w3[threadIdx.x]; }
  if(threadIdx.x<16) sb1[threadIdx.x]=ma.b1[threadIdx.x];
  if(threadIdx.x<8){ sb2[threadIdx.x]=ma.b2[threadIdx.x]; sw4[threadIdx.x]=ma.w4[threadIdx.x]; }
  if(threadIdx.x<4) sb3[threadIdx.x]=ma.b3[threadIdx.x];
  if(threadIdx.x<2){ sb4[threadIdx.x]=ma.b4[threadIdx.x]; sw5[threadIdx.x]=ma.w5[threadIdx.x]; }
  if(threadIdx.x==0) sb5[0]=ma.b5[0];
  __syncthreads();
  int n=blockIdx.x*256+threadIdx.x;
  if(n>=N) return;
  float a[64];
  const f32x4* p4=(const f32x4*)(in+(size_t)n*64);
  #pragma unroll
  for(int j=0;j<16;j++){ f32x4 t=p4[j]; a[4*j]=t[0]; a[4*j+1]=t[1]; a[4*j+2]=t[2]; a[4*j+3]=t[3]; }
  float h1[32];
  #pragma unroll
  for(int o=0;o<32;o++){ float s=sb0[o];
    #pragma unroll
    for(int c=0;c<64;c++) s+=a[c]*sw0[o*64+c];
    h1[o]=gelu_f(s); }
  float h2v[16];
  #pragma unroll
  for(int o=0;o<16;o++){ float s=sb1[o];
    #pragma unroll
    for(int c=0;c<32;c++) s+=h1[c]*sw1[o*32+c];
    h2v[o]=gelu_f(s); }
  float h3[8];
  #pragma unroll
  for(int o=0;o<8;o++){ float s=sb2[o];
    #pragma unroll
    for(int c=0;c<16;c++) s+=h2v[c]*sw2[o*16+c];
    h3[o]=gelu_f(s); }
  float h4[4];
  #pragma unroll
  for(int o=0;o<4;o++){ float s=sb3[o];
    #pragma unroll
    for(int c=0;c<8;c++) s+=h3[c]*sw3[o*8+c];
    h4[o]=gelu_f(s); }
  float h5[2];
  #pragma unroll
  for(int o=0;o<2;o++){ float s=sb4[o];
    #pragma unroll
    for(int c=0;c<4;c++) s+=h4[c]*sw4[o*4+c];
    h5[o]=gelu_f(s); }
  float r=sb5[0]+h5[0]*sw5[0]+h5[1]*sw5[1];
  out[n]=r;
}

// ================= host launcher =================
extern "C" void kernel_launch(void* const* d_in,const int* in_sizes,int n_in,
                              void* d_out,int out_size,void* d_ws,size_t ws_size,
                              hipStream_t stream){
  (void)in_sizes;(void)n_in;(void)out_size;(void)ws_size;
  const float* x_instr=(const float*)d_in[0];
  const float* x_var  =(const float*)d_in[1];
  const float* ba_i=(const float*)d_in[9];
  const float* skip_i=(const float*)d_in[10];
  const float* ba_v=(const float*)d_in[18];
  const float* skip_v=(const float*)d_in[19];
  const float* Wqkv=(const float*)d_in[29];
  const float* bqkv=(const float*)d_in[30];
  const float* Wo=(const float*)d_in[31];
  const float* bo=(const float*)d_in[32];
  const int* src_vv=(const int*)d_in[45];
  const int* dst_vv=(const int*)d_in[46];
  const int* src_vi=(const int*)d_in[47];
  const int* dst_vi=(const int*)d_in[48];
  const int* src_iv=(const int*)d_in[49];
  const int* dst_iv=(const int*)d_in[50];

  char* w=(char*)d_ws;
  auto alloc=[&](size_t b)->char*{ char* p=w; w+=(b+255)&~(size_t)255; return p; };
  // ---- fused CSR arrays (~12 MB) ----
  int* rp_all=(int*)alloc((size_t)(NT_N+1)*4);
  int* cnt_all=(int*)alloc((size_t)NT_N*4);
  int* cur_all=(int*)alloc((size_t)NT_N*4);
  int* bsum =(int*)alloc(640*4);
  int* boff =(int*)alloc(640*4);
  int* esrc_all=(int*)alloc((size_t)ET_N*4);
  int* rp_vv=rp_all;
  int* rp_iv=rp_all+NV_N;
  int* rp_vi=rp_all+2*NV_N;
  // ---- folded + pre-split weights (~400 KB) ----
  short* fwh_var=(short*)alloc(320*64*2);
  short* fwl_var=(short*)alloc(320*64*2);
  float* fwb_var=(float*)alloc(320*4);
  short* fwh_ins=(short*)alloc(192*64*2);
  short* fwl_ins=(short*)alloc(192*64*2);
  float* fwb_ins=(float*)alloc(192*4);
  short* wah_i=(short*)alloc(64*64*2);
  short* wal_i=(short*)alloc(64*64*2);
  short* wah_v=(short*)alloc(64*64*2);
  short* wal_v=(short*)alloc(64*64*2);
  short* qkvh=(short*)alloc(192*64*2);
  short* qkvl=(short*)alloc(192*64*2);
  short* woh=(short*)alloc(64*64*2);
  short* wol=(short*)alloc(64*64*2);
  // ---- persistent across phases: outs (f16, 21 MB) ----
  f16_t* outs=(f16_t*)alloc((size_t)5*NI_N*64*2);
  // ---- arena (140 MB), phase-overlaid ----
  char* arena=alloc((size_t)146800640);
  float*  xv      =(float*)(arena);                                // 33,554,432 B
  float*  xi      =(float*)(arena+33554432);                       //  8,388,608 B
  f16_t*  var_feat=(f16_t*)(arena+41943040);                       // 50,331,648 B (stride 192: q|k|v)
  f16_t*  ins_feat=(f16_t*)(arena+92274688);                       // 12,582,912 B (stride 192: q|k|v)
  float*  agg_v   =(float*)(arena+104857600);                      // 33,554,432 B
  float*  agg_i   =(float*)(arena+138412032);                      //  8,388,608 B
  // JK phase overlays:
  f16_t*  qkv   =(f16_t*)(arena);                                  // 62,914,560 B
  float*  osum  =agg_v;
  float*  out_jk=agg_i;

  // fused CSR build
  hipMemsetAsync(cnt_all,0,(size_t)NT_N*4,stream);
  k_hist3<<<ET_N/256,256,0,stream>>>(dst_vv,dst_iv,dst_vi,cnt_all);
  int nb=NT_N/512;   // 576
  k_scan1<<<nb,512,0,stream>>>(cnt_all,NT_N,rp_all,bsum);
  k_scan2<<<1,1024,0,stream>>>(bsum,boff,nb);
  k_scan3<<<nb,512,0,stream>>>(rp_all,boff,cur_all,NT_N,nb);
  for(int wdx=0;wdx<SC_WIN;wdx++){
    int dlo=wdx*(NT_N/SC_WIN), dhi=(wdx+1)*(NT_N/SC_WIN);
    k_scatter3w<<<ET_N/256,256,0,stream>>>(src_vv,dst_vv,src_iv,dst_iv,src_vi,dst_vi,cur_all,esrc_all,dlo,dhi);
  }

  hipMemcpyAsync(xi,x_instr,(size_t)NI_N*64*4,hipMemcpyDeviceToDevice,stream);
  hipMemcpyAsync(xv,x_var,(size_t)NV_N*64*4,hipMemcpyDeviceToDevice,stream);

  // one-time splits for JK weights
  k_split2<<<(192*64+255)/256,256,0,stream>>>(Wqkv,192*64,qkvh,qkvl);
  k_split2<<<(64*64+255)/256,256,0,stream>>>(Wo,64*64,woh,wol);

  FoldArgs fa;
  fa.Wk_i=(const float*)d_in[2]; fa.Wq_i=(const float*)d_in[3]; fa.Wv_i=(const float*)d_in[4];
  fa.bk_i=(const float*)d_in[6]; fa.bq_i=(const float*)d_in[7]; fa.bv_i=(const float*)d_in[8];
  fa.Wk_v=(const float*)d_in[11]; fa.Wq_v=(const float*)d_in[12]; fa.Wv_v=(const float*)d_in[13];
  fa.bk_v=(const float*)d_in[15]; fa.bq_v=(const float*)d_in[16]; fa.bv_v=(const float*)d_in[17];
  fa.arel_vv=(const float*)d_in[20]; fa.mrel_vv=(const float*)d_in[21]; fa.prel_vv=(const float*)d_in[22];
  fa.arel_vi=(const float*)d_in[23]; fa.mrel_vi=(const float*)d_in[24]; fa.prel_vi=(const float*)d_in[25];
  fa.arel_iv=(const float*)d_in[26]; fa.mrel_iv=(const float*)d_in[27]; fa.mrel_iv=(const float*)d_in[27]; fa.prel_iv=(const float*)d_in[28];
  fa.Wa_i=(const float*)d_in[5]; fa.Wa_v=(const float*)d_in[14];
  fa.fwh_var=fwh_var; fa.fwl_var=fwl_var; fa.fwh_ins=fwh_ins; fa.fwl_ins=fwl_ins;
  fa.wah_i=wah_i; fa.wal_i=wal_i; fa.wah_v=wah_v; fa.wal_v=wal_v;
  fa.fwb_var=fwb_var; fa.fwb_ins=fwb_ins;

  for(int l=0;l<6;l++){
    fa.l=l;
    k_fold<<<160,256,0,stream>>>(fa);
    // var pass 1: q | k_vv | v_vv (3 panels)
    k_gemm64p<float,f16_t><<<NV_N/64,256,0,stream>>>(xv,NV_N,fwh_var,fwl_var,fwb_var,1.0f,var_feat,192,0,3);
    // instr: q | k_iv | v_iv (3 panels)
    k_gemm64p<float,f16_t><<<NI_N/64,256,0,stream>>>(xi,NI_N,fwh_ins,fwl_ins,fwb_ins,1.0f,ins_feat,192,0,3);
    // var destinations: vv + iv fused
    k_edge_var<<<NV_N/4,256,0,stream>>>(rp_vv,rp_iv,esrc_all,var_feat,ins_feat,agg_v,NV_N);
    // var pass 2: overwrite cols 64..191 with k_vi | v_vi (2 panels)
    k_gemm64p<float,f16_t><<<NV_N/64,256,0,stream>>>(xv,NV_N,fwh_var+192*64,fwl_var+192*64,fwb_var+192,1.0f,var_feat,192,64,2);
    // instr destinations: vi
    k_edge_ins<<<NI_N/4,256,0,stream>>>(rp_vi,esrc_all,ins_feat,var_feat,agg_i,NI_N);
    // fused update (instr blocks then var blocks)
    k_update2<<<NI_N/64+NV_N/64,256,0,stream>>>(agg_i,agg_v,wah_i,wal_i,wah_v,wal_v,
        ba_i+l*64,ba_v+l*64,skip_i+l,skip_v+l,xi,xv,
        (l>0)?(outs+(size_t)(l-1)*NI_N*64):nullptr,NI_N/64);
  }

  // jumping knowledge + head
  k_gemm64p<f16_t,f16_t><<<5*NI_N/64,256,0,stream>>>(outs,5*NI_N,qkvh,qkvl,bqkv,1.0f,qkv,192,0,3);
  k_jk<<<NI_N/4,256,0,stream>>>(qkv,osum,NI_N);
  k_gemm64p<float,float><<<NI_N/64,256,0,stream>>>(osum,NI_N,woh,wol,bo,5.0f,out_jk,64,0,1);
  MlpArgs ma;
  ma.w0=(const float*)d_in[33]; ma.b0=(const float*)d_in[34];
  ma.w1=(const float*)d_in[35]; ma.b1=(const float*)d_in[36];
  ma.w2=(const float*)d_in[37]; ma.b2=(const float*)d_in[38];
  ma.w3=(const float*)d_in[39]; ma.b3=(const float*)d_in[40];
  ma.w4=(const float*)d_in[41]; ma.b4=(const float*)d_in[42];
  ma.w5=(const float*)d_in[43]; ma.b5=(const float*)d_in[44];
  k_mlp<<<NI_N/256,256,0,stream>>>(out_jk,ma,(float*)d_out,NI_N);
}

// Round 9
// 2312.024 us; speedup vs baseline: 1.3724x; 1.0348x over previous
//
#include <hip/hip_runtime.h>
#include <cmath>

typedef unsigned short bf16_t;                                  // raw bf16 bits
typedef _Float16 f16_t;                                         // IEEE fp16
typedef __attribute__((ext_vector_type(8))) short short8;       // MFMA A/B frag
typedef __attribute__((ext_vector_type(4))) float f32x4;        // MFMA C/D frag

#define NI_N 32768
#define NV_N 131072
#define E_VV 1048576
#define E_VI 524288
#define E_IV 524288
#define NT_N (NV_N+NV_N+NI_N)          // 294912 concatenated nodes (vv|iv|vi)
#define ET_N (E_VV+E_IV+E_VI)          // 2097152 concatenated edges
#define SC_WIN 8                        // scatter windows

__device__ __forceinline__ float bf2f(bf16_t u){ return __builtin_bit_cast(float,((unsigned)u)<<16); }
__device__ __forceinline__ bf16_t f2bf(float f){
  unsigned u=__builtin_bit_cast(unsigned,f);
  return (bf16_t)((u+0x7fffu+((u>>16)&1u))>>16);
}
__device__ __forceinline__ float gelu_f(float x){ return 0.5f*x*(1.0f+erff(x*0.7071067811865476f)); }

// split f32 into hi/lo bf16
__device__ __forceinline__ void splitf(float v, short& hi, short& lo){
  bf16_t h=f2bf(v);
  hi=(short)h;
  lo=(short)f2bf(v-bf2f(h));
}
__device__ __forceinline__ float ldval(const float* p){ return *p; }
__device__ __forceinline__ float ldval(const f16_t* p){ return (float)*p; }
__device__ __forceinline__ void stval(float* p,float v){ *p=v; }
__device__ __forceinline__ void stval(f16_t* p,float v){ *p=(f16_t)v; }

// ---------------- fused CSR build over 3 concatenated edge types ----------------
__global__ __launch_bounds__(256) void k_hist3(const int* __restrict__ dvv,const int* __restrict__ div_,
    const int* __restrict__ dvi,int* __restrict__ cnt){
  int i=blockIdx.x*256+threadIdx.x;
  if(i<E_VV) atomicAdd(&cnt[dvv[i]],1);
  else if(i<E_VV+E_IV) atomicAdd(&cnt[NV_N+div_[i-E_VV]],1);
  else atomicAdd(&cnt[2*NV_N+dvi[i-E_VV-E_IV]],1);
}
__global__ __launch_bounds__(512) void k_scan1(const int* __restrict__ cnt,int N,int* __restrict__ rp,int* __restrict__ bsum){
  __shared__ int sh[512];
  int i=blockIdx.x*512+threadIdx.x;
  int v=(i<N)?cnt[i]:0;
  sh[threadIdx.x]=v; __syncthreads();
  for(int off=1;off<512;off<<=1){
    int t=(threadIdx.x>=(unsigned)off)?sh[threadIdx.x-off]:0; __syncthreads();
    sh[threadIdx.x]+=t; __syncthreads();
  }
  if(i<N) rp[i]=sh[threadIdx.x]-v;
  if(threadIdx.x==511) bsum[blockIdx.x]=sh[511];
}
__global__ __launch_bounds__(1024) void k_scan2(const int* __restrict__ bsum,int* __restrict__ boff,int nb){
  __shared__ int sh[1024];
  int t=threadIdx.x;
  int v=(t<nb)?bsum[t]:0;
  sh[t]=v; __syncthreads();
  for(int off=1;off<1024;off<<=1){
    int x=(t>=(unsigned)off)?sh[t-off]:0; __syncthreads();
    sh[t]+=x; __syncthreads();
  }
  if(t<nb) boff[t]=sh[t]-v;
  if(t==1023) boff[nb]=sh[1023];
}
__global__ __launch_bounds__(512) void k_scan3(int* __restrict__ rp,const int* __restrict__ boff,int* __restrict__ cur,int N,int nb){
  int i=blockIdx.x*512+threadIdx.x;
  if(i<N){ int v=rp[i]+boff[i>>9]; rp[i]=v; cur[i]=v; }
  if(i==0) rp[N]=boff[nb];
}
// windowed scatter: rp monotone => each window's writes land in a contiguous slice => L2 merges stores.
__global__ __launch_bounds__(256) void k_scatter3w(const int* __restrict__ svv,const int* __restrict__ dvv,
    const int* __restrict__ siv,const int* __restrict__ div_,
    const int* __restrict__ svi,const int* __restrict__ dvi,
    int* __restrict__ cur,int* __restrict__ esrc,int dlo,int dhi){
  int i=blockIdx.x*256+threadIdx.x;
  int d,s;
  if(i<E_VV){ d=dvv[i]; if(d<dlo||d>=dhi) return; s=svv[i]; }
  else if(i<E_VV+E_IV){ int j=i-E_VV; d=NV_N+div_[j]; if(d<dlo||d>=dhi) return; s=siv[j]; }
  else { int j=i-E_VV-E_IV; d=2*NV_N+dvi[j]; if(d<dlo||d>=dhi) return; s=svi[j]; }
  int p=atomicAdd(&cur[d],1); esrc[p]=s;
}

// ---------------- weight folding + pre-split to bf16 hi/lo planes ----------------
struct FoldArgs{
  const float *Wk_i,*Wq_i,*Wv_i,*bk_i,*bq_i,*bv_i;
  const float *Wk_v,*Wq_v,*Wv_v,*bk_v,*bq_v,*bv_v;
  const float *arel_vv,*mrel_vv,*prel_vv,*arel_vi,*mrel_vi,*prel_vi,*arel_iv,*mrel_iv,*prel_iv;
  const float *Wa_i,*Wa_v;
  short *fwh_var,*fwl_var,*fwh_ins,*fwl_ins,*wah_i,*wal_i,*wah_v,*wal_v;
  float *fwb_var,*fwb_ins;
  int l;
};
__global__ __launch_bounds__(256) void k_fold(FoldArgs fa){
  int gid=blockIdx.x*256+threadIdx.x;
  if(gid>=640*64) return;
  int r=gid>>6, c=gid&63;
  int l=fa.l;
  if(r>=512){
    int ro=r&63;
    const float* W=(r<576)?fa.Wa_i:fa.Wa_v;
    short *sh=(r<576)?fa.wah_i:fa.wah_v, *sl=(r<576)?fa.wal_i:fa.wal_v;
    short h,lo; splitf(W[l*4096+ro*64+c],h,lo);
    sh[ro*64+c]=h; sl[ro*64+c]=lo;
    return;
  }
  const float *W,*B,*rel=nullptr,*prl=nullptr;
  short *sh,*sl; float *fwb; int orow;
  if(r<320){
    sh=fa.fwh_var; sl=fa.fwl_var; fwb=fa.fwb_var; orow=r;
    if(r<64){ W=fa.Wq_v; B=fa.bq_v; }
    else if(r<128){ W=fa.Wk_v; B=fa.bk_v; rel=fa.arel_vv; prl=fa.prel_vv; }
    else if(r<192){ W=fa.Wv_v; B=fa.bv_v; rel=fa.mrel_vv; }
    else if(r<256){ W=fa.Wk_v; B=fa.bk_v; rel=fa.arel_vi; prl=fa.prel_vi; }
    else         { W=fa.Wv_v; B=fa.bv_v; rel=fa.mrel_vi; }
  }else{
    int rr=r-320; sh=fa.fwh_ins; sl=fa.fwl_ins; fwb=fa.fwb_ins; orow=rr;
    if(rr<64){ W=fa.Wq_i; B=fa.bq_i; }
    else if(rr<128){ W=fa.Wk_i; B=fa.bk_i; rel=fa.arel_iv; prl=fa.prel_iv; }
    else           { W=fa.Wv_i; B=fa.bv_i; rel=fa.mrel_iv; }
  }
  int ro=orow&63;
  float val,bval;
  if(!rel){
    val=W[l*4096+ro*64+c]; bval=B[l*64+ro];
  }else{
    int h=ro>>3, e=ro&7;
    float s=prl?prl[l*8+h]*0.3535533905932738f:1.0f;
    float acc=0.f,bacc=0.f;
    #pragma unroll
    for(int d=0;d<8;d++){
      float rv=rel[l*512+h*64+d*8+e];
      acc += W[l*4096+(h*8+d)*64+c]*rv;
      bacc+= B[l*64+h*8+d]*rv;
    }
    val=acc*s; bval=bacc*s;
  }
  short h2v,lo2; splitf(val,h2v,lo2);
  sh[orow*64+c]=h2v; sl[orow*64+c]=lo2;
  if(c==0) fwb[orow]=bval;
}

__global__ __launch_bounds__(256) void k_split2(const float* __restrict__ W,int n,short* __restrict__ hi,short* __restrict__ lo){
  int i=blockIdx.x*256+threadIdx.x;
  if(i<n){ short h,l2; splitf(W[i],h,l2); hi[i]=h; lo[i]=l2; }
}

// ---------------- split-bf16 K=64 MFMA GEMM, panel-looped (A read once) ----------------
template<typename AT, typename OT>
__global__ __launch_bounds__(256) void k_gemm64p(const AT* __restrict__ A,int N,
    const short* __restrict__ Bh,const short* __restrict__ Bl,
    const float* __restrict__ bias,float bias_scale,
    OT* __restrict__ out,int octot,int ocol0,int npanels)
{
  const int wave=threadIdx.x>>6, lane=threadIdx.x&63;
  const int m=lane&15, quad=lane>>4;
  const int row0=blockIdx.x*64+wave*16;
  if(row0>=N) return;
  const AT* ap=A+(size_t)(row0+m)*64+quad*8;
  short8 ahi[2], alo[2];
  #pragma unroll
  for(int kf=0;kf<2;kf++){
    short8 th,tl;
    #pragma unroll
    for(int j=0;j<8;j++){ short h,l2; splitf(ldval(&ap[kf*32+j]),h,l2); th[j]=h; tl[j]=l2; }
    ahi[kf]=th; alo[kf]=tl;
  }
  for(int pan=0;pan<npanels;pan++){
    int colbase=pan*64;
    short8 bhi[4][2], blo[4][2];
    #pragma unroll
    for(int ot=0;ot<4;ot++){
      size_t o=(size_t)(colbase+ot*16+m)*64+quad*8;
      #pragma unroll
      for(int kf=0;kf<2;kf++){
        bhi[ot][kf]=*(const short8*)(Bh+o+kf*32);
        blo[ot][kf]=*(const short8*)(Bl+o+kf*32);
      }
    }
    f32x4 acc[4];
    #pragma unroll
    for(int ot=0;ot<4;ot++){
      float bv=bias[colbase+ot*16+m]*bias_scale;
      acc[ot][0]=bv; acc[ot][1]=bv; acc[ot][2]=bv; acc[ot][3]=bv;
    }
    #pragma unroll
    for(int ot=0;ot<4;ot++){
      #pragma unroll
      for(int kf=0;kf<2;kf++){
        acc[ot]=__builtin_amdgcn_mfma_f32_16x16x32_bf16(alo[kf],bhi[ot][kf],acc[ot],0,0,0);
        acc[ot]=__builtin_amdgcn_mfma_f32_16x16x32_bf16(ahi[kf],blo[ot][kf],acc[ot],0,0,0);
        acc[ot]=__builtin_amdgcn_mfma_f32_16x16x32_bf16(ahi[kf],bhi[ot][kf],acc[ot],0,0,0);
      }
    }
    #pragma unroll
    for(int ot=0;ot<4;ot++){
      int col=ocol0+colbase+ot*16+m;
      #pragma unroll
      for(int r=0;r<4;r++){
        int row=row0+quad*4+r;
        stval(&out[(size_t)row*octot+col],acc[ot][r]);
      }
    }
  }
}

// ---------------- fused per-layer update (instr blocks then var blocks) ----------------
__global__ __launch_bounds__(256) void k_update2(const float* __restrict__ agg_i,const float* __restrict__ agg_v,
    const short* __restrict__ wah_i,const short* __restrict__ wal_i,
    const short* __restrict__ wah_v,const short* __restrict__ wal_v,
    const float* __restrict__ ba_i,const float* __restrict__ ba_v,
    const float* __restrict__ skip_i,const float* __restrict__ skip_v,
    float* __restrict__ x_i,float* __restrict__ x_v,
    f16_t* __restrict__ outs,int nbi)
{
  const int wave=threadIdx.x>>6, lane=threadIdx.x&63;
  const int m=lane&15, quad=lane>>4;
  const bool isI=(int)blockIdx.x<nbi;
  const int row0=(isI?blockIdx.x:(blockIdx.x-nbi))*64+wave*16;
  const float* agg=isI?agg_i:agg_v;
  const short* Wah=isI?wah_i:wah_v;
  const short* Wal=isI?wal_i:wal_v;
  const float* ba=isI?ba_i:ba_v;
  const float* skip=isI?skip_i:skip_v;
  float* x=isI?x_i:x_v;
  f16_t* oo=isI?outs:nullptr;
  short8 bhi[4][2], blo[4][2];
  #pragma unroll
  for(int ot=0;ot<4;ot++){
    size_t o=(size_t)(ot*16+m)*64+quad*8;
    #pragma unroll
    for(int kf=0;kf<2;kf++){
      bhi[ot][kf]=*(const short8*)(Wah+o+kf*32);
      blo[ot][kf]=*(const short8*)(Wal+o+kf*32);
    }
  }
  const float* ap=agg+(size_t)(row0+m)*64+quad*8;
  short8 ahi[2], alo[2];
  #pragma unroll
  for(int kf=0;kf<2;kf++){
    short8 th,tl;
    #pragma unroll
    for(int j=0;j<8;j++){ short h,l2; splitf(gelu_f(ap[kf*32+j]),h,l2); th[j]=h; tl[j]=l2; }
    ahi[kf]=th; alo[kf]=tl;
  }
  f32x4 acc[4];
  #pragma unroll
  for(int ot=0;ot<4;ot++){
    float bv=ba[ot*16+m];
    acc[ot][0]=bv; acc[ot][1]=bv; acc[ot][2]=bv; acc[ot][3]=bv;
  }
  #pragma unroll
  for(int ot=0;ot<4;ot++){
    #pragma unroll
    for(int kf=0;kf<2;kf++){
      acc[ot]=__builtin_amdgcn_mfma_f32_16x16x32_bf16(alo[kf],bhi[ot][kf],acc[ot],0,0,0);
      acc[ot]=__builtin_amdgcn_mfma_f32_16x16x32_bf16(ahi[kf],blo[ot][kf],acc[ot],0,0,0);
      acc[ot]=__builtin_amdgcn_mfma_f32_16x16x32_bf16(ahi[kf],bhi[ot][kf],acc[ot],0,0,0);
    }
  }
  float s=1.0f/(1.0f+__expf(-skip[0]));
  #pragma unroll
  for(int ot=0;ot<4;ot++){
    int col=ot*16+m;
    #pragma unroll
    for(int r=0;r<4;r++){
      int row=row0+quad*4+r;
      size_t idx=(size_t)row*64+col;
      float xn=s*acc[ot][r]+(1.0f-s)*x[idx];
      x[idx]=xn;
      if(oo) oo[idx]=(f16_t)xn;
    }
  }
}

// ---------------- edge attention: lane = feature dim, 4-edge unroll ----------------
// feature layout: stride 192 f16, k@64, v@128. rp values ABSOLUTE into esrc_all.
// lane = h*8+d; per-head dot via 3 shuffle-adds over d (xor 1,2,4).
__device__ __forceinline__ float edge_aggD(const int* __restrict__ rp,const int* __restrict__ es,
    const f16_t* __restrict__ sf,int n,int lane,float q)
{
  int b=__builtin_amdgcn_readfirstlane(rp[n]);
  int e=__builtin_amdgcn_readfirstlane(rp[n+1]);
  float m=-INFINITY, ls=0.f, acc=0.f;
  int i=b;
  for(; i+3<e; i+=4){
    int s0=__builtin_amdgcn_readfirstlane(es[i]);
    int s1=__builtin_amdgcn_readfirstlane(es[i+1]);
    int s2=__builtin_amdgcn_readfirstlane(es[i+2]);
    int s3=__builtin_amdgcn_readfirstlane(es[i+3]);
    const f16_t* r0=sf+(size_t)s0*192;
    const f16_t* r1=sf+(size_t)s1*192;
    const f16_t* r2=sf+(size_t)s2*192;
    const f16_t* r3=sf+(size_t)s3*192;
    float k0=(float)r0[64+lane], v0=(float)r0[128+lane];
    float k1=(float)r1[64+lane], v1=(float)r1[128+lane];
    float k2=(float)r2[64+lane], v2=(float)r2[128+lane];
    float k3=(float)r3[64+lane], v3=(float)r3[128+lane];
    float p0=q*k0, p1=q*k1, p2=q*k2, p3=q*k3;
    p0+=__shfl_xor(p0,1); p1+=__shfl_xor(p1,1); p2+=__shfl_xor(p2,1); p3+=__shfl_xor(p3,1);
    p0+=__shfl_xor(p0,2); p1+=__shfl_xor(p1,2); p2+=__shfl_xor(p2,2); p3+=__shfl_xor(p3,2);
    p0+=__shfl_xor(p0,4); p1+=__shfl_xor(p1,4); p2+=__shfl_xor(p2,4); p3+=__shfl_xor(p3,4);
    float mn=fmaxf(fmaxf(m,fmaxf(p0,p1)),fmaxf(p2,p3));
    float sc=__expf(m-mn);            // first iter: exp(-inf)=0
    float w0=__expf(p0-mn), w1=__expf(p1-mn), w2=__expf(p2-mn), w3=__expf(p3-mn);
    ls=ls*sc+((w0+w1)+(w2+w3));
    acc=acc*sc+((w0*v0+w1*v1)+(w2*v2+w3*v3));
    m=mn;
  }
  for(; i<e; i++){
    int s0=__builtin_amdgcn_readfirstlane(es[i]);
    const f16_t* r0=sf+(size_t)s0*192;
    float k0=(float)r0[64+lane], v0=(float)r0[128+lane];
    float p0=q*k0;
    p0+=__shfl_xor(p0,1); p0+=__shfl_xor(p0,2); p0+=__shfl_xor(p0,4);
    float mn=fmaxf(m,p0);
    float sc=__expf(m-mn), w0=__expf(p0-mn);
    ls=ls*sc+w0;
    acc=acc*sc+w0*v0;
    m=mn;
  }
  return acc/(ls+1e-16f);   // degree 0 -> 0, matches PyG semantics
}

// var destinations: vv + iv fused, one write
__global__ __launch_bounds__(256) void k_edge_var(const int* __restrict__ rp_vv,const int* __restrict__ rp_iv,
    const int* __restrict__ es,
    const f16_t* __restrict__ var_feat,const f16_t* __restrict__ ins_feat,
    float* __restrict__ agg,int ndst)
{
  int wave=threadIdx.x>>6, lane=threadIdx.x&63;
  int n=blockIdx.x*4+wave;
  if(n>=ndst) return;
  float q=(float)var_feat[(size_t)n*192+lane];
  float r1=edge_aggD(rp_vv,es,var_feat,n,lane,q);
  float r2=edge_aggD(rp_iv,es,ins_feat,n,lane,q);
  agg[(size_t)n*64+lane]=r1+r2;
}
// instr destinations: vi
__global__ __launch_bounds__(256) void k_edge_ins(const int* __restrict__ rp,const int* __restrict__ es,
    const f16_t* __restrict__ ins_feat,const f16_t* __restrict__ var_feat,
    float* __restrict__ agg,int ndst)
{
  int wave=threadIdx.x>>6, lane=threadIdx.x&63;
  int n=blockIdx.x*4+wave;
  if(n>=ndst) return;
  float q=(float)ins_feat[(size_t)n*192+lane];
  agg[(size_t)n*64+lane]=edge_aggD(rp,es,var_feat,n,lane,q);
}

// ---------------- jumping-knowledge 5x5 attention, one wave per node
__global__ __launch_bounds__(256) void k_jk(const f16_t* __restrict__ qkv,float* __restrict__ osum,int n_nodes){
  int wave=threadIdx.x>>6, lane=threadIdx.x&63;
  int n=blockIdx.x*4+wave;
  if(n>=n_nodes) return;
  float q[5],k[5],v[5];
  #pragma unroll
  for(int s=0;s<5;s++){
    const f16_t* p=qkv+((size_t)s*n_nodes+n)*192;
    q[s]=(float)p[lane]; k[s]=(float)p[64+lane]; v[s]=(float)p[128+lane];
  }
  float sc[5][5];
  #pragma unroll
  for(int s=0;s<5;s++)
    #pragma unroll
    for(int t=0;t<5;t++){
      float x=q[s]*k[t];
      x+=__shfl_xor(x,1); x+=__shfl_xor(x,2); x+=__shfl_xor(x,4);
      sc[s][t]=x*0.3535533905932738f;
    }
  float os=0.f;
  #pragma unroll
  for(int s=0;s<5;s++){
    float m=sc[s][0];
    #pragma unroll
    for(int t=1;t<5;t++) m=fmaxf(m,sc[s][t]);
    float den=0.f, acc=0.f;
    #pragma unroll
    for(int t=0;t<5;t++){ float e=__expf(sc[s][t]-m); den+=e; acc+=e*v[t]; }
    os+=acc/den;
  }
  osum[(size_t)n*64+lane]=os;
}

// ---------------- MLP head ----------------
struct MlpArgs{ const float *w0,*b0,*w1,*b1,*w2,*b2,*w3,*b3,*w4,*b4,*w5,*b5; };
__global__ __launch_bounds__(256) void k_mlp(const float* __restrict__ in,MlpArgs ma,float* __restrict__ out,int N){
  __shared__ float sw0[2048],sb0[32],sw1[512],sb1[16],sw2[128],sb2[8],sw3[32],sb3[4],sw4[8],sb4[2],sw5[2],sb5[1];
  for(int i=threadIdx.x;i<2048;i+=256) sw0[i]=ma.w0[i];
  for(int i=threadIdx.x;i<512;i+=256)  sw1[i]=ma.w1[i];
  if(threadIdx.x<128) sw2[threadIdx.x]=ma.w2[threadIdx.x];
  if(threadIdx.x<32){ sb0[threadIdx.x]=ma.b0[threadIdx.x]; sw3[threadIdx.x]=ma.w3[threadIdx.x]; }
  if(threadIdx.x<16) sb1[threadIdx.x]=ma.b1[threadIdx.x];
  if(threadIdx.x<8){ sb2[threadIdx.x]=ma.b2[threadIdx.x]; sw4[threadIdx.x]=ma.w4[threadIdx.x]; }
  if(threadIdx.x<4) sb3[threadIdx.x]=ma.b3[threadIdx.x];
  if(threadIdx.x<2){ sb4[threadIdx.x]=ma.b4[threadIdx.x]; sw5[threadIdx.x]=ma.w5[threadIdx.x]; }
  if(threadIdx.x==0) sb5[0]=ma.b5[0];
  __syncthreads();
  int n=blockIdx.x*256+threadIdx.x;
  if(n>=N) return;
  float a[64];
  const f32x4* p4=(const f32x4*)(in+(size_t)n*64);
  #pragma unroll
  for(int j=0;j<16;j++){ f32x4 t=p4[j]; a[4*j]=t[0]; a[4*j+1]=t[1]; a[4*j+2]=t[2]; a[4*j+3]=t[3]; }
  float h1[32];
  #pragma unroll
  for(int o=0;o<32;o++){ float s=sb0[o];
    #pragma unroll
    for(int c=0;c<64;c++) s+=a[c]*sw0[o*64+c];
    h1[o]=gelu_f(s); }
  float h2v[16];
  #pragma unroll
  for(int o=0;o<16;o++){ float s=sb1[o];
    #pragma unroll
    for(int c=0;c<32;c++) s+=h1[c]*sw1[o*32+c];
    h2v[o]=gelu_f(s); }
  float h3[8];
  #pragma unroll
  for(int o=0;o<8;o++){ float s=sb2[o];
    #pragma unroll
    for(int c=0;c<16;c++) s+=h2v[c]*sw2[o*16+c];
    h3[o]=gelu_f(s); }
  float h4[4];
  #pragma unroll
  for(int o=0;o<4;o++){ float s=sb3[o];
    #pragma unroll
    for(int c=0;c<8;c++) s+=h3[c]*sw3[o*8+c];
    h4[o]=gelu_f(s); }
  float h5[2];
  #pragma unroll
  for(int o=0;o<2;o++){ float s=sb4[o];
    #pragma unroll
    for(int c=0;c<4;c++) s+=h4[c]*sw4[o*4+c];
    h5[o]=gelu_f(s); }
  float r=sb5[0]+h5[0]*sw5[0]+h5[1]*sw5[1];
  out[n]=r;
}

// ================= host launcher =================
extern "C" void kernel_launch(void* const* d_in,const int* in_sizes,int n_in,
                              void* d_out,int out_size,void* d_ws,size_t ws_size,
                              hipStream_t stream){
  (void)in_sizes;(void)n_in;(void)out_size;(void)ws_size;
  const float* x_instr=(const float*)d_in[0];
  const float* x_var  =(const float*)d_in[1];
  const float* ba_i=(const float*)d_in[9];
  const float* skip_i=(const float*)d_in[10];
  const float* ba_v=(const float*)d_in[18];
  const float* skip_v=(const float*)d_in[19];
  const float* Wqkv=(const float*)d_in[29];
  const float* bqkv=(const float*)d_in[30];
  const float* Wo=(const float*)d_in[31];
  const float* bo=(const float*)d_in[32];
  const int* src_vv=(const int*)d_in[45];
  const int* dst_vv=(const int*)d_in[46];
  const int* src_vi=(const int*)d_in[47];
  const int* dst_vi=(const int*)d_in[48];
  const int* src_iv=(const int*)d_in[49];
  const int* dst_iv=(const int*)d_in[50];

  char* w=(char*)d_ws;
  auto alloc=[&](size_t b)->char*{ char* p=w; w+=(b+255)&~(size_t)255; return p; };
  // ---- fused CSR arrays (~12 MB) ----
  int* rp_all=(int*)alloc((size_t)(NT_N+1)*4);
  int* cnt_all=(int*)alloc((size_t)NT_N*4);
  int* cur_all=(int*)alloc((size_t)NT_N*4);
  int* bsum =(int*)alloc(640*4);
  int* boff =(int*)alloc(640*4);
  int* esrc_all=(int*)alloc((size_t)ET_N*4);
  int* rp_vv=rp_all;
  int* rp_iv=rp_all+NV_N;
  int* rp_vi=rp_all+2*NV_N;
  // ---- folded + pre-split weights (~400 KB) ----
  short* fwh_var=(short*)alloc(320*64*2);
  short* fwl_var=(short*)alloc(320*64*2);
  float* fwb_var=(float*)alloc(320*4);
  short* fwh_ins=(short*)alloc(192*64*2);
  short* fwl_ins=(short*)alloc(192*64*2);
  float* fwb_ins=(float*)alloc(192*4);
  short* wah_i=(short*)alloc(64*64*2);
  short* wal_i=(short*)alloc(64*64*2);
  short* wah_v=(short*)alloc(64*64*2);
  short* wal_v=(short*)alloc(64*64*2);
  short* qkvh=(short*)alloc(192*64*2);
  short* qkvl=(short*)alloc(192*64*2);
  short* woh=(short*)alloc(64*64*2);
  short* wol=(short*)alloc(64*64*2);
  // ---- persistent across phases: outs (f16, 21 MB) ----
  f16_t* outs=(f16_t*)alloc((size_t)5*NI_N*64*2);
  // ---- arena (140 MB), phase-overlaid ----
  char* arena=alloc((size_t)146800640);
  float*  xv      =(float*)(arena);                                // 33,554,432 B
  float*  xi      =(float*)(arena+33554432);                       //  8,388,608 B
  f16_t*  var_feat=(f16_t*)(arena+41943040);                       // 50,331,648 B (stride 192: q|k|v)
  f16_t*  ins_feat=(f16_t*)(arena+92274688);                       // 12,582,912 B (stride 192: q|k|v)
  float*  agg_v   =(float*)(arena+104857600);                      // 33,554,432 B
  float*  agg_i   =(float*)(arena+138412032);                      //  8,388,608 B
  // JK phase overlays:
  f16_t*  qkv   =(f16_t*)(arena);                                  // 62,914,560 B
  float*  osum  =agg_v;
  float*  out_jk=agg_i;

  // fused CSR build
  hipMemsetAsync(cnt_all,0,(size_t)NT_N*4,stream);
  k_hist3<<<ET_N/256,256,0,stream>>>(dst_vv,dst_iv,dst_vi,cnt_all);
  int nb=NT_N/512;   // 576
  k_scan1<<<nb,512,0,stream>>>(cnt_all,NT_N,rp_all,bsum);
  k_scan2<<<1,1024,0,stream>>>(bsum,boff,nb);
  k_scan3<<<nb,512,0,stream>>>(rp_all,boff,cur_all,NT_N,nb);
  for(int wdx=0;wdx<SC_WIN;wdx++){
    int dlo=wdx*(NT_N/SC_WIN), dhi=(wdx+1)*(NT_N/SC_WIN);
    k_scatter3w<<<ET_N/256,256,0,stream>>>(src_vv,dst_vv,src_iv,dst_iv,src_vi,dst_vi,cur_all,esrc_all,dlo,dhi);
  }

  hipMemcpyAsync(xi,x_instr,(size_t)NI_N*64*4,hipMemcpyDeviceToDevice,stream);
  hipMemcpyAsync(xv,x_var,(size_t)NV_N*64*4,hipMemcpyDeviceToDevice,stream);

  // one-time splits for JK weights
  k_split2<<<(192*64+255)/256,256,0,stream>>>(Wqkv,192*64,qkvh,qkvl);
  k_split2<<<(64*64+255)/256,256,0,stream>>>(Wo,64*64,woh,wol);

  FoldArgs fa;
  fa.Wk_i=(const float*)d_in[2]; fa.Wq_i=(const float*)d_in[3]; fa.Wv_i=(const float*)d_in[4];
  fa.bk_i=(const float*)d_in[6]; fa.bq_i=(const float*)d_in[7]; fa.bv_i=(const float*)d_in[8];
  fa.Wk_v=(const float*)d_in[11]; fa.Wq_v=(const float*)d_in[12]; fa.Wv_v=(const float*)d_in[13];
  fa.bk_v=(const float*)d_in[15]; fa.bq_v=(const float*)d_in[16]; fa.bv_v=(const float*)d_in[17];
  fa.arel_vv=(const float*)d_in[20]; fa.mrel_vv=(const float*)d_in[21]; fa.prel_vv=(const float*)d_in[22];
  fa.arel_vi=(const float*)d_in[23]; fa.mrel_vi=(const float*)d_in[24]; fa.prel_vi=(const float*)d_in[25];
  fa.arel_iv=(const float*)d_in[26]; fa.mrel_iv=(const float*)d_in[27]; fa.prel_iv=(const float*)d_in[28];
  fa.Wa_i=(const float*)d_in[5]; fa.Wa_v=(const float*)d_in[14];
  fa.fwh_var=fwh_var; fa.fwl_var=fwl_var; fa.fwh_ins=fwh_ins; fa.fwl_ins=fwl_ins;
  fa.wah_i=wah_i; fa.wal_i=wal_i; fa.wah_v=wah_v; fa.wal_v=wal_v;
  fa.fwb_var=fwb_var; fa.fwb_ins=fwb_ins;

  for(int l=0;l<6;l++){
    fa.l=l;
    k_fold<<<160,256,0,stream>>>(fa);
    // var pass 1: q | k_vv | v_vv (3 panels)
    k_gemm64p<float,f16_t><<<NV_N/64,256,0,stream>>>(xv,NV_N,fwh_var,fwl_var,fwb_var,1.0f,var_feat,192,0,3);
    // instr: q | k_iv | v_iv (3 panels)
    k_gemm64p<float,f16_t><<<NI_N/64,256,0,stream>>>(xi,NI_N,fwh_ins,fwl_ins,fwb_ins,1.0f,ins_feat,192,0,3);
    // var destinations: vv + iv fused
    k_edge_var<<<NV_N/4,256,0,stream>>>(rp_vv,rp_iv,esrc_all,var_feat,ins_feat,agg_v,NV_N);
    // var pass 2: overwrite cols 64..191 with k_vi | v_vi (2 panels)
    k_gemm64p<float,f16_t><<<NV_N/64,256,0,stream>>>(xv,NV_N,fwh_var+192*64,fwl_var+192*64,fwb_var+192,1.0f,var_feat,192,64,2);
    // instr destinations: vi
    k_edge_ins<<<NI_N/4,256,0,stream>>>(rp_vi,esrc_all,ins_feat,var_feat,agg_i,NI_N);
    // fused update (instr blocks then var blocks)
    k_update2<<<NI_N/64+NV_N/64,256,0,stream>>>(agg_i,agg_v,wah_i,wal_i,wah_v,wal_v,
        ba_i+l*64,ba_v+l*64,skip_i+l,skip_v+l,xi,xv,
        (l>0)?(outs+(size_t)(l-1)*NI_N*64):nullptr,NI_N/64);
  }

  // jumping knowledge + head
  k_gemm64p<f16_t,f16_t><<<5*NI_N/64,256,0,stream>>>(outs,5*NI_N,qkvh,qkvl,bqkv,1.0f,qkv,192,0,3);
  k_jk<<<NI_N/4,256,0,stream>>>(qkv,osum,NI_N);
  k_gemm64p<float,float><<<NI_N/64,256,0,stream>>>(osum,NI_N,woh,wol,bo,5.0f,out_jk,64,0,1);
  MlpArgs ma;
  ma.w0=(const float*)d_in[33]; ma.b0=(const float*)d_in[34];
  ma.w1=(const float*)d_in[35]; ma.b1=(const float*)d_in[36];
  ma.w2=(const float*)d_in[37]; ma.b2=(const float*)d_in[38];
  ma.w3=(const float*)d_in[39]; ma.b3=(const float*)d_in[40];
  ma.w4=(const float*)d_in[41]; ma.b4=(const float*)d_in[42];
  ma.w5=(const float*)d_in[43]; ma.b5=(const float*)d_in[44];
  k_mlp<<<NI_N/256,256,0,stream>>>(out_jk,ma,(float*)d_out,NI_N);
}

// Round 10
// 2225.534 us; speedup vs baseline: 1.4257x; 1.0389x over previous
//
#include <hip/hip_runtime.h>
#include <cmath>

typedef unsigned short bf16_t;                                  // raw bf16 bits
typedef _Float16 f16_t;                                         // IEEE fp16
typedef __attribute__((ext_vector_type(8))) short short8;       // MFMA A/B frag
typedef __attribute__((ext_vector_type(4))) float f32x4;        // MFMA C/D frag
typedef _Float16 h2v __attribute__((ext_vector_type(2)));       // packed f16 pair

#define NI_N 32768
#define NV_N 131072
#define E_VV 1048576
#define E_VI 524288
#define E_IV 524288
#define NT_N (NV_N+NV_N+NI_N)          // 294912 concatenated nodes (vv|iv|vi)
#define ET_N (E_VV+E_IV+E_VI)          // 2097152 concatenated edges
#define SC_WIN 8                        // scatter windows

__device__ __forceinline__ float bf2f(bf16_t u){ return __builtin_bit_cast(float,((unsigned)u)<<16); }
__device__ __forceinline__ bf16_t f2bf(float f){
  unsigned u=__builtin_bit_cast(unsigned,f);
  return (bf16_t)((u+0x7fffu+((u>>16)&1u))>>16);
}
__device__ __forceinline__ float gelu_f(float x){ return 0.5f*x*(1.0f+erff(x*0.7071067811865476f)); }

// split f32 into hi/lo bf16
__device__ __forceinline__ void splitf(float v, short& hi, short& lo){
  bf16_t h=f2bf(v);
  hi=(short)h;
  lo=(short)f2bf(v-bf2f(h));
}
__device__ __forceinline__ float ldval(const float* p){ return *p; }
__device__ __forceinline__ float ldval(const f16_t* p){ return (float)*p; }
__device__ __forceinline__ void stval(float* p,float v){ *p=v; }
__device__ __forceinline__ void stval(f16_t* p,float v){ *p=(f16_t)v; }
__device__ __forceinline__ h2v shxor(h2v a,int m){
  return __builtin_bit_cast(h2v,__shfl_xor(__builtin_bit_cast(int,a),m));
}

// ---------------- fused CSR build over 3 concatenated edge types ----------------
__global__ __launch_bounds__(256) void k_hist3(const int* __restrict__ dvv,const int* __restrict__ div_,
    const int* __restrict__ dvi,int* __restrict__ cnt){
  int i=blockIdx.x*256+threadIdx.x;
  if(i<E_VV) atomicAdd(&cnt[dvv[i]],1);
  else if(i<E_VV+E_IV) atomicAdd(&cnt[NV_N+div_[i-E_VV]],1);
  else atomicAdd(&cnt[2*NV_N+dvi[i-E_VV-E_IV]],1);
}
__global__ __launch_bounds__(512) void k_scan1(const int* __restrict__ cnt,int N,int* __restrict__ rp,int* __restrict__ bsum){
  __shared__ int sh[512];
  int i=blockIdx.x*512+threadIdx.x;
  int v=(i<N)?cnt[i]:0;
  sh[threadIdx.x]=v; __syncthreads();
  for(int off=1;off<512;off<<=1){
    int t=(threadIdx.x>=(unsigned)off)?sh[threadIdx.x-off]:0; __syncthreads();
    sh[threadIdx.x]+=t; __syncthreads();
  }
  if(i<N) rp[i]=sh[threadIdx.x]-v;
  if(threadIdx.x==511) bsum[blockIdx.x]=sh[511];
}
__global__ __launch_bounds__(1024) void k_scan2(const int* __restrict__ bsum,int* __restrict__ boff,int nb){
  __shared__ int sh[1024];
  int t=threadIdx.x;
  int v=(t<nb)?bsum[t]:0;
  sh[t]=v; __syncthreads();
  for(int off=1;off<1024;off<<=1){
    int x=(t>=(unsigned)off)?sh[t-off]:0; __syncthreads();
    sh[t]+=x; __syncthreads();
  }
  if(t<nb) boff[t]=sh[t]-v;
  if(t==1023) boff[nb]=sh[1023];
}
__global__ __launch_bounds__(512) void k_scan3(int* __restrict__ rp,const int* __restrict__ boff,int* __restrict__ cur,int N,int nb){
  int i=blockIdx.x*512+threadIdx.x;
  if(i<N){ int v=rp[i]+boff[i>>9]; rp[i]=v; cur[i]=v; }
  if(i==0) rp[N]=boff[nb];
}
__global__ __launch_bounds__(256) void k_scatter3w(const int* __restrict__ svv,const int* __restrict__ dvv,
    const int* __restrict__ siv,const int* __restrict__ div_,
    const int* __restrict__ svi,const int* __restrict__ dvi,
    int* __restrict__ cur,int* __restrict__ esrc,int dlo,int dhi){
  int i=blockIdx.x*256+threadIdx.x;
  int d,s;
  if(i<E_VV){ d=dvv[i]; if(d<dlo||d>=dhi) return; s=svv[i]; }
  else if(i<E_VV+E_IV){ int j=i-E_VV; d=NV_N+div_[j]; if(d<dlo||d>=dhi) return; s=siv[j]; }
  else { int j=i-E_VV-E_IV; d=2*NV_N+dvi[j]; if(d<dlo||d>=dhi) return; s=svi[j]; }
  int p=atomicAdd(&cur[d],1); esrc[p]=s;
}

// initial cast: f32 inputs -> f16 x buffers
__global__ __launch_bounds__(256) void k_castx(const float* __restrict__ xi_in,const float* __restrict__ xv_in,
    f16_t* __restrict__ xi,f16_t* __restrict__ xv){
  int i=blockIdx.x*256+threadIdx.x;
  if(i<NI_N*64) xi[i]=(f16_t)xi_in[i];
  else { int j=i-NI_N*64; xv[j]=(f16_t)xv_in[j]; }
}

// ---------------- weight folding + pre-split to bf16 hi/lo planes ----------------
struct FoldArgs{
  const float *Wk_i,*Wq_i,*Wv_i,*bk_i,*bq_i,*bv_i;
  const float *Wk_v,*Wq_v,*Wv_v,*bk_v,*bq_v,*bv_v;
  const float *arel_vv,*mrel_vv,*prel_vv,*arel_vi,*mrel_vi,*prel_vi,*arel_iv,*mrel_iv,*prel_iv;
  const float *Wa_i,*Wa_v;
  short *fwh_var,*fwl_var,*fwh_ins,*fwl_ins,*wah_i,*wal_i,*wah_v,*wal_v;
  float *fwb_var,*fwb_ins;
  int l;
};
__global__ __launch_bounds__(256) void k_fold(FoldArgs fa){
  int gid=blockIdx.x*256+threadIdx.x;
  if(gid>=640*64) return;
  int r=gid>>6, c=gid&63;
  int l=fa.l;
  if(r>=512){
    int ro=r&63;
    const float* W=(r<576)?fa.Wa_i:fa.Wa_v;
    short *sh=(r<576)?fa.wah_i:fa.wah_v, *sl=(r<576)?fa.wal_i:fa.wal_v;
    short h,lo; splitf(W[l*4096+ro*64+c],h,lo);
    sh[ro*64+c]=h; sl[ro*64+c]=lo;
    return;
  }
  const float *W,*B,*rel=nullptr,*prl=nullptr;
  short *sh,*sl; float *fwb; int orow;
  if(r<320){
    sh=fa.fwh_var; sl=fa.fwl_var; fwb=fa.fwb_var; orow=r;
    if(r<64){ W=fa.Wq_v; B=fa.bq_v; }
    else if(r<128){ W=fa.Wk_v; B=fa.bk_v; rel=fa.arel_vv; prl=fa.prel_vv; }
    else if(r<192){ W=fa.Wv_v; B=fa.bv_v; rel=fa.mrel_vv; }
    else if(r<256){ W=fa.Wk_v; B=fa.bk_v; rel=fa.arel_vi; prl=fa.prel_vi; }
    else         { W=fa.Wv_v; B=fa.bv_v; rel=fa.mrel_vi; }
  }else{
    int rr=r-320; sh=fa.fwh_ins; sl=fa.fwl_ins; fwb=fa.fwb_ins; orow=rr;
    if(rr<64){ W=fa.Wq_i; B=fa.bq_i; }
    else if(rr<128){ W=fa.Wk_i; B=fa.bk_i; rel=fa.arel_iv; prl=fa.prel_iv; }
    else           { W=fa.Wv_i; B=fa.bv_i; rel=fa.mrel_iv; }
  }
  int ro=orow&63;
  float val,bval;
  if(!rel){
    val=W[l*4096+ro*64+c]; bval=B[l*64+ro];
  }else{
    int h=ro>>3, e=ro&7;
    float s=prl?prl[l*8+h]*0.3535533905932738f:1.0f;
    float acc=0.f,bacc=0.f;
    #pragma unroll
    for(int d=0;d<8;d++){
      float rv=rel[l*512+h*64+d*8+e];
      acc += W[l*4096+(h*8+d)*64+c]*rv;
      bacc+= B[l*64+h*8+d]*rv;
    }
    val=acc*s; bval=bacc*s;
  }
  short h2q,lo2; splitf(val,h2q,lo2);
  sh[orow*64+c]=h2q; sl[orow*64+c]=lo2;
  if(c==0) fwb[orow]=bval;
}

__global__ __launch_bounds__(256) void k_split2(const float* __restrict__ W,int n,short* __restrict__ hi,short* __restrict__ lo){
  int i=blockIdx.x*256+threadIdx.x;
  if(i<n){ short h,l2; splitf(W[i],h,l2); hi[i]=h; lo[i]=l2; }
}

// ---------------- shared split-bf16 GEMM body ----------------
template<typename AT, typename OT>
__device__ __forceinline__ void gemm_body(const AT* __restrict__ A,int row0,
    const short* __restrict__ Bh,const short* __restrict__ Bl,
    const float* __restrict__ bias,float bias_scale,
    OT* __restrict__ out,int octot,int ocol0,int npanels,int m,int quad)
{
  const AT* ap=A+(size_t)(row0+m)*64+quad*8;
  short8 ahi[2], alo[2];
  #pragma unroll
  for(int kf=0;kf<2;kf++){
    short8 th,tl;
    #pragma unroll
    for(int j=0;j<8;j++){ short h,l2; splitf(ldval(&ap[kf*32+j]),h,l2); th[j]=h; tl[j]=l2; }
    ahi[kf]=th; alo[kf]=tl;
  }
  for(int pan=0;pan<npanels;pan++){
    int colbase=pan*64;
    short8 bhi[4][2], blo[4][2];
    #pragma unroll
    for(int ot=0;ot<4;ot++){
      size_t o=(size_t)(colbase+ot*16+m)*64+quad*8;
      #pragma unroll
      for(int kf=0;kf<2;kf++){
        bhi[ot][kf]=*(const short8*)(Bh+o+kf*32);
        blo[ot][kf]=*(const short8*)(Bl+o+kf*32);
      }
    }
    f32x4 acc[4];
    #pragma unroll
    for(int ot=0;ot<4;ot++){
      float bv=bias[colbase+ot*16+m]*bias_scale;
      acc[ot][0]=bv; acc[ot][1]=bv; acc[ot][2]=bv; acc[ot][3]=bv;
    }
    #pragma unroll
    for(int ot=0;ot<4;ot++){
      #pragma unroll
      for(int kf=0;kf<2;kf++){
        acc[ot]=__builtin_amdgcn_mfma_f32_16x16x32_bf16(alo[kf],bhi[ot][kf],acc[ot],0,0,0);
        acc[ot]=__builtin_amdgcn_mfma_f32_16x16x32_bf16(ahi[kf],blo[ot][kf],acc[ot],0,0,0);
        acc[ot]=__builtin_amdgcn_mfma_f32_16x16x32_bf16(ahi[kf],bhi[ot][kf],acc[ot],0,0,0);
      }
    }
    #pragma unroll
    for(int ot=0;ot<4;ot++){
      int col=ocol0+colbase+ot*16+m;
      #pragma unroll
      for(int r=0;r<4;r++){
        int row=row0+quad*4+r;
        stval(&out[(size_t)row*octot+col],acc[ot][r]);
      }
    }
  }
}

template<typename AT, typename OT>
__global__ __launch_bounds__(256) void k_gemm64p(const AT* __restrict__ A,int N,
    const short* __restrict__ Bh,const short* __restrict__ Bl,
    const float* __restrict__ bias,float bias_scale,
    OT* __restrict__ out,int octot,int ocol0,int npanels)
{
  const int wave=threadIdx.x>>6, lane=threadIdx.x&63;
  const int m=lane&15, quad=lane>>4;
  const int row0=blockIdx.x*64+wave*16;
  if(row0>=N) return;
  gemm_body<AT,OT>(A,row0,Bh,Bl,bias,bias_scale,out,octot,ocol0,npanels,m,quad);
}

// fused feature GEMM: blocks [0,nbv) var rows, [nbv, nbv+nbi) ins rows; 3 panels each
__global__ __launch_bounds__(256) void k_gemm_feat(const f16_t* __restrict__ Av,const f16_t* __restrict__ Ai,
    const short* __restrict__ Bvh,const short* __restrict__ Bvl,const float* __restrict__ biasv,
    const short* __restrict__ Bih,const short* __restrict__ Bil,const float* __restrict__ biasi,
    f16_t* __restrict__ outv,f16_t* __restrict__ outi,int nbv)
{
  const int wave=threadIdx.x>>6, lane=threadIdx.x&63;
  const int m=lane&15, quad=lane>>4;
  if((int)blockIdx.x<nbv){
    int row0=blockIdx.x*64+wave*16;
    gemm_body<f16_t,f16_t>(Av,row0,Bvh,Bvl,biasv,1.0f,outv,192,0,3,m,quad);
  }else{
    int row0=(blockIdx.x-nbv)*64+wave*16;
    gemm_body<f16_t,f16_t>(Ai,row0,Bih,Bil,biasi,1.0f,outi,192,0,3,m,quad);
  }
}

// ---------------- fused per-layer update (instr blocks then var blocks), x in f16 ----------------
__global__ __launch_bounds__(256) void k_update2(const float* __restrict__ agg_i,const float* __restrict__ agg_v,
    const short* __restrict__ wah_i,const short* __restrict__ wal_i,
    const short* __restrict__ wah_v,const short* __restrict__ wal_v,
    const float* __restrict__ ba_i,const float* __restrict__ ba_v,
    const float* __restrict__ skip_i,const float* __restrict__ skip_v,
    f16_t* __restrict__ x_i,f16_t* __restrict__ x_v,
    f16_t* __restrict__ outs,int nbi)
{
  const int wave=threadIdx.x>>6, lane=threadIdx.x&63;
  const int m=lane&15, quad=lane>>4;
  const bool isI=(int)blockIdx.x<nbi;
  const int row0=(isI?blockIdx.x:(blockIdx.x-nbi))*64+wave*16;
  const float* agg=isI?agg_i:agg_v;
  const short* Wah=isI?wah_i:wah_v;
  const short* Wal=isI?wal_i:wal_v;
  const float* ba=isI?ba_i:ba_v;
  const float* skip=isI?skip_i:skip_v;
  f16_t* x=isI?x_i:x_v;
  f16_t* oo=isI?outs:nullptr;
  short8 bhi[4][2], blo[4][2];
  #pragma unroll
  for(int ot=0;ot<4;ot++){
    size_t o=(size_t)(ot*16+m)*64+quad*8;
    #pragma unroll
    for(int kf=0;kf<2;kf++){
      bhi[ot][kf]=*(const short8*)(Wah+o+kf*32);
      blo[ot][kf]=*(const short8*)(Wal+o+kf*32);
    }
  }
  const float* ap=agg+(size_t)(row0+m)*64+quad*8;
  short8 ahi[2], alo[2];
  #pragma unroll
  for(int kf=0;kf<2;kf++){
    short8 th,tl;
    #pragma unroll
    for(int j=0;j<8;j++){ short h,l2; splitf(gelu_f(ap[kf*32+j]),h,l2); th[j]=h; tl[j]=l2; }
    ahi[kf]=th; alo[kf]=tl;
  }
  f32x4 acc[4];
  #pragma unroll
  for(int ot=0;ot<4;ot++){
    float bv=ba[ot*16+m];
    acc[ot][0]=bv; acc[ot][1]=bv; acc[ot][2]=bv; acc[ot][3]=bv;
  }
  #pragma unroll
  for(int ot=0;ot<4;ot++){
    #pragma unroll
    for(int kf=0;kf<2;kf++){
      acc[ot]=__builtin_amdgcn_mfma_f32_16x16x32_bf16(alo[kf],bhi[ot][kf],acc[ot],0,0,0);
      acc[ot]=__builtin_amdgcn_mfma_f32_16x16x32_bf16(ahi[kf],blo[ot][kf],acc[ot],0,0,0);
      acc[ot]=__builtin_amdgcn_mfma_f32_16x16x32_bf16(ahi[kf],bhi[ot][kf],acc[ot],0,0,0);
    }
  }
  float s=1.0f/(1.0f+__expf(-skip[0]));
  #pragma unroll
  for(int ot=0;ot<4;ot++){
    int col=ot*16+m;
    #pragma unroll
    for(int r=0;r<4;r++){
      int row=row0+quad*4+r;
      size_t idx=(size_t)row*64+col;
      float xn=s*acc[ot][r]+(1.0f-s)*(float)x[idx];
      f16_t xh=(f16_t)xn;
      x[idx]=xh;
      if(oo) oo[idx]=xh;
    }
  }
}

// ---------------- edge attention: lane = feature dim, 4-edge unroll, packed-f16 dots ----------------
// feature layout: stride 192 f16, k@64, v@128. rp values ABSOLUTE into esrc_all.
__device__ __forceinline__ float edge_aggD(const int* __restrict__ rp,const int* __restrict__ es,
    const f16_t* __restrict__ sf,int n,int lane,f16_t qh)
{
  int b=__builtin_amdgcn_readfirstlane(rp[n]);
  int e=__builtin_amdgcn_readfirstlane(rp[n+1]);
  float m=-INFINITY, ls=0.f, acc=0.f;
  h2v q2={qh,qh};
  int i=b;
  for(; i+3<e; i+=4){
    int s0=__builtin_amdgcn_readfirstlane(es[i]);
    int s1=__builtin_amdgcn_readfirstlane(es[i+1]);
    int s2=__builtin_amdgcn_readfirstlane(es[i+2]);
    int s3=__builtin_amdgcn_readfirstlane(es[i+3]);
    const f16_t* r0=sf+(size_t)s0*192;
    const f16_t* r1=sf+(size_t)s1*192;
    const f16_t* r2=sf+(size_t)s2*192;
    const f16_t* r3=sf+(size_t)s3*192;
    f16_t k0=r0[64+lane], k1=r1[64+lane], k2=r2[64+lane], k3=r3[64+lane];
    float v0=(float)r0[128+lane], v1=(float)r1[128+lane];
    float v2=(float)r2[128+lane], v3=(float)r3[128+lane];
    h2v pa={k0,k1}; pa=q2*pa;
    h2v pb={k2,k3}; pb=q2*pb;
    pa=pa+shxor(pa,1); pb=pb+shxor(pb,1);
    pa=pa+shxor(pa,2); pb=pb+shxor(pb,2);
    pa=pa+shxor(pa,4); pb=pb+shxor(pb,4);
    float p0=(float)pa[0], p1=(float)pa[1], p2=(float)pb[0], p3=(float)pb[1];
    float mn=fmaxf(fmaxf(m,fmaxf(p0,p1)),fmaxf(p2,p3));
    float sc=__expf(m-mn);            // first iter: exp(-inf)=0
    float w0=__expf(p0-mn), w1=__expf(p1-mn), w2=__expf(p2-mn), w3=__expf(p3-mn);
    ls=ls*sc+((w0+w1)+(w2+w3));
    acc=acc*sc+((w0*v0+w1*v1)+(w2*v2+w3*v3));
    m=mn;
  }
  float qf=(float)qh;
  for(; i<e; i++){
    int s0=__builtin_amdgcn_readfirstlane(es[i]);
    const f16_t* r0=sf+(size_t)s0*192;
    float k0=(float)r0[64+lane], v0=(float)r0[128+lane];
    float p0=qf*k0;
    p0+=__shfl_xor(p0,1); p0+=__shfl_xor(p0,2); p0+=__shfl_xor(p0,4);
    float mn=fmaxf(m,p0);
    float sc=__expf(m-mn), w0=__expf(p0-mn);
    ls=ls*sc+w0;
    acc=acc*sc+w0*v0;
    m=mn;
  }
  return acc/(ls+1e-16f);   // degree 0 -> 0, matches PyG semantics
}

// var destinations: vv + iv fused, one write
__global__ __launch_bounds__(256) void k_edge_var(const int* __restrict__ rp_vv,const int* __restrict__ rp_iv,
    const int* __restrict__ es,
    const f16_t* __restrict__ var_feat,const f16_t* __restrict__ ins_feat,
    float* __restrict__ agg,int ndst)
{
  int wave=threadIdx.x>>6, lane=threadIdx.x&63;
  int n=blockIdx.x*4+wave;
  if(n>=ndst) return;
  f16_t qh=var_feat[(size_t)n*192+lane];
  float r1=edge_aggD(rp_vv,es,var_feat,n,lane,qh);
  float r2=edge_aggD(rp_iv,es,ins_feat,n,lane,qh);
  agg[(size_t)n*64+lane]=r1+r2;
}
// instr destinations: vi
__global__ __launch_bounds__(256) void k_edge_ins(const int* __restrict__ rp,const int* __restrict__ es,
    const f16_t* __restrict__ ins_feat,const f16_t* __restrict__ var_feat,
    float* __restrict__ agg,int ndst)
{
  int wave=threadIdx.x>>6, lane=threadIdx.x&63;
  int n=blockIdx.x*4+wave;
  if(n>=ndst) return;
  f16_t qh=ins_feat[(size_t)n*192+lane];
  agg[(size_t)n*64+lane]=edge_aggD(rp,es,var_feat,n,lane,qh);
}

// ---------------- jumping-knowledge 5x5 attention, one wave per node
__global__ __launch_bounds__(256) void k_jk(const f16_t* __restrict__ qkv,float* __restrict__ osum,int n_nodes){
  int wave=threadIdx.x>>6, lane=threadIdx.x&63;
  int n=blockIdx.x*4+wave;
  if(n>=n_nodes) return;
  float q[5],k[5],v[5];
  #pragma unroll
  for(int s=0;s<5;s++){
    const f16_t* p=qkv+((size_t)s*n_nodes+n)*192;
    q[s]=(float)p[lane]; k[s]=(float)p[64+lane]; v[s]=(float)p[128+lane];
  }
  float sc[5][5];
  #pragma unroll
  for(int s=0;s<5;s++)
    #pragma unroll
    for(int t=0;t<5;t++){
      float x=q[s]*k[t];
      x+=__shfl_xor(x,1); x+=__shfl_xor(x,2); x+=__shfl_xor(x,4);
      sc[s][t]=x*0.3535533905932738f;
    }
  float os=0.f;
  #pragma unroll
  for(int s=0;s<5;s++){
    float m=sc[s][0];
    #pragma unroll
    for(int t=1;t<5;t++) m=fmaxf(m,sc[s][t]);
    float den=0.f, acc=0.f;
    #pragma unroll
    for(int t=0;t<5;t++){ float e=__expf(sc[s][t]-m); den+=e; acc+=e*v[t]; }
    os+=acc/den;
  }
  osum[(size_t)n*64+lane]=os;
}

// ---------------- MLP head ----------------
struct MlpArgs{ const float *w0,*b0,*w1,*b1,*w2,*b2,*w3,*b3,*w4,*b4,*w5,*b5; };
__global__ __launch_bounds__(256) void k_mlp(const float* __restrict__ in,MlpArgs ma,float* __restrict__ out,int N){
  __shared__ float sw0[2048],sb0[32],sw1[512],sb1[16],sw2[128],sb2[8],sw3[32],sb3[4],sw4[8],sb4[2],sw5[2],sb5[1];
  for(int i=threadIdx.x;i<2048;i+=256) sw0[i]=ma.w0[i];
  for(int i=threadIdx.x;i<512;i+=256)  sw1[i]=ma.w1[i];
  if(threadIdx.x<128) sw2[threadIdx.x]=ma.w2[threadIdx.x];
  if(threadIdx.x<32){ sb0[threadIdx.x]=ma.b0[threadIdx.x]; sw3[threadIdx.x]=ma.w3[threadIdx.x]; }
  if(threadIdx.x<16) sb1[threadIdx.x]=ma.b1[threadIdx.x];
  if(threadIdx.x<8){ sb2[threadIdx.x]=ma.b2[threadIdx.x]; sw4[threadIdx.x]=ma.w4[threadIdx.x]; }
  if(threadIdx.x<4) sb3[threadIdx.x]=ma.b3[threadIdx.x];
  if(threadIdx.x<2){ sb4[threadIdx.x]=ma.b4[threadIdx.x]; sw5[threadIdx.x]=ma.w5[threadIdx.x]; }
  if(threadIdx.x==0) sb5[0]=ma.b5[0];
  __syncthreads();
  int n=blockIdx.x*256+threadIdx.x;
  if(n>=N) return;
  float a[64];
  const f32x4* p4=(const f32x4*)(in+(size_t)n*64);
  #pragma unroll
  for(int j=0;j<16;j++){ f32x4 t=p4[j]; a[4*j]=t[0]; a[4*j+1]=t[1]; a[4*j+2]=t[2]; a[4*j+3]=t[3]; }
  float h1[32];
  #pragma unroll
  for(int o=0;o<32;o++){ float s=sb0[o];
    #pragma unroll
    for(int c=0;c<64;c++) s+=a[c]*sw0[o*64+c];
    h1[o]=gelu_f(s); }
  float h2q[16];
  #pragma unroll
  for(int o=0;o<16;o++){ float s=sb1[o];
    #pragma unroll
    for(int c=0;c<32;c++) s+=h1[c]*sw1[o*32+c];
    h2q[o]=gelu_f(s); }
  float h3[8];
  #pragma unroll
  for(int o=0;o<8;o++){ float s=sb2[o];
    #pragma unroll
    for(int c=0;c<16;c++) s+=h2q[c]*sw2[o*16+c];
    h3[o]=gelu_f(s); }
  float h4[4];
  #pragma unroll
  for(int o=0;o<4;o++){ float s=sb3[o];
    #pragma unroll
    for(int c=0;c<8;c++) s+=h3[c]*sw3[o*8+c];
    h4[o]=gelu_f(s); }
  float h5[2];
  #pragma unroll
  for(int o=0;o<2;o++){ float s=sb4[o];
    #pragma unroll
    for(int c=0;c<4;c++) s+=h4[c]*sw4[o*4+c];
    h5[o]=gelu_f(s); }
  float r=sb5[0]+h5[0]*sw5[0]+h5[1]*sw5[1];
  out[n]=r;
}

// ================= host launcher =================
extern "C" void kernel_launch(void* const* d_in,const int* in_sizes,int n_in,
                              void* d_out,int out_size,void* d_ws,size_t ws_size,
                              hipStream_t stream){
  (void)in_sizes;(void)n_in;(void)out_size;(void)ws_size;
  const float* x_instr=(const float*)d_in[0];
  const float* x_var  =(const float*)d_in[1];
  const float* ba_i=(const float*)d_in[9];
  const float* skip_i=(const float*)d_in[10];
  const float* ba_v=(const float*)d_in[18];
  const float* skip_v=(const float*)d_in[19];
  const float* Wqkv=(const float*)d_in[29];
  const float* bqkv=(const float*)d_in[30];
  const float* Wo=(const float*)d_in[31];
  const float* bo=(const float*)d_in[32];
  const int* src_vv=(const int*)d_in[45];
  const int* dst_vv=(const int*)d_in[46];
  const int* src_vi=(const int*)d_in[47];
  const int* dst_vi=(const int*)d_in[48];
  const int* src_iv=(const int*)d_in[49];
  const int* dst_iv=(const int*)d_in[50];

  char* w=(char*)d_ws;
  auto alloc=[&](size_t b)->char*{ char* p=w; w+=(b+255)&~(size_t)255; return p; };
  // ---- fused CSR arrays (~12 MB) ----
  int* rp_all=(int*)alloc((size_t)(NT_N+1)*4);
  int* cnt_all=(int*)alloc((size_t)NT_N*4);
  int* cur_all=(int*)alloc((size_t)NT_N*4);
  int* bsum =(int*)alloc(640*4);
  int* boff =(int*)alloc(640*4);
  int* esrc_all=(int*)alloc((size_t)ET_N*4);
  int* rp_vv=rp_all;
  int* rp_iv=rp_all+NV_N;
  int* rp_vi=rp_all+2*NV_N;
  // ---- folded + pre-split weights (~400 KB) ----
  short* fwh_var=(short*)alloc(320*64*2);
  short* fwl_var=(short*)alloc(320*64*2);
  float* fwb_var=(float*)alloc(320*4);
  short* fwh_ins=(short*)alloc(192*64*2);
  short* fwl_ins=(short*)alloc(192*64*2);
  float* fwb_ins=(float*)alloc(192*4);
  short* wah_i=(short*)alloc(64*64*2);
  short* wal_i=(short*)alloc(64*64*2);
  short* wah_v=(short*)alloc(64*64*2);
  short* wal_v=(short*)alloc(64*64*2);
  short* qkvh=(short*)alloc(192*64*2);
  short* qkvl=(short*)alloc(192*64*2);
  short* woh=(short*)alloc(64*64*2);
  short* wol=(short*)alloc(64*64*2);
  // ---- persistent across phases: outs (f16, 21 MB) ----
  f16_t* outs=(f16_t*)alloc((size_t)5*NI_N*64*2);
  // ---- arena (140 MB), phase-overlaid ----
  char* arena=alloc((size_t)146800640);
  f16_t*  xv      =(f16_t*)(arena);                                // 16,777,216 B
  f16_t*  xi      =(f16_t*)(arena+16777216);                       //  4,194,304 B
  f16_t*  var_feat=(f16_t*)(arena+20971520);                       // 50,331,648 B (stride 192: q|k|v)
  f16_t*  ins_feat=(f16_t*)(arena+71303168);                       // 12,582,912 B (stride 192: q|k|v)
  float*  agg_v   =(float*)(arena+83886080);                       // 33,554,432 B
  float*  agg_i   =(float*)(arena+117440512);                      //  8,388,608 B
  // JK phase overlays (xv/xi/var_feat dead by then):
  f16_t*  qkv   =(f16_t*)(arena);                                  // 62,914,560 B
  float*  osum  =agg_v;
  float*  out_jk=agg_i;

  // fused CSR build
  hipMemsetAsync(cnt_all,0,(size_t)NT_N*4,stream);
  k_hist3<<<ET_N/256,256,0,stream>>>(dst_vv,dst_iv,dst_vi,cnt_all);
  int nb=NT_N/512;   // 576
  k_scan1<<<nb,512,0,stream>>>(cnt_all,NT_N,rp_all,bsum);
  k_scan2<<<1,1024,0,stream>>>(bsum,boff,nb);
  k_scan3<<<nb,512,0,stream>>>(rp_all,boff,cur_all,NT_N,nb);
  for(int wdx=0;wdx<SC_WIN;wdx++){
    int dlo=wdx*(NT_N/SC_WIN), dhi=(wdx+1)*(NT_N/SC_WIN);
    k_scatter3w<<<ET_N/256,256,0,stream>>>(src_vv,dst_vv,src_iv,dst_iv,src_vi,dst_vi,cur_all,esrc_all,dlo,dhi);
  }

  k_castx<<<(NI_N*64+NV_N*64)/256,256,0,stream>>>(x_instr,x_var,xi,xv);

  // one-time splits for JK weights
  k_split2<<<(192*64+255)/256,256,0,stream>>>(Wqkv,192*64,qkvh,qkvl);
  k_split2<<<(64*64+255)/256,256,0,stream>>>(Wo,64*64,woh,wol);

  FoldArgs fa;
  fa.Wk_i=(const float*)d_in[2]; fa.Wq_i=(const float*)d_in[3]; fa.Wv_i=(const float*)d_in[4];
  fa.bk_i=(const float*)d_in[6]; fa.bq_i=(const float*)d_in[7]; fa.bv_i=(const float*)d_in[8];
  fa.Wk_v=(const float*)d_in[11]; fa.Wq_v=(const float*)d_in[12]; fa.Wv_v=(const float*)d_in[13];
  fa.bk_v=(const float*)d_in[15]; fa.bq_v=(const float*)d_in[16]; fa.bv_v=(const float*)d_in[17];
  fa.arel_vv=(const float*)d_in[20]; fa.mrel_vv=(const float*)d_in[21]; fa.prel_vv=(const float*)d_in[22];
  fa.arel_vi=(const float*)d_in[23]; fa.mrel_vi=(const float*)d_in[24]; fa.prel_vi=(const float*)d_in[25];
  fa.arel_iv=(const float*)d_in[26]; fa.mrel_iv=(const float*)d_in[27]; fa.prel_iv=(const float*)d_in[28];
  fa.Wa_i=(const float*)d_in[5]; fa.Wa_v=(const float*)d_in[14];
  fa.fwh_var=fwh_var; fa.fwl_var=fwl_var; fa.fwh_ins=fwh_ins; fa.fwl_ins=fwl_ins;
  fa.wah_i=wah_i; fa.wal_i=wal_i; fa.wah_v=wah_v; fa.wal_v=wal_v;
  fa.fwb_var=fwb_var; fa.fwb_ins=fwb_ins;

  for(int l=0;l<6;l++){
    fa.l=l;
    k_fold<<<160,256,0,stream>>>(fa);
    // fused feature GEMM: var pass1 (q|k_vv|v_vv) + instr (q|k_iv|v_iv)
    k_gemm_feat<<<NV_N/64+NI_N/64,256,0,stream>>>(xv,xi,fwh_var,fwl_var,fwb_var,
        fwh_ins,fwl_ins,fwb_ins,var_feat,ins_feat,NV_N/64);
    // var destinations: vv + iv fused
    k_edge_var<<<NV_N/4,256,0,stream>>>(rp_vv,rp_iv,esrc_all,var_feat,ins_feat,agg_v,NV_N);
    // var pass 2: overwrite cols 64..191 with k_vi | v_vi (2 panels)
    k_gemm64p<f16_t,f16_t><<<NV_N/64,256,0,stream>>>(xv,NV_N,fwh_var+192*64,fwl_var+192*64,fwb_var+192,1.0f,var_feat,192,64,2);
    // instr destinations: vi
    k_edge_ins<<<NI_N/4,256,0,stream>>>(rp_vi,esrc_all,ins_feat,var_feat,agg_i,NI_N);
    // fused update (instr blocks then var blocks)
    k_update2<<<NI_N/64+NV_N/64,256,0,stream>>>(agg_i,agg_v,wah_i,wal_i,wah_v,wal_v,
        ba_i+l*64,ba_v+l*64,skip_i+l,skip_v+l,xi,xv,
        (l>0)?(outs+(size_t)(l-1)*NI_N*64):nullptr,NI_N/64);
  }

  // jumping knowledge + head
  k_gemm64p<f16_t,f16_t><<<5*NI_N/64,256,0,stream>>>(outs,5*NI_N,qkvh,qkvl,bqkv,1.0f,qkv,192,0,3);
  k_jk<<<NI_N/4,256,0,stream>>>(qkv,osum,NI_N);
  k_gemm64p<float,float><<<NI_N/64,256,0,stream>>>(osum,NI_N,woh,wol,bo,5.0f,out_jk,64,0,1);
  MlpArgs ma;
  ma.w0=(const float*)d_in[33]; ma.b0=(const float*)d_in[34];
  ma.w1=(const float*)d_in[35]; ma.b1=(const float*)d_in[36];
  ma.w2=(const float*)d_in[37]; ma.b2=(const float*)d_in[38];
  ma.w3=(const float*)d_in[39]; ma.b3=(const float*)d_in[40];
  ma.w4=(const float*)d_in[41]; ma.b4=(const float*)d_in[42];
  ma.w5=(const float*)d_in[43]; ma.b5=(const float*)d_in[44];
  k_mlp<<<NI_N/256,256,0,stream>>>(out_jk,ma,(float*)d_out,NI_N);
}

// Round 11
// 2111.241 us; speedup vs baseline: 1.5029x; 1.0541x over previous
//
#include <hip/hip_runtime.h>
#include <cmath>

typedef unsigned short bf16_t;                                  // raw bf16 bits
typedef _Float16 f16_t;                                         // IEEE fp16
typedef __attribute__((ext_vector_type(8))) short short8;       // MFMA A/B frag
typedef __attribute__((ext_vector_type(4))) float f32x4;        // MFMA C/D frag
typedef _Float16 h2v __attribute__((ext_vector_type(2)));       // packed f16 pair

#define NI_N 32768
#define NV_N 131072
#define E_VV 1048576
#define E_VI 524288
#define E_IV 524288
#define NT_N (NV_N+NV_N+NI_N)          // 294912 concatenated nodes (vv|iv|vi)
#define ET_N (E_VV+E_IV+E_VI)          // 2097152 concatenated edges
#define SC_WIN 8                        // scatter windows

__device__ __forceinline__ float bf2f(bf16_t u){ return __builtin_bit_cast(float,((unsigned)u)<<16); }
__device__ __forceinline__ bf16_t f2bf(float f){
  unsigned u=__builtin_bit_cast(unsigned,f);
  return (bf16_t)((u+0x7fffu+((u>>16)&1u))>>16);
}
__device__ __forceinline__ float gelu_f(float x){ return 0.5f*x*(1.0f+erff(x*0.7071067811865476f)); }

// split f32 into hi/lo bf16
__device__ __forceinline__ void splitf(float v, short& hi, short& lo){
  bf16_t h=f2bf(v);
  hi=(short)h;
  lo=(short)f2bf(v-bf2f(h));
}
__device__ __forceinline__ float ldval(const float* p){ return *p; }
__device__ __forceinline__ float ldval(const f16_t* p){ return (float)*p; }
__device__ __forceinline__ void stval(float* p,float v){ *p=v; }
__device__ __forceinline__ void stval(f16_t* p,float v){ *p=(f16_t)v; }
__device__ __forceinline__ h2v shxor(h2v a,int m){
  return __builtin_bit_cast(h2v,__shfl_xor(__builtin_bit_cast(int,a),m));
}

// ---------------- fused CSR build over 3 concatenated edge types ----------------
__global__ __launch_bounds__(256) void k_hist3(const int* __restrict__ dvv,const int* __restrict__ div_,
    const int* __restrict__ dvi,int* __restrict__ cnt){
  int i=blockIdx.x*256+threadIdx.x;
  if(i<E_VV) atomicAdd(&cnt[dvv[i]],1);
  else if(i<E_VV+E_IV) atomicAdd(&cnt[NV_N+div_[i-E_VV]],1);
  else atomicAdd(&cnt[2*NV_N+dvi[i-E_VV-E_IV]],1);
}
__global__ __launch_bounds__(512) void k_scan1(const int* __restrict__ cnt,int N,int* __restrict__ rp,int* __restrict__ bsum){
  __shared__ int sh[512];
  int i=blockIdx.x*512+threadIdx.x;
  int v=(i<N)?cnt[i]:0;
  sh[threadIdx.x]=v; __syncthreads();
  for(int off=1;off<512;off<<=1){
    int t=(threadIdx.x>=(unsigned)off)?sh[threadIdx.x-off]:0; __syncthreads();
    sh[threadIdx.x]+=t; __syncthreads();
  }
  if(i<N) rp[i]=sh[threadIdx.x]-v;
  if(threadIdx.x==511) bsum[blockIdx.x]=sh[511];
}
__global__ __launch_bounds__(1024) void k_scan2(const int* __restrict__ bsum,int* __restrict__ boff,int nb){
  __shared__ int sh[1024];
  int t=threadIdx.x;
  int v=(t<nb)?bsum[t]:0;
  sh[t]=v; __syncthreads();
  for(int off=1;off<1024;off<<=1){
    int x=(t>=(unsigned)off)?sh[t-off]:0; __syncthreads();
    sh[t]+=x; __syncthreads();
  }
  if(t<nb) boff[t]=sh[t]-v;
  if(t==1023) boff[nb]=sh[1023];
}
__global__ __launch_bounds__(512) void k_scan3(int* __restrict__ rp,const int* __restrict__ boff,int* __restrict__ cur,int N,int nb){
  int i=blockIdx.x*512+threadIdx.x;
  if(i<N){ int v=rp[i]+boff[i>>9]; rp[i]=v; cur[i]=v; }
  if(i==0) rp[N]=boff[nb];
}
__global__ __launch_bounds__(256) void k_scatter3w(const int* __restrict__ svv,const int* __restrict__ dvv,
    const int* __restrict__ siv,const int* __restrict__ div_,
    const int* __restrict__ svi,const int* __restrict__ dvi,
    int* __restrict__ cur,int* __restrict__ esrc,int dlo,int dhi){
  int i=blockIdx.x*256+threadIdx.x;
  int d,s;
  if(i<E_VV){ d=dvv[i]; if(d<dlo||d>=dhi) return; s=svv[i]; }
  else if(i<E_VV+E_IV){ int j=i-E_VV; d=NV_N+div_[j]; if(d<dlo||d>=dhi) return; s=siv[j]; }
  else { int j=i-E_VV-E_IV; d=2*NV_N+dvi[j]; if(d<dlo||d>=dhi) return; s=svi[j]; }
  int p=atomicAdd(&cur[d],1); esrc[p]=s;
}

// initial cast: f32 inputs -> f16 x buffers
__global__ __launch_bounds__(256) void k_castx(const float* __restrict__ xi_in,const float* __restrict__ xv_in,
    f16_t* __restrict__ xi,f16_t* __restrict__ xv){
  int i=blockIdx.x*256+threadIdx.x;
  if(i<NI_N*64) xi[i]=(f16_t)xi_in[i];
  else { int j=i-NI_N*64; xv[j]=(f16_t)xv_in[j]; }
}

// ---------------- weight folding for ALL 6 layers in one launch ----------------
// per-layer fw_var rows: [0,64)=q_v,[64,128)=k_vv,[128,192)=v_vv,[192,256)=k_vi,[256,320)=v_vi
// per-layer fw_ins rows: [0,64)=q_i,[64,128)=k_iv,[128,192)=v_iv ; rows 512..575=Wa_i, 576..639=Wa_v
struct FoldArgs{
  const float *Wk_i,*Wq_i,*Wv_i,*bk_i,*bq_i,*bv_i;
  const float *Wk_v,*Wq_v,*Wv_v,*bk_v,*bq_v,*bv_v;
  const float *arel_vv,*mrel_vv,*prel_vv,*arel_vi,*mrel_vi,*prel_vi,*arel_iv,*mrel_iv,*prel_iv;
  const float *Wa_i,*Wa_v;
  short *fwh_var,*fwl_var,*fwh_ins,*fwl_ins,*wah_i,*wal_i,*wah_v,*wal_v;
  float *fwb_var,*fwb_ins;
};
__global__ __launch_bounds__(256) void k_fold6(FoldArgs fa){
  int gid=blockIdx.x*256+threadIdx.x;
  if(gid>=6*640*64) return;
  int l=gid/(640*64);
  int rem=gid-l*640*64;
  int r=rem>>6, c=rem&63;
  if(r>=512){
    int ro=r&63;
    const float* W=(r<576)?fa.Wa_i:fa.Wa_v;
    short *sh=((r<576)?fa.wah_i:fa.wah_v)+l*4096, *sl=((r<576)?fa.wal_i:fa.wal_v)+l*4096;
    short h,lo; splitf(W[l*4096+ro*64+c],h,lo);
    sh[ro*64+c]=h; sl[ro*64+c]=lo;
    return;
  }
  const float *W,*B,*rel=nullptr,*prl=nullptr;
  short *sh,*sl; float *fwb; int orow;
  if(r<320){
    sh=fa.fwh_var+l*320*64; sl=fa.fwl_var+l*320*64; fwb=fa.fwb_var+l*320; orow=r;
    if(r<64){ W=fa.Wq_v; B=fa.bq_v; }
    else if(r<128){ W=fa.Wk_v; B=fa.bk_v; rel=fa.arel_vv; prl=fa.prel_vv; }
    else if(r<192){ W=fa.Wv_v; B=fa.bv_v; rel=fa.mrel_vv; }
    else if(r<256){ W=fa.Wk_v; B=fa.bk_v; rel=fa.arel_vi; prl=fa.prel_vi; }
    else         { W=fa.Wv_v; B=fa.bv_v; rel=fa.mrel_vi; }
  }else{
    int rr=r-320; sh=fa.fwh_ins+l*192*64; sl=fa.fwl_ins+l*192*64; fwb=fa.fwb_ins+l*192; orow=rr;
    if(rr<64){ W=fa.Wq_i; B=fa.bq_i; }
    else if(rr<128){ W=fa.Wk_i; B=fa.bk_i; rel=fa.arel_iv; prl=fa.prel_iv; }
    else           { W=fa.Wv_i; B=fa.bv_i; rel=fa.mrel_iv; }
  }
  int ro=orow&63;
  float val,bval;
  if(!rel){
    val=W[l*4096+ro*64+c]; bval=B[l*64+ro];
  }else{
    int h=ro>>3, e=ro&7;
    float s=prl?prl[l*8+h]*0.3535533905932738f:1.0f;
    float acc=0.f,bacc=0.f;
    #pragma unroll
    for(int d=0;d<8;d++){
      float rv=rel[l*512+h*64+d*8+e];
      acc += W[l*4096+(h*8+d)*64+c]*rv;
      bacc+= B[l*64+h*8+d]*rv;
    }
    val=acc*s; bval=bacc*s;
  }
  short h2q,lo2; splitf(val,h2q,lo2);
  sh[orow*64+c]=h2q; sl[orow*64+c]=lo2;
  if(c==0) fwb[orow]=bval;
}

__global__ __launch_bounds__(256) void k_split2(const float* __restrict__ W,int n,short* __restrict__ hi,short* __restrict__ lo){
  int i=blockIdx.x*256+threadIdx.x;
  if(i<n){ short h,l2; splitf(W[i],h,l2); hi[i]=h; lo[i]=l2; }
}

// ---------------- shared split-bf16 GEMM body ----------------
template<typename AT, typename OT>
__device__ __forceinline__ void gemm_body(const AT* __restrict__ A,int row0,
    const short* __restrict__ Bh,const short* __restrict__ Bl,
    const float* __restrict__ bias,float bias_scale,
    OT* __restrict__ out,int octot,int ocol0,int npanels,int m,int quad)
{
  const AT* ap=A+(size_t)(row0+m)*64+quad*8;
  short8 ahi[2], alo[2];
  #pragma unroll
  for(int kf=0;kf<2;kf++){
    short8 th,tl;
    #pragma unroll
    for(int j=0;j<8;j++){ short h,l2; splitf(ldval(&ap[kf*32+j]),h,l2); th[j]=h; tl[j]=l2; }
    ahi[kf]=th; alo[kf]=tl;
  }
  for(int pan=0;pan<npanels;pan++){
    int colbase=pan*64;
    short8 bhi[4][2], blo[4][2];
    #pragma unroll
    for(int ot=0;ot<4;ot++){
      size_t o=(size_t)(colbase+ot*16+m)*64+quad*8;
      #pragma unroll
      for(int kf=0;kf<2;kf++){
        bhi[ot][kf]=*(const short8*)(Bh+o+kf*32);
        blo[ot][kf]=*(const short8*)(Bl+o+kf*32);
      }
    }
    f32x4 acc[4];
    #pragma unroll
    for(int ot=0;ot<4;ot++){
      float bv=bias[colbase+ot*16+m]*bias_scale;
      acc[ot][0]=bv; acc[ot][1]=bv; acc[ot][2]=bv; acc[ot][3]=bv;
    }
    #pragma unroll
    for(int ot=0;ot<4;ot++){
      #pragma unroll
      for(int kf=0;kf<2;kf++){
        acc[ot]=__builtin_amdgcn_mfma_f32_16x16x32_bf16(alo[kf],bhi[ot][kf],acc[ot],0,0,0);
        acc[ot]=__builtin_amdgcn_mfma_f32_16x16x32_bf16(ahi[kf],blo[ot][kf],acc[ot],0,0,0);
        acc[ot]=__builtin_amdgcn_mfma_f32_16x16x32_bf16(ahi[kf],bhi[ot][kf],acc[ot],0,0,0);
      }
    }
    #pragma unroll
    for(int ot=0;ot<4;ot++){
      int col=ocol0+colbase+ot*16+m;
      #pragma unroll
      for(int r=0;r<4;r++){
        int row=row0+quad*4+r;
        stval(&out[(size_t)row*octot+col],acc[ot][r]);
      }
    }
  }
}

template<typename AT, typename OT>
__global__ __launch_bounds__(256) void k_gemm64p(const AT* __restrict__ A,int N,
    const short* __restrict__ Bh,const short* __restrict__ Bl,
    const float* __restrict__ bias,float bias_scale,
    OT* __restrict__ out,int octot,int ocol0,int npanels)
{
  const int wave=threadIdx.x>>6, lane=threadIdx.x&63;
  const int m=lane&15, quad=lane>>4;
  const int row0=blockIdx.x*64+wave*16;
  if(row0>=N) return;
  gemm_body<AT,OT>(A,row0,Bh,Bl,bias,bias_scale,out,octot,ocol0,npanels,m,quad);
}

// fused feature GEMM: blocks [0,nbv) var rows (5 panels, stride 320), rest ins rows (3 panels, 192)
__global__ __launch_bounds__(256) void k_gemm_feat(const f16_t* __restrict__ Av,const f16_t* __restrict__ Ai,
    const short* __restrict__ Bvh,const short* __restrict__ Bvl,const float* __restrict__ biasv,
    const short* __restrict__ Bih,const short* __restrict__ Bil,const float* __restrict__ biasi,
    f16_t* __restrict__ outv,f16_t* __restrict__ outi,int nbv)
{
  const int wave=threadIdx.x>>6, lane=threadIdx.x&63;
  const int m=lane&15, quad=lane>>4;
  if((int)blockIdx.x<nbv){
    int row0=blockIdx.x*64+wave*16;
    gemm_body<f16_t,f16_t>(Av,row0,Bvh,Bvl,biasv,1.0f,outv,320,0,5,m,quad);
  }else{
    int row0=(blockIdx.x-nbv)*64+wave*16;
    gemm_body<f16_t,f16_t>(Ai,row0,Bih,Bil,biasi,1.0f,outi,192,0,3,m,quad);
  }
}

// ---------------- fused per-layer update (instr blocks then var blocks), x/agg in f16 ----------------
__global__ __launch_bounds__(256) void k_update2(const f16_t* __restrict__ agg_i,const f16_t* __restrict__ agg_v,
    const short* __restrict__ wah_i,const short* __restrict__ wal_i,
    const short* __restrict__ wah_v,const short* __restrict__ wal_v,
    const float* __restrict__ ba_i,const float* __restrict__ ba_v,
    const float* __restrict__ skip_i,const float* __restrict__ skip_v,
    f16_t* __restrict__ x_i,f16_t* __restrict__ x_v,
    f16_t* __restrict__ outs,int nbi)
{
  const int wave=threadIdx.x>>6, lane=threadIdx.x&63;
  const int m=lane&15, quad=lane>>4;
  const bool isI=(int)blockIdx.x<nbi;
  const int row0=(isI?blockIdx.x:(blockIdx.x-nbi))*64+wave*16;
  const f16_t* agg=isI?agg_i:agg_v;
  const short* Wah=isI?wah_i:wah_v;
  const short* Wal=isI?wal_i:wal_v;
  const float* ba=isI?ba_i:ba_v;
  const float* skip=isI?skip_i:skip_v;
  f16_t* x=isI?x_i:x_v;
  f16_t* oo=isI?outs:nullptr;
  short8 bhi[4][2], blo[4][2];
  #pragma unroll
  for(int ot=0;ot<4;ot++){
    size_t o=(size_t)(ot*16+m)*64+quad*8;
    #pragma unroll
    for(int kf=0;kf<2;kf++){
      bhi[ot][kf]=*(const short8*)(Wah+o+kf*32);
      blo[ot][kf]=*(const short8*)(Wal+o+kf*32);
    }
  }
  const f16_t* ap=agg+(size_t)(row0+m)*64+quad*8;
  short8 ahi[2], alo[2];
  #pragma unroll
  for(int kf=0;kf<2;kf++){
    short8 th,tl;
    #pragma unroll
    for(int j=0;j<8;j++){ short h,l2; splitf(gelu_f((float)ap[kf*32+j]),h,l2); th[j]=h; tl[j]=l2; }
    ahi[kf]=th; alo[kf]=tl;
  }
  f32x4 acc[4];
  #pragma unroll
  for(int ot=0;ot<4;ot++){
    float bv=ba[ot*16+m];
    acc[ot][0]=bv; acc[ot][1]=bv; acc[ot][2]=bv; acc[ot][3]=bv;
  }
  #pragma unroll
  for(int ot=0;ot<4;ot++){
    #pragma unroll
    for(int kf=0;kf<2;kf++){
      acc[ot]=__builtin_amdgcn_mfma_f32_16x16x32_bf16(alo[kf],bhi[ot][kf],acc[ot],0,0,0);
      acc[ot]=__builtin_amdgcn_mfma_f32_16x16x32_bf16(ahi[kf],blo[ot][kf],acc[ot],0,0,0);
      acc[ot]=__builtin_amdgcn_mfma_f32_16x16x32_bf16(ahi[kf],bhi[ot][kf],acc[ot],0,0,0);
    }
  }
  float s=1.0f/(1.0f+__expf(-skip[0]));
  #pragma unroll
  for(int ot=0;ot<4;ot++){
    int col=ot*16+m;
    #pragma unroll
    for(int r=0;r<4;r++){
      int row=row0+quad*4+r;
      size_t idx=(size_t)row*64+col;
      float xn=s*acc[ot][r]+(1.0f-s)*(float)x[idx];
      f16_t xh=(f16_t)xn;
      x[idx]=xh;
      if(oo) oo[idx]=xh;
    }
  }
}

// ---------------- edge attention: lane = feature dim, 4-edge unroll, packed-f16 dots ----------------
// rp values ABSOLUTE into esrc_all. stride/koff/voff runtime (var_feat stride 320, ins_feat 192).
__device__ __forceinline__ float edge_aggD(const int* __restrict__ rp,const int* __restrict__ es,
    const f16_t* __restrict__ sf,int stride,int koff,int voff,int n,int lane,f16_t qh)
{
  int b=__builtin_amdgcn_readfirstlane(rp[n]);
  int e=__builtin_amdgcn_readfirstlane(rp[n+1]);
  float m=-INFINITY, ls=0.f, acc=0.f;
  h2v q2={qh,qh};
  int i=b;
  for(; i+3<e; i+=4){
    int s0=__builtin_amdgcn_readfirstlane(es[i]);
    int s1=__builtin_amdgcn_readfirstlane(es[i+1]);
    int s2=__builtin_amdgcn_readfirstlane(es[i+2]);
    int s3=__builtin_amdgcn_readfirstlane(es[i+3]);
    const f16_t* r0=sf+(size_t)s0*stride;
    const f16_t* r1=sf+(size_t)s1*stride;
    const f16_t* r2=sf+(size_t)s2*stride;
    const f16_t* r3=sf+(size_t)s3*stride;
    f16_t k0=r0[koff+lane], k1=r1[koff+lane], k2=r2[koff+lane], k3=r3[koff+lane];
    float v0=(float)r0[voff+lane], v1=(float)r1[voff+lane];
    float v2=(float)r2[voff+lane], v3=(float)r3[voff+lane];
    h2v pa={k0,k1}; pa=q2*pa;
    h2v pb={k2,k3}; pb=q2*pb;
    pa=pa+shxor(pa,1); pb=pb+shxor(pb,1);
    pa=pa+shxor(pa,2); pb=pb+shxor(pb,2);
    pa=pa+shxor(pa,4); pb=pb+shxor(pb,4);
    float p0=(float)pa[0], p1=(float)pa[1], p2=(float)pb[0], p3=(float)pb[1];
    float mn=fmaxf(fmaxf(m,fmaxf(p0,p1)),fmaxf(p2,p3));
    float sc=__expf(m-mn);            // first iter: exp(-inf)=0
    float w0=__expf(p0-mn), w1=__expf(p1-mn), w2=__expf(p2-mn), w3=__expf(p3-mn);
    ls=ls*sc+((w0+w1)+(w2+w3));
    acc=acc*sc+((w0*v0+w1*v1)+(w2*v2+w3*v3));
    m=mn;
  }
  float qf=(float)qh;
  for(; i<e; i++){
    int s0=__builtin_amdgcn_readfirstlane(es[i]);
    const f16_t* r0=sf+(size_t)s0*stride;
    float k0=(float)r0[koff+lane], v0=(float)r0[voff+lane];
    float p0=qf*k0;
    p0+=__shfl_xor(p0,1); p0+=__shfl_xor(p0,2); p0+=__shfl_xor(p0,4);
    float mn=fmaxf(m,p0);
    float sc=__expf(m-mn), w0=__expf(p0-mn);
    ls=ls*sc+w0;
    acc=acc*sc+w0*v0;
    m=mn;
  }
  return acc/(ls+1e-16f);   // degree 0 -> 0, matches PyG semantics
}

// fused edge kernel: blocks [0,nbv) var destinations (vv+iv), rest instr destinations (vi)
__global__ __launch_bounds__(256) void k_edge_all(const int* __restrict__ rp_all,const int* __restrict__ es,
    const f16_t* __restrict__ var_feat,const f16_t* __restrict__ ins_feat,
    f16_t* __restrict__ agg_v,f16_t* __restrict__ agg_i,int nbv)
{
  int wave=threadIdx.x>>6, lane=threadIdx.x&63;
  if((int)blockIdx.x<nbv){
    int n=blockIdx.x*4+wave;
    f16_t qh=var_feat[(size_t)n*320+lane];
    float r1=edge_aggD(rp_all,es,var_feat,320,64,128,n,lane,qh);
    float r2=edge_aggD(rp_all+NV_N,es,ins_feat,192,64,128,n,lane,qh);
    agg_v[(size_t)n*64+lane]=(f16_t)(r1+r2);
  }else{
    int n=(blockIdx.x-nbv)*4+wave;
    f16_t qh=ins_feat[(size_t)n*192+lane];
    float r=edge_aggD(rp_all+2*NV_N,es,var_feat,320,192,256,n,lane,qh);
    agg_i[(size_t)n*64+lane]=(f16_t)r;
  }
}

// ---------------- jumping-knowledge 5x5 attention, one wave per node
__global__ __launch_bounds__(256) void k_jk(const f16_t* __restrict__ qkv,float* __restrict__ osum,int n_nodes){
  int wave=threadIdx.x>>6, lane=threadIdx.x&63;
  int n=blockIdx.x*4+wave;
  if(n>=n_nodes) return;
  float q[5],k[5],v[5];
  #pragma unroll
  for(int s=0;s<5;s++){
    const f16_t* p=qkv+((size_t)s*n_nodes+n)*192;
    q[s]=(float)p[lane]; k[s]=(float)p[64+lane]; v[s]=(float)p[128+lane];
  }
  float sc[5][5];
  #pragma unroll
  for(int s=0;s<5;s++)
    #pragma unroll
    for(int t=0;t<5;t++){
      float x=q[s]*k[t];
      x+=__shfl_xor(x,1); x+=__shfl_xor(x,2); x+=__shfl_xor(x,4);
      sc[s][t]=x*0.3535533905932738f;
    }
  float os=0.f;
  #pragma unroll
  for(int s=0;s<5;s++){
    float m=sc[s][0];
    #pragma unroll
    for(int t=1;t<5;t++) m=fmaxf(m,sc[s][t]);
    float den=0.f, acc=0.f;
    #pragma unroll
    for(int t=0;t<5;t++){ float e=__expf(sc[s][t]-m); den+=e; acc+=e*v[t]; }
    os+=acc/den;
  }
  osum[(size_t)n*64+lane]=os;
}

// ---------------- MLP head ----------------
struct MlpArgs{ const float *w0,*b0,*w1,*b1,*w2,*b2,*w3,*b3,*w4,*b4,*w5,*b5; };
__global__ __launch_bounds__(256) void k_mlp(const float* __restrict__ in,MlpArgs ma,float* __restrict__ out,int N){
  __shared__ float sw0[2048],sb0[32],sw1[512],sb1[16],sw2[128],sb2[8],sw3[32],sb3[4],sw4[8],sb4[2],sw5[2],sb5[1];
  for(int i=threadIdx.x;i<2048;i+=256) sw0[i]=ma.w0[i];
  for(int i=threadIdx.x;i<512;i+=256)  sw1[i]=ma.w1[i];
  if(threadIdx.x<128) sw2[threadIdx.x]=ma.w2[threadIdx.x];
  if(threadIdx.x<32){ sb0[threadIdx.x]=ma.b0[threadIdx.x]; sw3[threadIdx.x]=ma.w3[threadIdx.x]; }
  if(threadIdx.x<16) sb1[threadIdx.x]=ma.b1[threadIdx.x];
  if(threadIdx.x<8){ sb2[threadIdx.x]=ma.b2[threadIdx.x]; sw4[threadIdx.x]=ma.w4[threadIdx.x]; }
  if(threadIdx.x<4) sb3[threadIdx.x]=ma.b3[threadIdx.x];
  if(threadIdx.x<2){ sb4[threadIdx.x]=ma.b4[threadIdx.x]; sw5[threadIdx.x]=ma.w5[threadIdx.x]; }
  if(threadIdx.x==0) sb5[0]=ma.b5[0];
  __syncthreads();
  int n=blockIdx.x*256+threadIdx.x;
  if(n>=N) return;
  float a[64];
  const f32x4* p4=(const f32x4*)(in+(size_t)n*64);
  #pragma unroll
  for(int j=0;j<16;j++){ f32x4 t=p4[j]; a[4*j]=t[0]; a[4*j+1]=t[1]; a[4*j+2]=t[2]; a[4*j+3]=t[3]; }
  float h1[32];
  #pragma unroll
  for(int o=0;o<32;o++){ float s=sb0[o];
    #pragma unroll
    for(int c=0;c<64;c++) s+=a[c]*sw0[o*64+c];
    h1[o]=gelu_f(s); }
  float h2q[16];
  #pragma unroll
  for(int o=0;o<16;o++){ float s=sb1[o];
    #pragma unroll
    for(int c=0;c<32;c++) s+=h1[c]*sw1[o*32+c];
    h2q[o]=gelu_f(s); }
  float h3[8];
  #pragma unroll
  for(int o=0;o<8;o++){ float s=sb2[o];
    #pragma unroll
    for(int c=0;c<16;c++) s+=h2q[c]*sw2[o*16+c];
    h3[o]=gelu_f(s); }
  float h4[4];
  #pragma unroll
  for(int o=0;o<4;o++){ float s=sb3[o];
    #pragma unroll
    for(int c=0;c<8;c++) s+=h3[c]*sw3[o*8+c];
    h4[o]=gelu_f(s); }
  float h5[2];
  #pragma unroll
  for(int o=0;o<2;o++){ float s=sb4[o];
    #pragma unroll
    for(int c=0;c<4;c++) s+=h4[c]*sw4[o*4+c];
    h5[o]=gelu_f(s); }
  float r=sb5[0]+h5[0]*sw5[0]+h5[1]*sw5[1];
  out[n]=r;
}

// ================= host launcher =================
extern "C" void kernel_launch(void* const* d_in,const int* in_sizes,int n_in,
                              void* d_out,int out_size,void* d_ws,size_t ws_size,
                              hipStream_t stream){
  (void)in_sizes;(void)n_in;(void)out_size;(void)ws_size;
  const float* x_instr=(const float*)d_in[0];
  const float* x_var  =(const float*)d_in[1];
  const float* ba_i=(const float*)d_in[9];
  const float* skip_i=(const float*)d_in[10];
  const float* ba_v=(const float*)d_in[18];
  const float* skip_v=(const float*)d_in[19];
  const float* Wqkv=(const float*)d_in[29];
  const float* bqkv=(const float*)d_in[30];
  const float* Wo=(const float*)d_in[31];
  const float* bo=(const float*)d_in[32];
  const int* src_vv=(const int*)d_in[45];
  const int* dst_vv=(const int*)d_in[46];
  const int* src_vi=(const int*)d_in[47];
  const int* dst_vi=(const int*)d_in[48];
  const int* src_iv=(const int*)d_in[49];
  const int* dst_iv=(const int*)d_in[50];

  char* w=(char*)d_ws;
  auto alloc=[&](size_t b)->char*{ char* p=w; w+=(b+255)&~(size_t)255; return p; };
  // ---- fused CSR arrays (~12 MB) ----
  int* rp_all=(int*)alloc((size_t)(NT_N+1)*4);
  int* cnt_all=(int*)alloc((size_t)NT_N*4);
  int* cur_all=(int*)alloc((size_t)NT_N*4);
  int* bsum =(int*)alloc(640*4);
  int* boff =(int*)alloc(640*4);
  int* esrc_all=(int*)alloc((size_t)ET_N*4);
  // ---- folded + pre-split weights for all 6 layers (~2.5 MB) ----
  short* fwh_var=(short*)alloc((size_t)6*320*64*2);
  short* fwl_var=(short*)alloc((size_t)6*320*64*2);
  float* fwb_var=(float*)alloc((size_t)6*320*4);
  short* fwh_ins=(short*)alloc((size_t)6*192*64*2);
  short* fwl_ins=(short*)alloc((size_t)6*192*64*2);
  float* fwb_ins=(float*)alloc((size_t)6*192*4);
  short* wah_i=(short*)alloc((size_t)6*64*64*2);
  short* wal_i=(short*)alloc((size_t)6*64*64*2);
  short* wah_v=(short*)alloc((size_t)6*64*64*2);
  short* wal_v=(short*)alloc((size_t)6*64*64*2);
  short* qkvh=(short*)alloc(192*64*2);
  short* qkvl=(short*)alloc(192*64*2);
  short* woh=(short*)alloc(64*64*2);
  short* wol=(short*)alloc(64*64*2);
  // ---- persistent across phases: outs (f16, 21 MB) ----
  f16_t* outs=(f16_t*)alloc((size_t)5*NI_N*64*2);
  // ---- arena (140 MB), phase-overlaid ----
  char* arena=alloc((size_t)146800640);
  f16_t*  xv      =(f16_t*)(arena);                                // 16,777,216 B
  f16_t*  xi      =(f16_t*)(arena+16777216);                       //  4,194,304 B
  f16_t*  var_feat=(f16_t*)(arena+20971520);                       // 83,886,080 B (stride 320: q|k_vv|v_vv|k_vi|v_vi)
  f16_t*  ins_feat=(f16_t*)(arena+104857600);                      // 12,582,912 B (stride 192: q|k|v)
  f16_t*  agg_v   =(f16_t*)(arena+117440512);                      // 16,777,216 B
  f16_t*  agg_i   =(f16_t*)(arena+134217728);                      //  4,194,304 B  (ends 138,412,032)
  // JK phase overlays (xv/xi/var_feat dead by then):
  f16_t*  qkv    =(f16_t*)(arena);                                 // 62,914,560 B
  float*  osum   =(float*)(arena+67108864);                        //  8,388,608 B (inside dead var_feat)
  float*  out_jk =(float*)(arena+75497472);                        //  8,388,608 B (inside dead var_feat)

  // fused CSR build
  hipMemsetAsync(cnt_all,0,(size_t)NT_N*4,stream);
  k_hist3<<<ET_N/256,256,0,stream>>>(dst_vv,dst_iv,dst_vi,cnt_all);
  int nb=NT_N/512;   // 576
  k_scan1<<<nb,512,0,stream>>>(cnt_all,NT_N,rp_all,bsum);
  k_scan2<<<1,1024,0,stream>>>(bsum,boff,nb);
  k_scan3<<<nb,512,0,stream>>>(rp_all,boff,cur_all,NT_N,nb);
  for(int wdx=0;wdx<SC_WIN;wdx++){
    int dlo=wdx*(NT_N/SC_WIN), dhi=(wdx+1)*(NT_N/SC_WIN);
    k_scatter3w<<<ET_N/256,256,0,stream>>>(src_vv,dst_vv,src_iv,dst_iv,src_vi,dst_vi,cur_all,esrc_all,dlo,dhi);
  }

  k_castx<<<(NI_N*64+NV_N*64)/256,256,0,stream>>>(x_instr,x_var,xi,xv);

  // one-time splits for JK weights
  k_split2<<<(192*64+255)/256,256,0,stream>>>(Wqkv,192*64,qkvh,qkvl);
  k_split2<<<(64*64+255)/256,256,0,stream>>>(Wo,64*64,woh,wol);

  FoldArgs fa;
  fa.Wk_i=(const float*)d_in[2]; fa.Wq_i=(const float*)d_in[3]; fa.Wv_i=(const float*)d_in[4];
  fa.bk_i=(const float*)d_in[6]; fa.bq_i=(const float*)d_in[7]; fa.bv_i=(const float*)d_in[8];
  fa.Wk_v=(const float*)d_in[11]; fa.Wq_v=(const float*)d_in[12]; fa.Wv_v=(const float*)d_in[13];
  fa.bk_v=(const float*)d_in[15]; fa.bq_v=(const float*)d_in[16]; fa.bv_v=(const float*)d_in[17];
  fa.arel_vv=(const float*)d_in[20]; fa.mrel_vv=(const float*)d_in[21]; fa.prel_vv=(const float*)d_in[22];
  fa.arel_vi=(const float*)d_in[23]; fa.mrel_vi=(const float*)d_in[24]; fa.prel_vi=(const float*)d_in[25];
  fa.arel_iv=(const float*)d_in[26]; fa.mrel_iv=(const float*)d_in[27]; fa.prel_iv=(const float*)d_in[28];
  fa.Wa_i=(const float*)d_in[5]; fa.Wa_v=(const float*)d_in[14];
  fa.fwh_var=fwh_var; fa.fwl_var=fwl_var; fa.fwh_ins=fwh_ins; fa.fwl_ins=fwl_ins;
  fa.wah_i=wah_i; fa.wal_i=wal_i; fa.wah_v=wah_v; fa.wal_v=wal_v;
  fa.fwb_var=fwb_var; fa.fwb_ins=fwb_ins;
  k_fold6<<<(6*640*64)/256,256,0,stream>>>(fa);     // all 6 layers, hoisted out of the loop

  for(int l=0;l<6;l++){
    // fused feature GEMM: var (5 panels, stride 320) + instr (3 panels, stride 192)
    k_gemm_feat<<<NV_N/64+NI_N/64,256,0,stream>>>(xv,xi,
        fwh_var+(size_t)l*320*64,fwl_var+(size_t)l*320*64,fwb_var+l*320,
        fwh_ins+(size_t)l*192*64,fwl_ins+(size_t)l*192*64,fwb_ins+l*192,
        var_feat,ins_feat,NV_N/64);
    // fused edge kernel: var destinations (vv+iv) + instr destinations (vi)
    k_edge_all<<<NV_N/4+NI_N/4,256,0,stream>>>(rp_all,esrc_all,var_feat,ins_feat,agg_v,agg_i,NV_N/4);
    // fused update (instr blocks then var blocks)
    k_update2<<<NI_N/64+NV_N/64,256,0,stream>>>(agg_i,agg_v,
        wah_i+(size_t)l*4096,wal_i+(size_t)l*4096,wah_v+(size_t)l*4096,wal_v+(size_t)l*4096,
        ba_i+l*64,ba_v+l*64,skip_i+l,skip_v+l,xi,xv,
        (l>0)?(outs+(size_t)(l-1)*NI_N*64):nullptr,NI_N/64);
  }

  // jumping knowledge + head
  k_gemm64p<f16_t,f16_t><<<5*NI_N/64,256,0,stream>>>(outs,5*NI_N,qkvh,qkvl,bqkv,1.0f,qkv,192,0,3);
  k_jk<<<NI_N/4,256,0,stream>>>(qkv,osum,NI_N);
  k_gemm64p<float,float><<<NI_N/64,256,0,stream>>>(osum,NI_N,woh,wol,bo,5.0f,out_jk,64,0,1);
  MlpArgs ma;
  ma.w0=(const float*)d_in[33]; ma.b0=(const float*)d_in[34];
  ma.w1=(const float*)d_in[35]; ma.b1=(const float*)d_in[36];
  ma.w2=(const float*)d_in[37]; ma.b2=(const float*)d_in[38];
  ma.w3=(const float*)d_in[39]; ma.b3=(const float*)d_in[40];
  ma.w4=(const float*)d_in[41]; ma.b4=(const float*)d_in[42];
  ma.w5=(const float*)d_in[43]; ma.b5=(const float*)d_in[44];
  k_mlp<<<NI_N/256,256,0,stream>>>(out_jk,ma,(float*)d_out,NI_N);
}

// Round 12
// 2034.183 us; speedup vs baseline: 1.5598x; 1.0379x over previous
//
#include <hip/hip_runtime.h>
#include <cmath>

typedef unsigned short bf16_t;                                  // raw bf16 bits
typedef _Float16 f16_t;                                         // IEEE fp16
typedef __attribute__((ext_vector_type(8))) short short8;       // MFMA A/B frag
typedef __attribute__((ext_vector_type(4))) float f32x4;        // MFMA C/D frag
typedef _Float16 h2v __attribute__((ext_vector_type(2)));       // packed f16 pair
typedef _Float16 h8 __attribute__((ext_vector_type(8)));        // 16B f16 vector

#define NI_N 32768
#define NV_N 131072
#define E_VV 1048576
#define E_VI 524288
#define E_IV 524288
#define NT_N (NV_N+NV_N+NI_N)          // 294912 concatenated nodes (vv|iv|vi)
#define ET_N (E_VV+E_IV+E_VI)          // 2097152 concatenated edges
#define SC_WIN 4                        // scatter windows

__device__ __forceinline__ float bf2f(bf16_t u){ return __builtin_bit_cast(float,((unsigned)u)<<16); }
__device__ __forceinline__ bf16_t f2bf(float f){
  unsigned u=__builtin_bit_cast(unsigned,f);
  return (bf16_t)((u+0x7fffu+((u>>16)&1u))>>16);
}
__device__ __forceinline__ float gelu_f(float x){ return 0.5f*x*(1.0f+erff(x*0.7071067811865476f)); }

// split f32 into hi/lo bf16
__device__ __forceinline__ void splitf(float v, short& hi, short& lo){
  bf16_t h=f2bf(v);
  hi=(short)h;
  lo=(short)f2bf(v-bf2f(h));
}
__device__ __forceinline__ float ldval(const float* p){ return *p; }
__device__ __forceinline__ float ldval(const f16_t* p){ return (float)*p; }
__device__ __forceinline__ void stval(float* p,float v){ *p=v; }
__device__ __forceinline__ void stval(f16_t* p,float v){ *p=(f16_t)v; }
__device__ __forceinline__ h2v shxor(h2v a,int m){
  return __builtin_bit_cast(h2v,__shfl_xor(__builtin_bit_cast(int,a),m));
}

// ---------------- fused CSR build over 3 concatenated edge types ----------------
__global__ __launch_bounds__(256) void k_hist3(const int* __restrict__ dvv,const int* __restrict__ div_,
    const int* __restrict__ dvi,int* __restrict__ cnt){
  int i=blockIdx.x*256+threadIdx.x;
  if(i<E_VV) atomicAdd(&cnt[dvv[i]],1);
  else if(i<E_VV+E_IV) atomicAdd(&cnt[NV_N+div_[i-E_VV]],1);
  else atomicAdd(&cnt[2*NV_N+dvi[i-E_VV-E_IV]],1);
}
__global__ __launch_bounds__(512) void k_scan1(const int* __restrict__ cnt,int N,int* __restrict__ rp,int* __restrict__ bsum){
  __shared__ int sh[512];
  int i=blockIdx.x*512+threadIdx.x;
  int v=(i<N)?cnt[i]:0;
  sh[threadIdx.x]=v; __syncthreads();
  for(int off=1;off<512;off<<=1){
    int t=(threadIdx.x>=(unsigned)off)?sh[threadIdx.x-off]:0; __syncthreads();
    sh[threadIdx.x]+=t; __syncthreads();
  }
  if(i<N) rp[i]=sh[threadIdx.x]-v;
  if(threadIdx.x==511) bsum[blockIdx.x]=sh[511];
}
__global__ __launch_bounds__(1024) void k_scan2(const int* __restrict__ bsum,int* __restrict__ boff,int nb){
  __shared__ int sh[1024];
  int t=threadIdx.x;
  int v=(t<nb)?bsum[t]:0;
  sh[t]=v; __syncthreads();
  for(int off=1;off<1024;off<<=1){
    int x=(t>=(unsigned)off)?sh[t-off]:0; __syncthreads();
    sh[t]+=x; __syncthreads();
  }
  if(t<nb) boff[t]=sh[t]-v;
  if(t==1023) boff[nb]=sh[1023];
}
__global__ __launch_bounds__(512) void k_scan3(int* __restrict__ rp,const int* __restrict__ boff,int* __restrict__ cur,int N,int nb){
  int i=blockIdx.x*512+threadIdx.x;
  if(i<N){ int v=rp[i]+boff[i>>9]; rp[i]=v; cur[i]=v; }
  if(i==0) rp[N]=boff[nb];
}
__global__ __launch_bounds__(256) void k_scatter3w(const int* __restrict__ svv,const int* __restrict__ dvv,
    const int* __restrict__ siv,const int* __restrict__ div_,
    const int* __restrict__ svi,const int* __restrict__ dvi,
    int* __restrict__ cur,int* __restrict__ esrc,int dlo,int dhi){
  int i=blockIdx.x*256+threadIdx.x;
  int d,s;
  if(i<E_VV){ d=dvv[i]; if(d<dlo||d>=dhi) return; s=svv[i]; }
  else if(i<E_VV+E_IV){ int j=i-E_VV; d=NV_N+div_[j]; if(d<dlo||d>=dhi) return; s=siv[j]; }
  else { int j=i-E_VV-E_IV; d=2*NV_N+dvi[j]; if(d<dlo||d>=dhi) return; s=svi[j]; }
  int p=atomicAdd(&cur[d],1); esrc[p]=s;
}

// initial cast: f32 inputs -> f16 x buffers
__global__ __launch_bounds__(256) void k_castx(const float* __restrict__ xi_in,const float* __restrict__ xv_in,
    f16_t* __restrict__ xi,f16_t* __restrict__ xv){
  int i=blockIdx.x*256+threadIdx.x;
  if(i<NI_N*64) xi[i]=(f16_t)xi_in[i];
  else { int j=i-NI_N*64; xv[j]=(f16_t)xv_in[j]; }
}

// ---------------- weight folding for ALL 6 layers in one launch ----------------
struct FoldArgs{
  const float *Wk_i,*Wq_i,*Wv_i,*bk_i,*bq_i,*bv_i;
  const float *Wk_v,*Wq_v,*Wv_v,*bk_v,*bq_v,*bv_v;
  const float *arel_vv,*mrel_vv,*prel_vv,*arel_vi,*mrel_vi,*prel_vi,*arel_iv,*mrel_iv,*prel_iv;
  const float *Wa_i,*Wa_v;
  short *fwh_var,*fwl_var,*fwh_ins,*fwl_ins,*wah_i,*wal_i,*wah_v,*wal_v;
  float *fwb_var,*fwb_ins;
};
__global__ __launch_bounds__(256) void k_fold6(FoldArgs fa){
  int gid=blockIdx.x*256+threadIdx.x;
  if(gid>=6*640*64) return;
  int l=gid/(640*64);
  int rem=gid-l*640*64;
  int r=rem>>6, c=rem&63;
  if(r>=512){
    int ro=r&63;
    const float* W=(r<576)?fa.Wa_i:fa.Wa_v;
    short *sh=((r<576)?fa.wah_i:fa.wah_v)+l*4096, *sl=((r<576)?fa.wal_i:fa.wal_v)+l*4096;
    short h,lo; splitf(W[l*4096+ro*64+c],h,lo);
    sh[ro*64+c]=h; sl[ro*64+c]=lo;
    return;
  }
  const float *W,*B,*rel=nullptr,*prl=nullptr;
  short *sh,*sl; float *fwb; int orow;
  if(r<320){
    sh=fa.fwh_var+l*320*64; sl=fa.fwl_var+l*320*64; fwb=fa.fwb_var+l*320; orow=r;
    if(r<64){ W=fa.Wq_v; B=fa.bq_v; }
    else if(r<128){ W=fa.Wk_v; B=fa.bk_v; rel=fa.arel_vv; prl=fa.prel_vv; }
    else if(r<192){ W=fa.Wv_v; B=fa.bv_v; rel=fa.mrel_vv; }
    else if(r<256){ W=fa.Wk_v; B=fa.bk_v; rel=fa.arel_vi; prl=fa.prel_vi; }
    else         { W=fa.Wv_v; B=fa.bv_v; rel=fa.mrel_vi; }
  }else{
    int rr=r-320; sh=fa.fwh_ins+l*192*64; sl=fa.fwl_ins+l*192*64; fwb=fa.fwb_ins+l*192; orow=rr;
    if(rr<64){ W=fa.Wq_i; B=fa.bq_i; }
    else if(rr<128){ W=fa.Wk_i; B=fa.bk_i; rel=fa.arel_iv; prl=fa.prel_iv; }
    else           { W=fa.Wv_i; B=fa.bv_i; rel=fa.mrel_iv; }
  }
  int ro=orow&63;
  float val,bval;
  if(!rel){
    val=W[l*4096+ro*64+c]; bval=B[l*64+ro];
  }else{
    int h=ro>>3, e=ro&7;
    float s=prl?prl[l*8+h]*0.3535533905932738f:1.0f;
    float acc=0.f,bacc=0.f;
    #pragma unroll
    for(int d=0;d<8;d++){
      float rv=rel[l*512+h*64+d*8+e];
      acc += W[l*4096+(h*8+d)*64+c]*rv;
      bacc+= B[l*64+h*8+d]*rv;
    }
    val=acc*s; bval=bacc*s;
  }
  short h2q,lo2; splitf(val,h2q,lo2);
  sh[orow*64+c]=h2q; sl[orow*64+c]=lo2;
  if(c==0) fwb[orow]=bval;
}

__global__ __launch_bounds__(256) void k_split2(const float* __restrict__ W,int n,short* __restrict__ hi,short* __restrict__ lo){
  int i=blockIdx.x*256+threadIdx.x;
  if(i<n){ short h,l2; splitf(W[i],h,l2); hi[i]=h; lo[i]=l2; }
}

// ---------------- shared split-bf16 GEMM body with LDS-repacked wide f16 stores ----------------
// rep: per-wave LDS tile [16][72] (f16), nullptr-free for f16 out; float out stores directly.
template<typename AT, typename OT>
__device__ __forceinline__ void gemm_body(const AT* __restrict__ A,int row0,
    const short* __restrict__ Bh,const short* __restrict__ Bl,
    const float* __restrict__ bias,float bias_scale,
    OT* __restrict__ out,int octot,int ocol0,int npanels,int m,int quad,int lane,
    f16_t (*rep)[72])
{
  const AT* ap=A+(size_t)(row0+m)*64+quad*8;
  short8 ahi[2], alo[2];
  #pragma unroll
  for(int kf=0;kf<2;kf++){
    short8 th,tl;
    #pragma unroll
    for(int j=0;j<8;j++){ short h,l2; splitf(ldval(&ap[kf*32+j]),h,l2); th[j]=h; tl[j]=l2; }
    ahi[kf]=th; alo[kf]=tl;
  }
  for(int pan=0;pan<npanels;pan++){
    int colbase=pan*64;
    short8 bhi[4][2], blo[4][2];
    #pragma unroll
    for(int ot=0;ot<4;ot++){
      size_t o=(size_t)(colbase+ot*16+m)*64+quad*8;
      #pragma unroll
      for(int kf=0;kf<2;kf++){
        bhi[ot][kf]=*(const short8*)(Bh+o+kf*32);
        blo[ot][kf]=*(const short8*)(Bl+o+kf*32);
      }
    }
    f32x4 acc[4];
    #pragma unroll
    for(int ot=0;ot<4;ot++){
      float bv=bias[colbase+ot*16+m]*bias_scale;
      acc[ot][0]=bv; acc[ot][1]=bv; acc[ot][2]=bv; acc[ot][3]=bv;
    }
    #pragma unroll
    for(int ot=0;ot<4;ot++){
      #pragma unroll
      for(int kf=0;kf<2;kf++){
        acc[ot]=__builtin_amdgcn_mfma_f32_16x16x32_bf16(alo[kf],bhi[ot][kf],acc[ot],0,0,0);
        acc[ot]=__builtin_amdgcn_mfma_f32_16x16x32_bf16(ahi[kf],blo[ot][kf],acc[ot],0,0,0);
        acc[ot]=__builtin_amdgcn_mfma_f32_16x16x32_bf16(ahi[kf],bhi[ot][kf],acc[ot],0,0,0);
      }
    }
    if constexpr(sizeof(OT)==2){
      // repack via LDS, store wide
      #pragma unroll
      for(int ot=0;ot<4;ot++)
        #pragma unroll
        for(int r=0;r<4;r++)
          rep[quad*4+r][ot*16+m]=(f16_t)acc[ot][r];
      #pragma unroll
      for(int it=0;it<2;it++){
        int rr=it*8+(lane>>3), seg=lane&7;
        h8 vals=*(const h8*)&rep[rr][seg*8];
        *(h8*)(out+(size_t)(row0+rr)*octot+ocol0+colbase+seg*8)=vals;
      }
    }else{
      #pragma unroll
      for(int ot=0;ot<4;ot++){
        int col=ocol0+colbase+ot*16+m;
        #pragma unroll
        for(int r=0;r<4;r++){
          int row=row0+quad*4+r;
          stval(&out[(size_t)row*octot+col],acc[ot][r]);
        }
      }
    }
  }
}

template<typename AT, typename OT>
__global__ __launch_bounds__(256) void k_gemm64p(const AT* __restrict__ A,int N,
    const short* __restrict__ Bh,const short* __restrict__ Bl,
    const float* __restrict__ bias,float bias_scale,
    OT* __restrict__ out,int octot,int ocol0,int npanels)
{
  __shared__ f16_t rep[4][16][72];
  const int wave=threadIdx.x>>6, lane=threadIdx.x&63;
  const int m=lane&15, quad=lane>>4;
  const int row0=blockIdx.x*64+wave*16;
  if(row0>=N) return;
  gemm_body<AT,OT>(A,row0,Bh,Bl,bias,bias_scale,out,octot,ocol0,npanels,m,quad,lane,rep[wave]);
}

// fused feature GEMM: blocks [0,nbv) var rows (5 panels, stride 320), rest ins rows (3 panels, 192)
__global__ __launch_bounds__(256) void k_gemm_feat(const f16_t* __restrict__ Av,const f16_t* __restrict__ Ai,
    const short* __restrict__ Bvh,const short* __restrict__ Bvl,const float* __restrict__ biasv,
    const short* __restrict__ Bih,const short* __restrict__ Bil,const float* __restrict__ biasi,
    f16_t* __restrict__ outv,f16_t* __restrict__ outi,int nbv)
{
  __shared__ f16_t rep[4][16][72];
  const int wave=threadIdx.x>>6, lane=threadIdx.x&63;
  const int m=lane&15, quad=lane>>4;
  if((int)blockIdx.x<nbv){
    int row0=blockIdx.x*64+wave*16;
    gemm_body<f16_t,f16_t>(Av,row0,Bvh,Bvl,biasv,1.0f,outv,320,0,5,m,quad,lane,rep[wave]);
  }else{
    int row0=(blockIdx.x-nbv)*64+wave*16;
    gemm_body<f16_t,f16_t>(Ai,row0,Bih,Bil,biasi,1.0f,outi,192,0,3,m,quad,lane,rep[wave]);
  }
}

// ---------------- fused per-layer update (instr blocks then var blocks), x/agg f16, LDS-repacked I/O ----------------
__global__ __launch_bounds__(256) void k_update2(const f16_t* __restrict__ agg_i,const f16_t* __restrict__ agg_v,
    const short* __restrict__ wah_i,const short* __restrict__ wal_i,
    const short* __restrict__ wah_v,const short* __restrict__ wal_v,
    const float* __restrict__ ba_i,const float* __restrict__ ba_v,
    const float* __restrict__ skip_i,const float* __restrict__ skip_v,
    f16_t* __restrict__ x_i,f16_t* __restrict__ x_v,
    f16_t* __restrict__ outs,int nbi)
{
  __shared__ f16_t rep[4][16][72];
  const int wave=threadIdx.x>>6, lane=threadIdx.x&63;
  const int m=lane&15, quad=lane>>4;
  const bool isI=(int)blockIdx.x<nbi;
  const int row0=(isI?blockIdx.x:(blockIdx.x-nbi))*64+wave*16;
  const f16_t* agg=isI?agg_i:agg_v;
  const short* Wah=isI?wah_i:wah_v;
  const short* Wal=isI?wal_i:wal_v;
  const float* ba=isI?ba_i:ba_v;
  const float* skip=isI?skip_i:skip_v;
  f16_t* x=isI?x_i:x_v;
  f16_t* oo=isI?outs:nullptr;
  f16_t (*R)[72]=rep[wave];
  short8 bhi[4][2], blo[4][2];
  #pragma unroll
  for(int ot=0;ot<4;ot++){
    size_t o=(size_t)(ot*16+m)*64+quad*8;
    #pragma unroll
    for(int kf=0;kf<2;kf++){
      bhi[ot][kf]=*(const short8*)(Wah+o+kf*32);
      blo[ot][kf]=*(const short8*)(Wal+o+kf*32);
    }
  }
  const f16_t* ap=agg+(size_t)(row0+m)*64+quad*8;
  short8 ahi[2], alo[2];
  #pragma unroll
  for(int kf=0;kf<2;kf++){
    short8 th,tl;
    #pragma unroll
    for(int j=0;j<8;j++){ short h,l2; splitf(gelu_f((float)ap[kf*32+j]),h,l2); th[j]=h; tl[j]=l2; }
    ahi[kf]=th; alo[kf]=tl;
  }
  // stage x rows into LDS (wide loads)
  int rr0=lane>>3, seg=lane&7;
  h8 x0=*(const h8*)(x+(size_t)(row0+rr0)*64+seg*8);
  h8 x1=*(const h8*)(x+(size_t)(row0+8+rr0)*64+seg*8);
  *(h8*)&R[rr0][seg*8]=x0;
  *(h8*)&R[8+rr0][seg*8]=x1;
  f32x4 acc[4];
  #pragma unroll
  for(int ot=0;ot<4;ot++){
    float bv=ba[ot*16+m];
    acc[ot][0]=bv; acc[ot][1]=bv; acc[ot][2]=bv; acc[ot][3]=bv;
  }
  #pragma unroll
  for(int ot=0;ot<4;ot++){
    #pragma unroll
    for(int kf=0;kf<2;kf++){
      acc[ot]=__builtin_amdgcn_mfma_f32_16x16x32_bf16(alo[kf],bhi[ot][kf],acc[ot],0,0,0);
      acc[ot]=__builtin_amdgcn_mfma_f32_16x16x32_bf16(ahi[kf],blo[ot][kf],acc[ot],0,0,0);
      acc[ot]=__builtin_amdgcn_mfma_f32_16x16x32_bf16(ahi[kf],bhi[ot][kf],acc[ot],0,0,0);
    }
  }
  float s=1.0f/(1.0f+__expf(-skip[0]));
  // blend against LDS-staged x, write result back into the SAME cells (each cell owned by one lane)
  #pragma unroll
  for(int ot=0;ot<4;ot++){
    int col=ot*16+m;
    #pragma unroll
    for(int r=0;r<4;r++){
      int row=quad*4+r;
      float xn=s*acc[ot][r]+(1.0f-s)*(float)R[row][col];
      R[row][col]=(f16_t)xn;
    }
  }
  // wide write-back
  h8 o0=*(const h8*)&R[rr0][seg*8];
  h8 o1=*(const h8*)&R[8+rr0][seg*8];
  *(h8*)(x+(size_t)(row0+rr0)*64+seg*8)=o0;
  *(h8*)(x+(size_t)(row0+8+rr0)*64+seg*8)=o1;
  if(oo){
    *(h8*)(oo+(size_t)(row0+rr0)*64+seg*8)=o0;
    *(h8*)(oo+(size_t)(row0+8+rr0)*64+seg*8)=o1;
  }
}

// ---------------- edge attention: lane = feature dim, 4-edge unroll, packed-f16 dots ----------------
__device__ __forceinline__ float edge_aggD(const int* __restrict__ rp,const int* __restrict__ es,
    const f16_t* __restrict__ sf,int stride,int koff,int voff,int n,int lane,f16_t qh)
{
  int b=__builtin_amdgcn_readfirstlane(rp[n]);
  int e=__builtin_amdgcn_readfirstlane(rp[n+1]);
  float m=-INFINITY, ls=0.f, acc=0.f;
  h2v q2={qh,qh};
  int i=b;
  for(; i+3<e; i+=4){
    int s0=__builtin_amdgcn_readfirstlane(es[i]);
    int s1=__builtin_amdgcn_readfirstlane(es[i+1]);
    int s2=__builtin_amdgcn_readfirstlane(es[i+2]);
    int s3=__builtin_amdgcn_readfirstlane(es[i+3]);
    const f16_t* r0=sf+(size_t)s0*stride;
    const f16_t* r1=sf+(size_t)s1*stride;
    const f16_t* r2=sf+(size_t)s2*stride;
    const f16_t* r3=sf+(size_t)s3*stride;
    f16_t k0=r0[koff+lane], k1=r1[koff+lane], k2=r2[koff+lane], k3=r3[koff+lane];
    float v0=(float)r0[voff+lane], v1=(float)r1[voff+lane];
    float v2=(float)r2[voff+lane], v3=(float)r3[voff+lane];
    h2v pa={k0,k1}; pa=q2*pa;
    h2v pb={k2,k3}; pb=q2*pb;
    pa=pa+shxor(pa,1); pb=pb+shxor(pb,1);
    pa=pa+shxor(pa,2); pb=pb+shxor(pb,2);
    pa=pa+shxor(pa,4); pb=pb+shxor(pb,4);
    float p0=(float)pa[0], p1=(float)pa[1], p2=(float)pb[0], p3=(float)pb[1];
    float mn=fmaxf(fmaxf(m,fmaxf(p0,p1)),fmaxf(p2,p3));
    float sc=__expf(m-mn);            // first iter: exp(-inf)=0
    float w0=__expf(p0-mn), w1=__expf(p1-mn), w2=__expf(p2-mn), w3=__expf(p3-mn);
    ls=ls*sc+((w0+w1)+(w2+w3));
    acc=acc*sc+((w0*v0+w1*v1)+(w2*v2+w3*v3));
    m=mn;
  }
  float qf=(float)qh;
  for(; i<e; i++){
    int s0=__builtin_amdgcn_readfirstlane(es[i]);
    const f16_t* r0=sf+(size_t)s0*stride;
    float k0=(float)r0[koff+lane], v0=(float)r0[voff+lane];
    float p0=qf*k0;
    p0+=__shfl_xor(p0,1); p0+=__shfl_xor(p0,2); p0+=__shfl_xor(p0,4);
    float mn=fmaxf(m,p0);
    float sc=__expf(m-mn), w0=__expf(p0-mn);
    ls=ls*sc+w0;
    acc=acc*sc+w0*v0;
    m=mn;
  }
  return acc/(ls+1e-16f);   // degree 0 -> 0, matches PyG semantics
}

// fused edge kernel: blocks [0,nbv) var destinations (vv+iv), rest instr destinations (vi)
__global__ __launch_bounds__(256) void k_edge_all(const int* __restrict__ rp_all,const int* __restrict__ es,
    const f16_t* __restrict__ var_feat,const f16_t* __restrict__ ins_feat,
    f16_t* __restrict__ agg_v,f16_t* __restrict__ agg_i,int nbv)
{
  int wave=threadIdx.x>>6, lane=threadIdx.x&63;
  if((int)blockIdx.x<nbv){
    int n=blockIdx.x*4+wave;
    f16_t qh=var_feat[(size_t)n*320+lane];
    float r1=edge_aggD(rp_all,es,var_feat,320,64,128,n,lane,qh);
    float r2=edge_aggD(rp_all+NV_N,es,ins_feat,192,64,128,n,lane,qh);
    agg_v[(size_t)n*64+lane]=(f16_t)(r1+r2);
  }else{
    int n=(blockIdx.x-nbv)*4+wave;
    f16_t qh=ins_feat[(size_t)n*192+lane];
    float r=edge_aggD(rp_all+2*NV_N,es,var_feat,320,192,256,n,lane,qh);
    agg_i[(size_t)n*64+lane]=(f16_t)r;
  }
}

// ---------------- jumping-knowledge 5x5 attention, one wave per node
__global__ __launch_bounds__(256) void k_jk(const f16_t* __restrict__ qkv,float* __restrict__ osum,int n_nodes){
  int wave=threadIdx.x>>6, lane=threadIdx.x&63;
  int n=blockIdx.x*4+wave;
  if(n>=n_nodes) return;
  float q[5],k[5],v[5];
  #pragma unroll
  for(int s=0;s<5;s++){
    const f16_t* p=qkv+((size_t)s*n_nodes+n)*192;
    q[s]=(float)p[lane]; k[s]=(float)p[64+lane]; v[s]=(float)p[128+lane];
  }
  float sc[5][5];
  #pragma unroll
  for(int s=0;s<5;s++)
    #pragma unroll
    for(int t=0;t<5;t++){
      float x=q[s]*k[t];
      x+=__shfl_xor(x,1); x+=__shfl_xor(x,2); x+=__shfl_xor(x,4);
      sc[s][t]=x*0.3535533905932738f;
    }
  float os=0.f;
  #pragma unroll
  for(int s=0;s<5;s++){
    float m=sc[s][0];
    #pragma unroll
    for(int t=1;t<5;t++) m=fmaxf(m,sc[s][t]);
    float den=0.f, acc=0.f;
    #pragma unroll
    for(int t=0;t<5;t++){ float e=__expf(sc[s][t]-m); den+=e; acc+=e*v[t]; }
    os+=acc/den;
  }
  osum[(size_t)n*64+lane]=os;
}

// ---------------- MLP head ----------------
struct MlpArgs{ const float *w0,*b0,*w1,*b1,*w2,*b2,*w3,*b3,*w4,*b4,*w5,*b5; };
__global__ __launch_bounds__(256) void k_mlp(const float* __restrict__ in,MlpArgs ma,float* __restrict__ out,int N){
  __shared__ float sw0[2048],sb0[32],sw1[512],sb1[16],sw2[128],sb2[8],sw3[32],sb3[4],sw4[8],sb4[2],sw5[2],sb5[1];
  for(int i=threadIdx.x;i<2048;i+=256) sw0[i]=ma.w0[i];
  for(int i=threadIdx.x;i<512;i+=256)  sw1[i]=ma.w1[i];
  if(threadIdx.x<128) sw2[threadIdx.x]=ma.w2[threadIdx.x];
  if(threadIdx.x<32){ sb0[threadIdx.x]=ma.b0[threadIdx.x]; sw3[threadIdx.x]=ma.w3[threadIdx.x]; }
  if(threadIdx.x<16) sb1[threadIdx.x]=ma.b1[threadIdx.x];
  if(threadIdx.x<8){ sb2[threadIdx.x]=ma.b2[threadIdx.x]; sw4[threadIdx.x]=ma.w4[threadIdx.x]; }
  if(threadIdx.x<4) sb3[threadIdx.x]=ma.b3[threadIdx.x];
  if(threadIdx.x<2){ sb4[threadIdx.x]=ma.b4[threadIdx.x]; sw5[threadIdx.x]=ma.w5[threadIdx.x]; }
  if(threadIdx.x==0) sb5[0]=ma.b5[0];
  __syncthreads();
  int n=blockIdx.x*256+threadIdx.x;
  if(n>=N) return;
  float a[64];
  const f32x4* p4=(const f32x4*)(in+(size_t)n*64);
  #pragma unroll
  for(int j=0;j<16;j++){ f32x4 t=p4[j]; a[4*j]=t[0]; a[4*j+1]=t[1]; a[4*j+2]=t[2]; a[4*j+3]=t[3]; }
  float h1[32];
  #pragma unroll
  for(int o=0;o<32;o++){ float s=sb0[o];
    #pragma unroll
    for(int c=0;c<64;c++) s+=a[c]*sw0[o*64+c];
    h1[o]=gelu_f(s); }
  float h2q[16];
  #pragma unroll
  for(int o=0;o<16;o++){ float s=sb1[o];
    #pragma unroll
    for(int c=0;c<32;c++) s+=h1[c]*sw1[o*32+c];
    h2q[o]=gelu_f(s); }
  float h3[8];
  #pragma unroll
  for(int o=0;o<8;o++){ float s=sb2[o];
    #pragma unroll
    for(int c=0;c<16;c++) s+=h2q[c]*sw2[o*16+c];
    h3[o]=gelu_f(s); }
  float h4[4];
  #pragma unroll
  for(int o=0;o<4;o++){ float s=sb3[o];
    #pragma unroll
    for(int c=0;c<8;c++) s+=h3[c]*sw3[o*8+c];
    h4[o]=gelu_f(s); }
  float h5[2];
  #pragma unroll
  for(int o=0;o<2;o++){ float s=sb4[o];
    #pragma unroll
    for(int c=0;c<4;c++) s+=h4[c]*sw4[o*4+c];
    h5[o]=gelu_f(s); }
  float r=sb5[0]+h5[0]*sw5[0]+h5[1]*sw5[1];
  out[n]=r;
}

// ================= host launcher =================
extern "C" void kernel_launch(void* const* d_in,const int* in_sizes,int n_in,
                              void* d_out,int out_size,void* d_ws,size_t ws_size,
                              hipStream_t stream){
  (void)in_sizes;(void)n_in;(void)out_size;(void)ws_size;
  const float* x_instr=(const float*)d_in[0];
  const float* x_var  =(const float*)d_in[1];
  const float* ba_i=(const float*)d_in[9];
  const float* skip_i=(const float*)d_in[10];
  const float* ba_v=(const float*)d_in[18];
  const float* skip_v=(const float*)d_in[19];
  const float* Wqkv=(const float*)d_in[29];
  const float* bqkv=(const float*)d_in[30];
  const float* Wo=(const float*)d_in[31];
  const float* bo=(const float*)d_in[32];
  const int* src_vv=(const int*)d_in[45];
  const int* dst_vv=(const int*)d_in[46];
  const int* src_vi=(const int*)d_in[47];
  const int* dst_vi=(const int*)d_in[48];
  const int* src_iv=(const int*)d_in[49];
  const int* dst_iv=(const int*)d_in[50];

  char* w=(char*)d_ws;
  auto alloc=[&](size_t b)->char*{ char* p=w; w+=(b+255)&~(size_t)255; return p; };
  // ---- fused CSR arrays (~12 MB) ----
  int* rp_all=(int*)alloc((size_t)(NT_N+1)*4);
  int* cnt_all=(int*)alloc((size_t)NT_N*4);
  int* cur_all=(int*)alloc((size_t)NT_N*4);
  int* bsum =(int*)alloc(640*4);
  int* boff =(int*)alloc(640*4);
  int* esrc_all=(int*)alloc((size_t)ET_N*4);
  // ---- folded + pre-split weights for all 6 layers (~2.5 MB) ----
  short* fwh_var=(short*)alloc((size_t)6*320*64*2);
  short* fwl_var=(short*)alloc((size_t)6*320*64*2);
  float* fwb_var=(float*)alloc((size_t)6*320*4);
  short* fwh_ins=(short*)alloc((size_t)6*192*64*2);
  short* fwl_ins=(short*)alloc((size_t)6*192*64*2);
  float* fwb_ins=(float*)alloc((size_t)6*192*4);
  short* wah_i=(short*)alloc((size_t)6*64*64*2);
  short* wal_i=(short*)alloc((size_t)6*64*64*2);
  short* wah_v=(short*)alloc((size_t)6*64*64*2);
  short* wal_v=(short*)alloc((size_t)6*64*64*2);
  short* qkvh=(short*)alloc(192*64*2);
  short* qkvl=(short*)alloc(192*64*2);
  short* woh=(short*)alloc(64*64*2);
  short* wol=(short*)alloc(64*64*2);
  // ---- persistent across phases: outs (f16, 21 MB) ----
  f16_t* outs=(f16_t*)alloc((size_t)5*NI_N*64*2);
  // ---- arena (140 MB), phase-overlaid ----
  char* arena=alloc((size_t)146800640);
  f16_t*  xv      =(f16_t*)(arena);                                // 16,777,216 B
  f16_t*  xi      =(f16_t*)(arena+16777216);                       //  4,194,304 B
  f16_t*  var_feat=(f16_t*)(arena+20971520);                       // 83,886,080 B (stride 320: q|k_vv|v_vv|k_vi|v_vi)
  f16_t*  ins_feat=(f16_t*)(arena+104857600);                      // 12,582,912 B (stride 192: q|k|v)
  f16_t*  agg_v   =(f16_t*)(arena+117440512);                      // 16,777,216 B
  f16_t*  agg_i   =(f16_t*)(arena+134217728);                      //  4,194,304 B
  // JK phase overlays (xv/xi/var_feat dead by then):
  f16_t*  qkv    =(f16_t*)(arena);                                 // 62,914,560 B
  float*  osum   =(float*)(arena+67108864);                        //  8,388,608 B (inside dead var_feat)
  float*  out_jk =(float*)(arena+75497472);                        //  8,388,608 B (inside dead var_feat)

  // fused CSR build
  hipMemsetAsync(cnt_all,0,(size_t)NT_N*4,stream);
  k_hist3<<<ET_N/256,256,0,stream>>>(dst_vv,dst_iv,dst_vi,cnt_all);
  int nb=NT_N/512;   // 576
  k_scan1<<<nb,512,0,stream>>>(cnt_all,NT_N,rp_all,bsum);
  k_scan2<<<1,1024,0,stream>>>(bsum,boff,nb);
  k_scan3<<<nb,512,0,stream>>>(rp_all,boff,cur_all,NT_N,nb);
  for(int wdx=0;wdx<SC_WIN;wdx++){
    int dlo=wdx*(NT_N/SC_WIN), dhi=(wdx+1)*(NT_N/SC_WIN);
    k_scatter3w<<<ET_N/256,256,0,stream>>>(src_vv,dst_vv,src_iv,dst_iv,src_vi,dst_vi,cur_all,esrc_all,dlo,dhi);
  }

  k_castx<<<(NI_N*64+NV_N*64)/256,256,0,stream>>>(x_instr,x_var,xi,xv);

  // one-time splits for JK weights
  k_split2<<<(192*64+255)/256,256,0,stream>>>(Wqkv,192*64,qkvh,qkvl);
  k_split2<<<(64*64+255)/256,256,0,stream>>>(Wo,64*64,woh,wol);

  FoldArgs fa;
  fa.Wk_i=(const float*)d_in[2]; fa.Wq_i=(const float*)d_in[3]; fa.Wv_i=(const float*)d_in[4];
  fa.bk_i=(const float*)d_in[6]; fa.bq_i=(const float*)d_in[7]; fa.bv_i=(const float*)d_in[8];
  fa.Wk_v=(const float*)d_in[11]; fa.Wq_v=(const float*)d_in[12]; fa.Wv_v=(const float*)d_in[13];
  fa.bk_v=(const float*)d_in[15]; fa.bq_v=(const float*)d_in[16]; fa.bv_v=(const float*)d_in[17];
  fa.arel_vv=(const float*)d_in[20]; fa.mrel_vv=(const float*)d_in[21]; fa.prel_vv=(const float*)d_in[22];
  fa.arel_vi=(const float*)d_in[23]; fa.mrel_vi=(const float*)d_in[24]; fa.prel_vi=(const float*)d_in[25];
  fa.arel_iv=(const float*)d_in[26]; fa.mrel_iv=(const float*)d_in[27]; fa.prel_iv=(const float*)d_in[28];
  fa.Wa_i=(const float*)d_in[5]; fa.Wa_v=(const float*)d_in[14];
  fa.fwh_var=fwh_var; fa.fwl_var=fwl_var; fa.fwh_ins=fwh_ins; fa.fwl_ins=fwl_ins;
  fa.wah_i=wah_i; fa.wal_i=wal_i; fa.wah_v=wah_v; fa.wal_v=wal_v;
  fa.fwb_var=fwb_var; fa.fwb_ins=fwb_ins;
  k_fold6<<<(6*640*64)/256,256,0,stream>>>(fa);

  for(int l=0;l<6;l++){
    k_gemm_feat<<<NV_N/64+NI_N/64,256,0,stream>>>(xv,xi,
        fwh_var+(size_t)l*320*64,fwl_var+(size_t)l*320*64,fwb_var+l*320,
        fwh_ins+(size_t)l*192*64,fwl_ins+(size_t)l*192*64,fwb_ins+l*192,
        var_feat,ins_feat,NV_N/64);
    k_edge_all<<<NV_N/4+NI_N/4,256,0,stream>>>(rp_all,esrc_all,var_feat,ins_feat,agg_v,agg_i,NV_N/4);
    k_update2<<<NI_N/64+NV_N/64,256,0,stream>>>(agg_i,agg_v,
        wah_i+(size_t)l*4096,wal_i+(size_t)l*4096,wah_v+(size_t)l*4096,wal_v+(size_t)l*4096,
        ba_i+l*64,ba_v+l*64,skip_i+l,skip_v+l,xi,xv,
        (l>0)?(outs+(size_t)(l-1)*NI_N*64):nullptr,NI_N/64);
  }

  // jumping knowledge + head
  k_gemm64p<f16_t,f16_t><<<5*NI_N/64,256,0,stream>>>(outs,5*NI_N,qkvh,qkvl,bqkv,1.0f,qkv,192,0,3);
  k_jk<<<NI_N/4,256,0,stream>>>(qkv,osum,NI_N);
  k_gemm64p<float,float><<<NI_N/64,256,0,stream>>>(osum,NI_N,woh,wol,bo,5.0f,out_jk,64,0,1);
  MlpArgs ma;
  ma.w0=(const float*)d_in[33]; ma.b0=(const float*)d_in[34];
  ma.w1=(const float*)d_in[35]; ma.b1=(const float*)d_in[36];
  ma.w2=(const float*)d_in[37]; ma.b2=(const float*)d_in[38];
  ma.w3=(const float*)d_in[39]; ma.b3=(const float*)d_in[40];
  ma.w4=(const float*)d_in[41]; ma.b4=(const float*)d_in[42];
  ma.w5=(const float*)d_in[43]; ma.b5=(const float*)d_in[44];
  k_mlp<<<NI_N/256,256,0,stream>>>(out_jk,ma,(float*)d_out,NI_N);
}